// Round 2
// baseline (16889.891 us; speedup 1.0000x reference)
//
#include <hip/hip_runtime.h>

#define LTOT 21952      // 28^3
#define NTOK 343        // 7^3
#define PP   148        // padded patch pitch (144 positions used)

// ---------------- LayerNorm (norm1) : f32 in -> f32 out --------------------
__global__ __launch_bounds__(64) void k_ln(const float* __restrict__ mov, const float* __restrict__ fix,
                                           const float* __restrict__ g, const float* __restrict__ b,
                                           float* __restrict__ om, float* __restrict__ of){
  int row = blockIdx.x;
  const float* src; float* dst;
  if (row < LTOT){ src = mov + (size_t)row*192; dst = om + (size_t)row*192; }
  else          { src = fix + (size_t)(row-LTOT)*192; dst = of + (size_t)(row-LTOT)*192; }
  int t = threadIdx.x;
  float x0 = src[t], x1 = src[t+64], x2 = src[t+128];
  float s = x0+x1+x2, s2 = x0*x0 + x1*x1 + x2*x2;
  for (int o=32;o;o>>=1){ s += __shfl_xor(s,o); s2 += __shfl_xor(s2,o); }
  float mu = s*(1.f/192.f);
  float var = s2*(1.f/192.f) - mu*mu;
  float rs = rsqrtf(var + 1e-5f);
  dst[t]     = (x0-mu)*rs*g[t]     + b[t];
  dst[t+64]  = (x1-mu)*rs*g[t+64]  + b[t+64];
  dst[t+128] = (x2-mu)*rs*g[t+128] + b[t+128];
}

// -------------- weight re-layout: (O,C,27) -> (27,C,O) f32 -----------------
__global__ void k_prepw(const float* __restrict__ src, float* __restrict__ dst, int C, int O){
  int idx = blockIdx.x*256 + threadIdx.x;
  int total = 27*C*O;
  if (idx >= total) return;
  int o = idx % O; int c = (idx / O) % C; int t = idx / (O*C);
  dst[idx] = src[(o*C + c)*27 + t];
}

// ------------- conv1: 384 -> 192, 3x3x3 pad1, direct conv ------------------
// block = 192 threads (one per out channel), tile = 14 voxels along W
__global__ __launch_bounds__(192) void k_conv1(const float* __restrict__ xa, const float* __restrict__ xb,
                                               const float* __restrict__ wt, float* __restrict__ out){
  __shared__ float patch[64*PP];
  int b = blockIdx.x;
  int d = b / 56; int rem = b % 56; int h = rem >> 1; int w0 = (rem & 1)*14;
  int tid = threadIdx.x;
  float acc[14];
  #pragma unroll
  for (int i=0;i<14;i++) acc[i]=0.f;
  for (int cc=0; cc<6; cc++){
    const float* xs = (cc<3) ? xa : xb;
    int cbase = (cc%3)*64;
    __syncthreads();
    for (int idx = tid; idx < 64*144; idx += 192){
      int c = idx & 63; int p = idx >> 6;
      int pw = p & 15; int pdh = p >> 4;
      int pd = pdh/3 - 1 + d; int ph = pdh%3 - 1 + h; int pww = w0 - 1 + pw;
      float v = 0.f;
      if ((unsigned)pd < 28u && (unsigned)ph < 28u && (unsigned)pww < 28u)
        v = xs[(size_t)((pd*28 + ph)*28 + pww)*192 + cbase + c];
      patch[c*PP + p] = v;
    }
    __syncthreads();
    for (int c=0;c<64;c++){
      const float* prow = patch + c*PP;
      const float* wb = wt + (size_t)(cc*64 + c)*192 + tid;
      #pragma unroll
      for (int kdh=0;kdh<9;kdh++){
        const float4* p4 = (const float4*)(prow + kdh*16);
        float4 q0=p4[0], q1=p4[1], q2=p4[2], q3=p4[3];
        float r[16] = {q0.x,q0.y,q0.z,q0.w, q1.x,q1.y,q1.z,q1.w,
                       q2.x,q2.y,q2.z,q2.w, q3.x,q3.y,q3.z,q3.w};
        #pragma unroll
        for (int kw=0;kw<3;kw++){
          float wv = wb[(size_t)(kdh*3+kw)*384*192];
          #pragma unroll
          for (int v=0;v<14;v++) acc[v] += r[kw+v]*wv;
        }
      }
    }
  }
  int obase = (d*28 + h)*28 + w0;
  #pragma unroll
  for (int v=0;v<14;v++) out[(size_t)(obase+v)*192 + tid] = acc[v];
}

// per-channel BN stats -> fused scale/shift (a*x+b)
__global__ __launch_bounds__(256) void k_bnstats(const float* __restrict__ x, int C,
                                                 const float* __restrict__ g, const float* __restrict__ b,
                                                 float* __restrict__ a_out, float* __restrict__ b_out){
  int c = blockIdx.x;
  float s=0.f, s2=0.f;
  for (int l = threadIdx.x; l < LTOT; l += 256){
    float v = x[(size_t)l*C + c]; s += v; s2 += v*v;
  }
  for (int o=32;o;o>>=1){ s += __shfl_xor(s,o); s2 += __shfl_xor(s2,o); }
  __shared__ float rs_[4], rs2_[4];
  int wv = threadIdx.x>>6;
  if ((threadIdx.x&63)==0){ rs_[wv]=s; rs2_[wv]=s2; }
  __syncthreads();
  if (threadIdx.x==0){
    s = rs_[0]+rs_[1]+rs_[2]+rs_[3]; s2 = rs2_[0]+rs2_[1]+rs2_[2]+rs2_[3];
    float mu = s/(float)LTOT;
    float var = s2/(float)LTOT - mu*mu;
    float rstd = rsqrtf(var + 1e-5f);
    float aa = rstd * g[c];
    a_out[c] = aa;
    b_out[c] = b[c] - mu*aa;
  }
}

// ------------- conv2: 192 -> 96, 3x3x3 pad1 (input = relu(bn(t1))) ---------
__global__ __launch_bounds__(96) void k_conv2(const float* __restrict__ t1,
                                              const float* __restrict__ a1, const float* __restrict__ b1,
                                              const float* __restrict__ wt, float* __restrict__ out){
  __shared__ float patch[64*PP];
  int b = blockIdx.x;
  int d = b / 56; int rem = b % 56; int h = rem >> 1; int w0 = (rem & 1)*14;
  int tid = threadIdx.x;
  float acc[14];
  #pragma unroll
  for (int i=0;i<14;i++) acc[i]=0.f;
  for (int cc=0; cc<3; cc++){
    int cbase = cc*64;
    __syncthreads();
    for (int idx = tid; idx < 64*144; idx += 96){
      int c = idx & 63; int p = idx >> 6;
      int pw = p & 15; int pdh = p >> 4;
      int pd = pdh/3 - 1 + d; int ph = pdh%3 - 1 + h; int pww = w0 - 1 + pw;
      float v = 0.f;
      if ((unsigned)pd < 28u && (unsigned)ph < 28u && (unsigned)pww < 28u){
        float xv = t1[(size_t)((pd*28 + ph)*28 + pww)*192 + cbase + c];
        v = fmaxf(xv*a1[cbase+c] + b1[cbase+c], 0.f);
      }
      patch[c*PP + p] = v;
    }
    __syncthreads();
    for (int c=0;c<64;c++){
      const float* prow = patch + c*PP;
      const float* wb = wt + (size_t)(cbase + c)*96 + tid;
      #pragma unroll
      for (int kdh=0;kdh<9;kdh++){
        const float4* p4 = (const float4*)(prow + kdh*16);
        float4 q0=p4[0], q1=p4[1], q2=p4[2], q3=p4[3];
        float r[16] = {q0.x,q0.y,q0.z,q0.w, q1.x,q1.y,q1.z,q1.w,
                       q2.x,q2.y,q2.z,q2.w, q3.x,q3.y,q3.z,q3.w};
        #pragma unroll
        for (int kw=0;kw<3;kw++){
          float wv = wb[(size_t)(kdh*3+kw)*192*96];
          #pragma unroll
          for (int v=0;v<14;v++) acc[v] += r[kw+v]*wv;
        }
      }
    }
  }
  int obase = (d*28 + h)*28 + w0;
  #pragma unroll
  for (int v=0;v<14;v++) out[(size_t)(obase+v)*96 + tid] = acc[v];
}

// ------------- conv3 1x1x1: 96 -> 18 flow channels, layout (18, L) ---------
__global__ __launch_bounds__(96) void k_flow(const float* __restrict__ t2,
                                             const float* __restrict__ a2, const float* __restrict__ b2,
                                             const float* __restrict__ w3, float* __restrict__ flow){
  __shared__ float xr[96];
  int l = blockIdx.x; int t = threadIdx.x;
  float xv = t2[(size_t)l*96 + t];
  xr[t] = fmaxf(xv*a2[t] + b2[t], 0.f);
  __syncthreads();
  if (t < 18){
    float acc = 0.f;
    for (int c=0;c<96;c++) acc += xr[c]*w3[t*96 + c];
    flow[(size_t)t*LTOT + l] = acc;
  }
}

// ------------- trilinear warp (per-head flow), border clamp ----------------
__global__ __launch_bounds__(192) void k_warp(const float* __restrict__ src,
                                              const float* __restrict__ flow, float* __restrict__ dst){
  int l = blockIdx.x; int tid = threadIdx.x; int hh = tid>>5;
  int d = l/784; int rm = l - d*784; int y = rm/28; int x = rm - y*28;
  float fd = flow[(size_t)(hh*3+0)*LTOT + l];
  float fy = flow[(size_t)(hh*3+1)*LTOT + l];
  float fx = flow[(size_t)(hh*3+2)*LTOT + l];
  float cd = fminf(fmaxf((float)d + fd, 0.f), 27.f);
  float cy = fminf(fmaxf((float)y + fy, 0.f), 27.f);
  float cx = fminf(fmaxf((float)x + fx, 0.f), 27.f);
  int d0 = (int)floorf(cd); int d1 = min(d0+1, 27);
  int y0 = (int)floorf(cy); int y1 = min(y0+1, 27);
  int x0 = (int)floorf(cx); int x1 = min(x0+1, 27);
  float wd = cd - (float)d0, wy = cy - (float)y0, wx = cx - (float)x0;
  #define SMP(di,yi,xi) src[(size_t)(((di)*28+(yi))*28+(xi))*192 + tid]
  float v000 = SMP(d0,y0,x0), v001 = SMP(d0,y0,x1), v010 = SMP(d0,y1,x0), v011 = SMP(d0,y1,x1);
  float v100 = SMP(d1,y0,x0), v101 = SMP(d1,y0,x1), v110 = SMP(d1,y1,x0), v111 = SMP(d1,y1,x1);
  #undef SMP
  float o = v000*(1-wd)*(1-wy)*(1-wx) + v001*(1-wd)*(1-wy)*wx
          + v010*(1-wd)*wy*(1-wx)     + v011*(1-wd)*wy*wx
          + v100*wd*(1-wy)*(1-wx)     + v101*wd*(1-wy)*wx
          + v110*wd*wy*(1-wx)         + v111*wd*wy*wx;
  dst[(size_t)l*192 + tid] = o;
}

// ------- windowed GEMV: out[(w*6+h)*343+n][c] = (A[roll-map]*W^T + b)*scale -
__global__ __launch_bounds__(192) void k_qkv(const float* __restrict__ A,
                                             const float* __restrict__ Wt, const float* __restrict__ bias,
                                             float* __restrict__ outp, float scale){
  __shared__ float xs[16*192];
  __shared__ int lsrc[16];
  int tid = threadIdx.x; int r0 = blockIdx.x*16;
  if (tid < 16){
    int r = r0 + tid; int w = r/343; int n = r - w*343;
    int nd = w>>4, nh = (w>>2)&3, nw = w&3;
    int i = n/49; int rr = n - i*49; int j = rr/7; int k = rr - j*7;
    int dd = nd*7 + i + 3; if (dd >= 28) dd -= 28;
    int hh = nh*7 + j + 3; if (hh >= 28) hh -= 28;
    int ww = nw*7 + k + 3; if (ww >= 28) ww -= 28;
    lsrc[tid] = (dd*28 + hh)*28 + ww;
  }
  __syncthreads();
  #pragma unroll
  for (int it=0; it<16; it++) xs[it*192 + tid] = A[(size_t)lsrc[it]*192 + tid];
  __syncthreads();
  float acc[16];
  #pragma unroll
  for (int u=0;u<16;u++) acc[u]=0.f;
  const float4* wrow = (const float4*)(Wt + (size_t)tid*192);
  for (int kc=0; kc<24; kc++){
    float4 wa = wrow[kc*2], wbv = wrow[kc*2+1];
    #pragma unroll
    for (int rr2=0; rr2<16; rr2++){
      const float4* xp = (const float4*)(xs + rr2*192 + kc*8);
      float4 x0 = xp[0], x1 = xp[1];
      acc[rr2] += x0.x*wa.x + x0.y*wa.y + x0.z*wa.z + x0.w*wa.w
                + x1.x*wbv.x + x1.y*wbv.y + x1.z*wbv.z + x1.w*wbv.w;
    }
  }
  float bb = bias[tid];
  int h = tid>>5, c = tid&31;
  #pragma unroll
  for (int rr2=0; rr2<16; rr2++){
    int r = r0 + rr2; int w = r/343; int n = r - w*343;
    outp[((size_t)(w*6 + h)*343 + n)*32 + c] = (acc[rr2] + bb)*scale;
  }
}

// ------------ attention: per (window, head), online softmax ----------------
__device__ __forceinline__ int seg3(int nd, int i){ return (nd==3) ? ((i<4)?1:2) : 0; }

__global__ __launch_bounds__(256) void k_attend(const float* __restrict__ Q,
                                                const float* __restrict__ K, const float* __restrict__ V,
                                                float* __restrict__ ctx, const float* __restrict__ rpt){
  __shared__ float kl[NTOK*32];
  int wh = blockIdx.x; int w = wh/6, h = wh - w*6;
  int tid = threadIdx.x;
  const float* kb = K + (size_t)wh*10976;
  for (int idx=tid; idx<10976; idx+=256) kl[idx] = kb[idx];
  __syncthreads();
  int nd = w>>4, nh = (w>>2)&3, nw = w&3;
  const float* vb = V + (size_t)wh*10976;
  for (int rep=0; rep<2; rep++){
    int n = tid + rep*256;
    if (n >= NTOK) break;
    float q[32];
    {
      const float4* qp = (const float4*)(Q + (size_t)wh*10976 + n*32);
      #pragma unroll
      for (int u=0;u<8;u++){ float4 t4 = qp[u]; q[u*4]=t4.x; q[u*4+1]=t4.y; q[u*4+2]=t4.z; q[u*4+3]=t4.w; }
    }
    int i1 = n/49; int r1 = n - i1*49; int j1 = r1/7; int k1 = r1 - j1*7;
    int lab1 = seg3(nd,i1)*9 + seg3(nh,j1)*3 + seg3(nw,k1);
    float mx = -1e30f, sm = 0.f;
    int i2=0, j2=0, k2=0;
    for (int m=0;m<NTOK;m++){
      const float4* kp = (const float4*)(kl + m*32);
      float s = 0.f;
      #pragma unroll
      for (int u=0;u<8;u++){ float4 kk = kp[u];
        s += q[u*4]*kk.x + q[u*4+1]*kk.y + q[u*4+2]*kk.z + q[u*4+3]*kk.w; }
      int ridx = ((i1-i2+6)*13 + (j1-j2+6))*13 + (k1-k2+6);
      s += rpt[ridx*6 + h];
      int lab2 = seg3(nd,i2)*9 + seg3(nh,j2)*3 + seg3(nw,k2);
      s += (lab2==lab1) ? 0.f : -100.f;
      float nm = fmaxf(mx, s);
      sm = sm*__expf(mx-nm) + __expf(s-nm);
      mx = nm;
      k2++; if (k2==7){ k2=0; j2++; if (j2==7){ j2=0; i2++; } }
    }
    float inv = 1.f/sm;
    float acc[32];
    #pragma unroll
    for (int u=0;u<32;u++) acc[u]=0.f;
    i2=0; j2=0; k2=0;
    for (int m=0;m<NTOK;m++){
      const float4* kp = (const float4*)(kl + m*32);
      float s = 0.f;
      #pragma unroll
      for (int u=0;u<8;u++){ float4 kk = kp[u];
        s += q[u*4]*kk.x + q[u*4+1]*kk.y + q[u*4+2]*kk.z + q[u*4+3]*kk.w; }
      int ridx = ((i1-i2+6)*13 + (j1-j2+6))*13 + (k1-k2+6);
      s += rpt[ridx*6 + h];
      int lab2 = seg3(nd,i2)*9 + seg3(nh,j2)*3 + seg3(nw,k2);
      s += (lab2==lab1) ? 0.f : -100.f;
      float p = __expf(s-mx)*inv;
      const float4* vp = (const float4*)(vb + m*32);
      #pragma unroll
      for (int u=0;u<8;u++){ float4 vv = vp[u];
        acc[u*4] += p*vv.x; acc[u*4+1] += p*vv.y; acc[u*4+2] += p*vv.z; acc[u*4+3] += p*vv.w; }
      k2++; if (k2==7){ k2=0; j2++; if (j2==7){ j2=0; i2++; } }
    }
    float4* o4 = (float4*)(ctx + ((size_t)(w*NTOK + n))*192 + h*32);
    #pragma unroll
    for (int u=0;u<8;u++){ float4 t4; t4.x=acc[u*4]; t4.y=acc[u*4+1]; t4.z=acc[u*4+2]; t4.w=acc[u*4+3]; o4[u]=t4; }
  }
}

// ---- proj + residual + window-reverse/unroll: out f32 (L,192) -------------
__global__ __launch_bounds__(192) void k_proj(const float* __restrict__ ctx,
                                              const float* __restrict__ Wt, const float* __restrict__ bias,
                                              const float* __restrict__ resid, float* __restrict__ outp){
  __shared__ float xs[16*192];
  __shared__ int lsrc[16];
  int tid = threadIdx.x; int r0 = blockIdx.x*16;
  if (tid < 16){
    int l = r0 + tid;
    int d = l/784; int rm = l - d*784; int y = rm/28; int x = rm - y*28;
    int dp = d-3; if (dp<0) dp+=28;
    int yp = y-3; if (yp<0) yp+=28;
    int xp = x-3; if (xp<0) xp+=28;
    int nd = dp/7, i = dp - nd*7;
    int nh = yp/7, j = yp - nh*7;
    int nw = xp/7, k = xp - nw*7;
    lsrc[tid] = ((nd*4+nh)*4+nw)*NTOK + (i*7+j)*7 + k;
  }
  __syncthreads();
  #pragma unroll
  for (int it=0; it<16; it++) xs[it*192 + tid] = ctx[(size_t)lsrc[it]*192 + tid];
  __syncthreads();
  float acc[16];
  #pragma unroll
  for (int u=0;u<16;u++) acc[u]=0.f;
  const float4* wrow = (const float4*)(Wt + (size_t)tid*192);
  for (int kc=0; kc<24; kc++){
    float4 wa = wrow[kc*2], wbv = wrow[kc*2+1];
    #pragma unroll
    for (int rr2=0; rr2<16; rr2++){
      const float4* xp = (const float4*)(xs + rr2*192 + kc*8);
      float4 x0 = xp[0], x1 = xp[1];
      acc[rr2] += x0.x*wa.x + x0.y*wa.y + x0.z*wa.z + x0.w*wa.w
                + x1.x*wbv.x + x1.y*wbv.y + x1.z*wbv.z + x1.w*wbv.w;
    }
  }
  float bb = bias[tid];
  #pragma unroll
  for (int rr2=0; rr2<16; rr2++){
    size_t o = (size_t)(r0 + rr2)*192 + tid;
    outp[o] = acc[rr2] + bb + resid[o];
  }
}

// -------- fused LN(norm2) + MLP(gelu exact) + residual, f32 out ------------
__global__ __launch_bounds__(256) void k_mlp(const float* __restrict__ xin,
                                             const float* __restrict__ g, const float* __restrict__ b,
                                             const float* __restrict__ w1, const float* __restrict__ b1,
                                             const float* __restrict__ w2, const float* __restrict__ b2,
                                             float* __restrict__ outp){
  __shared__ float xs[4*192];
  __shared__ float hs[4*768];
  __shared__ float mvv[8];
  int l0 = blockIdx.x*4; int tid = threadIdx.x;
  for (int idx=tid; idx<768; idx+=256) xs[idx] = xin[(size_t)l0*192 + idx];
  __syncthreads();
  {
    int wv = tid>>6, ln = tid&63;
    float a0 = xs[wv*192+ln], a1 = xs[wv*192+ln+64], a2 = xs[wv*192+ln+128];
    float s = a0+a1+a2, s2 = a0*a0+a1*a1+a2*a2;
    for (int o=32;o;o>>=1){ s += __shfl_xor(s,o); s2 += __shfl_xor(s2,o); }
    if (ln==0){
      float mu = s*(1.f/192.f);
      float var = s2*(1.f/192.f) - mu*mu;
      mvv[wv*2] = mu; mvv[wv*2+1] = rsqrtf(var + 1e-5f);
    }
  }
  __syncthreads();
  for (int idx=tid; idx<768; idx+=256){
    int r = idx/192, c = idx - r*192;
    xs[idx] = (xs[idx]-mvv[r*2])*mvv[r*2+1]*g[c] + b[c];
  }
  __syncthreads();
  // fc1 + gelu
  #pragma unroll
  for (int jj=0;jj<3;jj++){
    int j = tid*3 + jj;
    float a0=0.f,a1=0.f,a2=0.f,a3=0.f;
    const float4* wr = (const float4*)(w1 + (size_t)j*192);
    for (int kc=0;kc<24;kc++){
      float4 wa = wr[kc*2], wbv = wr[kc*2+1];
      #pragma unroll
      for (int r=0;r<4;r++){
        const float4* xp = (const float4*)(xs + r*192 + kc*8);
        float4 x0 = xp[0], x1 = xp[1];
        float dv = x0.x*wa.x + x0.y*wa.y + x0.z*wa.z + x0.w*wa.w
                 + x1.x*wbv.x + x1.y*wbv.y + x1.z*wbv.z + x1.w*wbv.w;
        if (r==0) a0 += dv; else if (r==1) a1 += dv; else if (r==2) a2 += dv; else a3 += dv;
      }
    }
    float bv = b1[j];
    a0 += bv; a1 += bv; a2 += bv; a3 += bv;
    hs[0*768+j] = 0.5f*a0*(1.f + erff(a0*0.70710678118f));
    hs[1*768+j] = 0.5f*a1*(1.f + erff(a1*0.70710678118f));
    hs[2*768+j] = 0.5f*a2*(1.f + erff(a2*0.70710678118f));
    hs[3*768+j] = 0.5f*a3*(1.f + erff(a3*0.70710678118f));
  }
  __syncthreads();
  // fc2 + residual + store
  #pragma unroll
  for (int oo=0;oo<3;oo++){
    int gidx = tid*3 + oo; int r = gidx/192; int o = gidx - r*192;
    float acc = b2[o];
    const float4* wr = (const float4*)(w2 + (size_t)o*768);
    const float* hrow = hs + r*768;
    for (int kc=0;kc<96;kc++){
      float4 wa = wr[kc*2], wbv = wr[kc*2+1];
      const float4* hp = (const float4*)(hrow + kc*8);
      float4 h0 = hp[0], h1 = hp[1];
      acc += h0.x*wa.x + h0.y*wa.y + h0.z*wa.z + h0.w*wa.w
           + h1.x*wbv.x + h1.y*wbv.y + h1.z*wbv.z + h1.w*wbv.w;
    }
    float res = xin[(size_t)(l0+r)*192 + o];
    outp[(size_t)(l0+r)*192 + o] = res + acc;
  }
}

// ===========================================================================
extern "C" void kernel_launch(void* const* d_in, const int* in_sizes, int n_in,
                              void* d_out, int out_size, void* d_ws, size_t ws_size,
                              hipStream_t stream){
  const float* mov     = (const float*)d_in[0];
  const float* fix     = (const float*)d_in[1];
  const float* n1g     = (const float*)d_in[2];
  const float* n1b     = (const float*)d_in[3];
  const float* offm_w1 = (const float*)d_in[4];
  const float* offm_g1 = (const float*)d_in[5];
  const float* offm_b1 = (const float*)d_in[6];
  const float* offm_w2 = (const float*)d_in[7];
  const float* offm_g2 = (const float*)d_in[8];
  const float* offm_b2 = (const float*)d_in[9];
  const float* offm_w3 = (const float*)d_in[10];
  const float* offf_w1 = (const float*)d_in[11];
  const float* offf_g1 = (const float*)d_in[12];
  const float* offf_b1 = (const float*)d_in[13];
  const float* offf_w2 = (const float*)d_in[14];
  const float* offf_g2 = (const float*)d_in[15];
  const float* offf_b2 = (const float*)d_in[16];
  const float* offf_w3 = (const float*)d_in[17];
  const float* mq_w    = (const float*)d_in[18];
  const float* mkv_w   = (const float*)d_in[19];
  const float* fq_w    = (const float*)d_in[20];
  const float* fkv_w   = (const float*)d_in[21];
  const float* mproj_w = (const float*)d_in[22];
  const float* fproj_w = (const float*)d_in[23];
  const float* mq_b    = (const float*)d_in[24];
  const float* mkv_b   = (const float*)d_in[25];
  const float* fq_b    = (const float*)d_in[26];
  const float* fkv_b   = (const float*)d_in[27];
  const float* mproj_b = (const float*)d_in[28];
  const float* fproj_b = (const float*)d_in[29];
  const float* rpbt    = (const float*)d_in[30];
  const float* n2g     = (const float*)d_in[31];
  const float* n2b     = (const float*)d_in[32];
  const float* fc1_w   = (const float*)d_in[33];
  const float* fc1_b   = (const float*)d_in[34];
  const float* fc2_w   = (const float*)d_in[35];
  const float* fc2_b   = (const float*)d_in[36];
  float* outp = (float*)d_out;

  float* W = (float*)d_ws;
  const size_t L192 = (size_t)LTOT*192;
  float* m_   = W;
  float* f_   = W + 1*L192;
  float* t1   = W + 2*L192;
  float* t2   = W + 3*L192;
  float* dmov = W + 4*L192;
  float* dfix = W + 5*L192;
  float* QM   = W + 6*L192;
  float* QF   = W + 7*L192;
  float* Kf   = W + 8*L192;
  float* Vf   = W + 9*L192;
  float* Km = t1;  float* Vm = t2;
  float* ctxm = dmov; float* ctxf = dfix;
  float* mout = m_;   float* fout = f_;
  // transient aliases (lifetimes end before the hosting regions are written):
  float* a1v = QM;        float* b1v = QM + 192;   // BN params (dead before QM write)
  float* a2v = QM + 384;  float* b2v = QM + 480;
  float* flowm = QF;      float* flowf = QF + (size_t)LTOT*18;  // dead before QF write
  float* wt1m = Kf;                       // prepped conv1 weights (f32, 7.96MB each) in Kf
  float* wt1f = wt1m + 27*384*192;        // 2x 1,990,656 floats = 15.9MB < 16.86MB region
  float* wt2m = Vf;                       // prepped conv2 weights in Vf (2x ~2MB)
  float* wt2f = wt2m + 27*192*96;

  // weight re-layout
  {
    int tot1 = 27*384*192;
    k_prepw<<<(tot1+255)/256, 256, 0, stream>>>(offm_w1, wt1m, 384, 192);
    k_prepw<<<(tot1+255)/256, 256, 0, stream>>>(offf_w1, wt1f, 384, 192);
    int tot2 = 27*192*96;
    k_prepw<<<(tot2+255)/256, 256, 0, stream>>>(offm_w2, wt2m, 192, 96);
    k_prepw<<<(tot2+255)/256, 256, 0, stream>>>(offf_w2, wt2f, 192, 96);
  }
  // layernorm1
  k_ln<<<2*LTOT, 64, 0, stream>>>(mov, fix, n1g, n1b, m_, f_);
  // offset block (moving): input concat(m, f)
  k_conv1<<<1568, 192, 0, stream>>>(m_, f_, wt1m, t1);
  k_bnstats<<<192, 256, 0, stream>>>(t1, 192, offm_g1, offm_b1, a1v, b1v);
  k_conv2<<<1568, 96, 0, stream>>>(t1, a1v, b1v, wt2m, t2);
  k_bnstats<<<96, 256, 0, stream>>>(t2, 96, offm_g2, offm_b2, a2v, b2v);
  k_flow<<<LTOT, 96, 0, stream>>>(t2, a2v, b2v, offm_w3, flowm);
  // offset block (fixed): input concat(f, m)
  k_conv1<<<1568, 192, 0, stream>>>(f_, m_, wt1f, t1);
  k_bnstats<<<192, 256, 0, stream>>>(t1, 192, offf_g1, offf_b1, a1v, b1v);
  k_conv2<<<1568, 96, 0, stream>>>(t1, a1v, b1v, wt2f, t2);
  k_bnstats<<<96, 256, 0, stream>>>(t2, 96, offf_g2, offf_b2, a2v, b2v);
  k_flow<<<LTOT, 96, 0, stream>>>(t2, a2v, b2v, offf_w3, flowf);
  // deformable warp
  k_warp<<<LTOT, 192, 0, stream>>>(m_, flowm, dmov);
  k_warp<<<LTOT, 192, 0, stream>>>(f_, flowf, dfix);
  // windowed projections (roll folded into gather)
  const float scale = 0.17677669529663687f; // 32^-0.5
  k_qkv<<<1372, 192, 0, stream>>>(dmov, mq_w,  mq_b,  QM, scale);   // dmQ
  k_qkv<<<1372, 192, 0, stream>>>(dfix, fq_w,  fq_b,  QF, scale);   // dfQ
  k_qkv<<<1372, 192, 0, stream>>>(m_, mkv_w,          mkv_b,     Km, 1.f);
  k_qkv<<<1372, 192, 0, stream>>>(m_, mkv_w+192*192,  mkv_b+192, Vm, 1.f);
  k_qkv<<<1372, 192, 0, stream>>>(f_, fkv_w,          fkv_b,     Kf, 1.f);
  k_qkv<<<1372, 192, 0, stream>>>(f_, fkv_w+192*192,  fkv_b+192, Vf, 1.f);
  // attention: mo = attend(dfQ, mK, mV); fo = attend(dmQ, fK, fV)
  k_attend<<<384, 256, 0, stream>>>(QF, Km, Vm, ctxm, rpbt);
  k_attend<<<384, 256, 0, stream>>>(QM, Kf, Vf, ctxf, rpbt);
  // proj + residual + window-reverse/unroll
  k_proj<<<1372, 192, 0, stream>>>(ctxm, mproj_w, mproj_b, mov, mout);
  k_proj<<<1372, 192, 0, stream>>>(ctxf, fproj_w, fproj_b, fix, fout);
  // MLP + residual -> final f32 output (2, B, L, DIM)
  k_mlp<<<LTOT/4, 256, 0, stream>>>(mout, n2g, n2b, fc1_w, fc1_b, fc2_w, fc2_b, outp);
  k_mlp<<<LTOT/4, 256, 0, stream>>>(fout, n2g, n2b, fc1_w, fc1_b, fc2_w, fc2_b, outp + L192);
}

// Round 3
// 10228.522 us; speedup vs baseline: 1.6513x; 1.6513x over previous
//
#include <hip/hip_runtime.h>

#define LTOT 21952      // 28^3
#define NTOK 343        // 7^3
#define PP   148        // padded patch pitch (144 positions used)

// ---------------- LayerNorm (norm1) : f32 in -> f32 out --------------------
__global__ __launch_bounds__(64) void k_ln(const float* __restrict__ mov, const float* __restrict__ fix,
                                           const float* __restrict__ g, const float* __restrict__ b,
                                           float* __restrict__ om, float* __restrict__ of){
  int row = blockIdx.x;
  const float* src; float* dst;
  if (row < LTOT){ src = mov + (size_t)row*192; dst = om + (size_t)row*192; }
  else          { src = fix + (size_t)(row-LTOT)*192; dst = of + (size_t)(row-LTOT)*192; }
  int t = threadIdx.x;
  float x0 = src[t], x1 = src[t+64], x2 = src[t+128];
  float s = x0+x1+x2, s2 = x0*x0 + x1*x1 + x2*x2;
  for (int o=32;o;o>>=1){ s += __shfl_xor(s,o); s2 += __shfl_xor(s2,o); }
  float mu = s*(1.f/192.f);
  float var = s2*(1.f/192.f) - mu*mu;
  float rs = rsqrtf(var + 1e-5f);
  dst[t]     = (x0-mu)*rs*g[t]     + b[t];
  dst[t+64]  = (x1-mu)*rs*g[t+64]  + b[t+64];
  dst[t+128] = (x2-mu)*rs*g[t+128] + b[t+128];
}

// ---------------- LayerNorm (norm2), single buffer -------------------------
__global__ __launch_bounds__(64) void k_ln1(const float* __restrict__ x,
                                            const float* __restrict__ g, const float* __restrict__ b,
                                            float* __restrict__ y){
  int row = blockIdx.x;
  const float* src = x + (size_t)row*192;
  float* dst = y + (size_t)row*192;
  int t = threadIdx.x;
  float x0 = src[t], x1 = src[t+64], x2 = src[t+128];
  float s = x0+x1+x2, s2 = x0*x0 + x1*x1 + x2*x2;
  for (int o=32;o;o>>=1){ s += __shfl_xor(s,o); s2 += __shfl_xor(s2,o); }
  float mu = s*(1.f/192.f);
  float var = s2*(1.f/192.f) - mu*mu;
  float rs = rsqrtf(var + 1e-5f);
  dst[t]     = (x0-mu)*rs*g[t]     + b[t];
  dst[t+64]  = (x1-mu)*rs*g[t+64]  + b[t+64];
  dst[t+128] = (x2-mu)*rs*g[t+128] + b[t+128];
}

// -------------- weight re-layout: (O,C,27) -> (27,C,O) f32 -----------------
__global__ void k_prepw(const float* __restrict__ src, float* __restrict__ dst, int C, int O){
  int idx = blockIdx.x*256 + threadIdx.x;
  int total = 27*C*O;
  if (idx >= total) return;
  int o = idx % O; int c = (idx / O) % C; int t = idx / (O*C);
  dst[idx] = src[(o*C + c)*27 + t];
}

// ------------- conv1: 384 -> 192, 3x3x3 pad1, direct conv ------------------
__global__ __launch_bounds__(192) void k_conv1(const float* __restrict__ xa, const float* __restrict__ xb,
                                               const float* __restrict__ wt, float* __restrict__ out){
  __shared__ float patch[64*PP];
  int b = blockIdx.x;
  int d = b / 56; int rem = b % 56; int h = rem >> 1; int w0 = (rem & 1)*14;
  int tid = threadIdx.x;
  float acc[14];
  #pragma unroll
  for (int i=0;i<14;i++) acc[i]=0.f;
  for (int cc=0; cc<6; cc++){
    const float* xs = (cc<3) ? xa : xb;
    int cbase = (cc%3)*64;
    __syncthreads();
    for (int idx = tid; idx < 64*144; idx += 192){
      int c = idx & 63; int p = idx >> 6;
      int pw = p & 15; int pdh = p >> 4;
      int pd = pdh/3 - 1 + d; int ph = pdh%3 - 1 + h; int pww = w0 - 1 + pw;
      float v = 0.f;
      if ((unsigned)pd < 28u && (unsigned)ph < 28u && (unsigned)pww < 28u)
        v = xs[(size_t)((pd*28 + ph)*28 + pww)*192 + cbase + c];
      patch[c*PP + p] = v;
    }
    __syncthreads();
    for (int c=0;c<64;c++){
      const float* prow = patch + c*PP;
      const float* wb = wt + (size_t)(cc*64 + c)*192 + tid;
      #pragma unroll
      for (int kdh=0;kdh<9;kdh++){
        const float4* p4 = (const float4*)(prow + kdh*16);
        float4 q0=p4[0], q1=p4[1], q2=p4[2], q3=p4[3];
        float r[16] = {q0.x,q0.y,q0.z,q0.w, q1.x,q1.y,q1.z,q1.w,
                       q2.x,q2.y,q2.z,q2.w, q3.x,q3.y,q3.z,q3.w};
        #pragma unroll
        for (int kw=0;kw<3;kw++){
          float wv = wb[(size_t)(kdh*3+kw)*384*192];
          #pragma unroll
          for (int v=0;v<14;v++) acc[v] += r[kw+v]*wv;
        }
      }
    }
  }
  int obase = (d*28 + h)*28 + w0;
  #pragma unroll
  for (int v=0;v<14;v++) out[(size_t)(obase+v)*192 + tid] = acc[v];
}

// per-channel BN stats -> fused scale/shift (a*x+b)
__global__ __launch_bounds__(256) void k_bnstats(const float* __restrict__ x, int C,
                                                 const float* __restrict__ g, const float* __restrict__ b,
                                                 float* __restrict__ a_out, float* __restrict__ b_out){
  int c = blockIdx.x;
  float s=0.f, s2=0.f;
  for (int l = threadIdx.x; l < LTOT; l += 256){
    float v = x[(size_t)l*C + c]; s += v; s2 += v*v;
  }
  for (int o=32;o;o>>=1){ s += __shfl_xor(s,o); s2 += __shfl_xor(s2,o); }
  __shared__ float rs_[4], rs2_[4];
  int wv = threadIdx.x>>6;
  if ((threadIdx.x&63)==0){ rs_[wv]=s; rs2_[wv]=s2; }
  __syncthreads();
  if (threadIdx.x==0){
    s = rs_[0]+rs_[1]+rs_[2]+rs_[3]; s2 = rs2_[0]+rs2_[1]+rs2_[2]+rs2_[3];
    float mu = s/(float)LTOT;
    float var = s2/(float)LTOT - mu*mu;
    float rstd = rsqrtf(var + 1e-5f);
    float aa = rstd * g[c];
    a_out[c] = aa;
    b_out[c] = b[c] - mu*aa;
  }
}

// ------------- conv2: 192 -> 96, 3x3x3 pad1 (input = relu(bn(t1))) ---------
__global__ __launch_bounds__(96) void k_conv2(const float* __restrict__ t1,
                                              const float* __restrict__ a1, const float* __restrict__ b1,
                                              const float* __restrict__ wt, float* __restrict__ out){
  __shared__ float patch[64*PP];
  int b = blockIdx.x;
  int d = b / 56; int rem = b % 56; int h = rem >> 1; int w0 = (rem & 1)*14;
  int tid = threadIdx.x;
  float acc[14];
  #pragma unroll
  for (int i=0;i<14;i++) acc[i]=0.f;
  for (int cc=0; cc<3; cc++){
    int cbase = cc*64;
    __syncthreads();
    for (int idx = tid; idx < 64*144; idx += 96){
      int c = idx & 63; int p = idx >> 6;
      int pw = p & 15; int pdh = p >> 4;
      int pd = pdh/3 - 1 + d; int ph = pdh%3 - 1 + h; int pww = w0 - 1 + pw;
      float v = 0.f;
      if ((unsigned)pd < 28u && (unsigned)ph < 28u && (unsigned)pww < 28u){
        float xv = t1[(size_t)((pd*28 + ph)*28 + pww)*192 + cbase + c];
        v = fmaxf(xv*a1[cbase+c] + b1[cbase+c], 0.f);
      }
      patch[c*PP + p] = v;
    }
    __syncthreads();
    for (int c=0;c<64;c++){
      const float* prow = patch + c*PP;
      const float* wb = wt + (size_t)(cbase + c)*96 + tid;
      #pragma unroll
      for (int kdh=0;kdh<9;kdh++){
        const float4* p4 = (const float4*)(prow + kdh*16);
        float4 q0=p4[0], q1=p4[1], q2=p4[2], q3=p4[3];
        float r[16] = {q0.x,q0.y,q0.z,q0.w, q1.x,q1.y,q1.z,q1.w,
                       q2.x,q2.y,q2.z,q2.w, q3.x,q3.y,q3.z,q3.w};
        #pragma unroll
        for (int kw=0;kw<3;kw++){
          float wv = wb[(size_t)(kdh*3+kw)*192*96];
          #pragma unroll
          for (int v=0;v<14;v++) acc[v] += r[kw+v]*wv;
        }
      }
    }
  }
  int obase = (d*28 + h)*28 + w0;
  #pragma unroll
  for (int v=0;v<14;v++) out[(size_t)(obase+v)*96 + tid] = acc[v];
}

// ------------- conv3 1x1x1: 96 -> 18 flow channels, layout (18, L) ---------
__global__ __launch_bounds__(96) void k_flow(const float* __restrict__ t2,
                                             const float* __restrict__ a2, const float* __restrict__ b2,
                                             const float* __restrict__ w3, float* __restrict__ flow){
  __shared__ float xr[96];
  int l = blockIdx.x; int t = threadIdx.x;
  float xv = t2[(size_t)l*96 + t];
  xr[t] = fmaxf(xv*a2[t] + b2[t], 0.f);
  __syncthreads();
  if (t < 18){
    float acc = 0.f;
    for (int c=0;c<96;c++) acc += xr[c]*w3[t*96 + c];
    flow[(size_t)t*LTOT + l] = acc;
  }
}

// ------------- trilinear warp (per-head flow), border clamp ----------------
__global__ __launch_bounds__(192) void k_warp(const float* __restrict__ src,
                                              const float* __restrict__ flow, float* __restrict__ dst){
  int l = blockIdx.x; int tid = threadIdx.x; int hh = tid>>5;
  int d = l/784; int rm = l - d*784; int y = rm/28; int x = rm - y*28;
  float fd = flow[(size_t)(hh*3+0)*LTOT + l];
  float fy = flow[(size_t)(hh*3+1)*LTOT + l];
  float fx = flow[(size_t)(hh*3+2)*LTOT + l];
  float cd = fminf(fmaxf((float)d + fd, 0.f), 27.f);
  float cy = fminf(fmaxf((float)y + fy, 0.f), 27.f);
  float cx = fminf(fmaxf((float)x + fx, 0.f), 27.f);
  int d0 = (int)floorf(cd); int d1 = min(d0+1, 27);
  int y0 = (int)floorf(cy); int y1 = min(y0+1, 27);
  int x0 = (int)floorf(cx); int x1 = min(x0+1, 27);
  float wd = cd - (float)d0, wy = cy - (float)y0, wx = cx - (float)x0;
  #define SMP(di,yi,xi) src[(size_t)(((di)*28+(yi))*28+(xi))*192 + tid]
  float v000 = SMP(d0,y0,x0), v001 = SMP(d0,y0,x1), v010 = SMP(d0,y1,x0), v011 = SMP(d0,y1,x1);
  float v100 = SMP(d1,y0,x0), v101 = SMP(d1,y0,x1), v110 = SMP(d1,y1,x0), v111 = SMP(d1,y1,x1);
  #undef SMP
  float o = v000*(1-wd)*(1-wy)*(1-wx) + v001*(1-wd)*(1-wy)*wx
          + v010*(1-wd)*wy*(1-wx)     + v011*(1-wd)*wy*wx
          + v100*wd*(1-wy)*(1-wx)     + v101*wd*(1-wy)*wx
          + v110*wd*wy*(1-wx)         + v111*wd*wy*wx;
  dst[(size_t)l*192 + tid] = o;
}

// ------- windowed GEMV: out[(w*6+h)*343+n][c] = (A[roll-map]*W^T + b)*scale -
__global__ __launch_bounds__(192) void k_qkv(const float* __restrict__ A,
                                             const float* __restrict__ Wt, const float* __restrict__ bias,
                                             float* __restrict__ outp, float scale){
  __shared__ float xs[16*192];
  __shared__ int lsrc[16];
  int tid = threadIdx.x; int r0 = blockIdx.x*16;
  if (tid < 16){
    int r = r0 + tid; int w = r/343; int n = r - w*343;
    int nd = w>>4, nh = (w>>2)&3, nw = w&3;
    int i = n/49; int rr = n - i*49; int j = rr/7; int k = rr - j*7;
    int dd = nd*7 + i + 3; if (dd >= 28) dd -= 28;
    int hh = nh*7 + j + 3; if (hh >= 28) hh -= 28;
    int ww = nw*7 + k + 3; if (ww >= 28) ww -= 28;
    lsrc[tid] = (dd*28 + hh)*28 + ww;
  }
  __syncthreads();
  #pragma unroll
  for (int it=0; it<16; it++) xs[it*192 + tid] = A[(size_t)lsrc[it]*192 + tid];
  __syncthreads();
  float acc[16];
  #pragma unroll
  for (int u=0;u<16;u++) acc[u]=0.f;
  const float4* wrow = (const float4*)(Wt + (size_t)tid*192);
  for (int kc=0; kc<24; kc++){
    float4 wa = wrow[kc*2], wbv = wrow[kc*2+1];
    #pragma unroll
    for (int rr2=0; rr2<16; rr2++){
      const float4* xp = (const float4*)(xs + rr2*192 + kc*8);
      float4 x0 = xp[0], x1 = xp[1];
      acc[rr2] += x0.x*wa.x + x0.y*wa.y + x0.z*wa.z + x0.w*wa.w
                + x1.x*wbv.x + x1.y*wbv.y + x1.z*wbv.z + x1.w*wbv.w;
    }
  }
  float bb = bias[tid];
  int h = tid>>5, c = tid&31;
  #pragma unroll
  for (int rr2=0; rr2<16; rr2++){
    int r = r0 + rr2; int w = r/343; int n = r - w*343;
    outp[((size_t)(w*6 + h)*343 + n)*32 + c] = (acc[rr2] + bb)*scale;
  }
}

// ------------ attention: per (window, head), online softmax ----------------
__device__ __forceinline__ int seg3(int nd, int i){ return (nd==3) ? ((i<4)?1:2) : 0; }

__global__ __launch_bounds__(256) void k_attend(const float* __restrict__ Q,
                                                const float* __restrict__ K, const float* __restrict__ V,
                                                float* __restrict__ ctx, const float* __restrict__ rpt){
  __shared__ float kl[NTOK*32];
  int wh = blockIdx.x; int w = wh/6, h = wh - w*6;
  int tid = threadIdx.x;
  const float* kb = K + (size_t)wh*10976;
  for (int idx=tid; idx<10976; idx+=256) kl[idx] = kb[idx];
  __syncthreads();
  int nd = w>>4, nh = (w>>2)&3, nw = w&3;
  const float* vb = V + (size_t)wh*10976;
  for (int rep=0; rep<2; rep++){
    int n = tid + rep*256;
    if (n >= NTOK) break;
    float q[32];
    {
      const float4* qp = (const float4*)(Q + (size_t)wh*10976 + n*32);
      #pragma unroll
      for (int u=0;u<8;u++){ float4 t4 = qp[u]; q[u*4]=t4.x; q[u*4+1]=t4.y; q[u*4+2]=t4.z; q[u*4+3]=t4.w; }
    }
    int i1 = n/49; int r1 = n - i1*49; int j1 = r1/7; int k1 = r1 - j1*7;
    int lab1 = seg3(nd,i1)*9 + seg3(nh,j1)*3 + seg3(nw,k1);
    float mx = -1e30f, sm = 0.f;
    int i2=0, j2=0, k2=0;
    for (int m=0;m<NTOK;m++){
      const float4* kp = (const float4*)(kl + m*32);
      float s = 0.f;
      #pragma unroll
      for (int u=0;u<8;u++){ float4 kk = kp[u];
        s += q[u*4]*kk.x + q[u*4+1]*kk.y + q[u*4+2]*kk.z + q[u*4+3]*kk.w; }
      int ridx = ((i1-i2+6)*13 + (j1-j2+6))*13 + (k1-k2+6);
      s += rpt[ridx*6 + h];
      int lab2 = seg3(nd,i2)*9 + seg3(nh,j2)*3 + seg3(nw,k2);
      s += (lab2==lab1) ? 0.f : -100.f;
      float nm = fmaxf(mx, s);
      sm = sm*__expf(mx-nm) + __expf(s-nm);
      mx = nm;
      k2++; if (k2==7){ k2=0; j2++; if (j2==7){ j2=0; i2++; } }
    }
    float inv = 1.f/sm;
    float acc[32];
    #pragma unroll
    for (int u=0;u<32;u++) acc[u]=0.f;
    i2=0; j2=0; k2=0;
    for (int m=0;m<NTOK;m++){
      const float4* kp = (const float4*)(kl + m*32);
      float s = 0.f;
      #pragma unroll
      for (int u=0;u<8;u++){ float4 kk = kp[u];
        s += q[u*4]*kk.x + q[u*4+1]*kk.y + q[u*4+2]*kk.z + q[u*4+3]*kk.w; }
      int ridx = ((i1-i2+6)*13 + (j1-j2+6))*13 + (k1-k2+6);
      s += rpt[ridx*6 + h];
      int lab2 = seg3(nd,i2)*9 + seg3(nh,j2)*3 + seg3(nw,k2);
      s += (lab2==lab1) ? 0.f : -100.f;
      float p = __expf(s-mx)*inv;
      const float4* vp = (const float4*)(vb + m*32);
      #pragma unroll
      for (int u=0;u<8;u++){ float4 vv = vp[u];
        acc[u*4] += p*vv.x; acc[u*4+1] += p*vv.y; acc[u*4+2] += p*vv.z; acc[u*4+3] += p*vv.w; }
      k2++; if (k2==7){ k2=0; j2++; if (j2==7){ j2=0; i2++; } }
    }
    float4* o4 = (float4*)(ctx + ((size_t)(w*NTOK + n))*192 + h*32);
    #pragma unroll
    for (int u=0;u<8;u++){ float4 t4; t4.x=acc[u*4]; t4.y=acc[u*4+1]; t4.z=acc[u*4+2]; t4.w=acc[u*4+3]; o4[u]=t4; }
  }
}

// ---- proj + residual + window-reverse/unroll: out f32 (L,192) -------------
__global__ __launch_bounds__(192) void k_proj(const float* __restrict__ ctx,
                                              const float* __restrict__ Wt, const float* __restrict__ bias,
                                              const float* __restrict__ resid, float* __restrict__ outp){
  __shared__ float xs[16*192];
  __shared__ int lsrc[16];
  int tid = threadIdx.x; int r0 = blockIdx.x*16;
  if (tid < 16){
    int l = r0 + tid;
    int d = l/784; int rm = l - d*784; int y = rm/28; int x = rm - y*28;
    int dp = d-3; if (dp<0) dp+=28;
    int yp = y-3; if (yp<0) yp+=28;
    int xp = x-3; if (xp<0) xp+=28;
    int nd = dp/7, i = dp - nd*7;
    int nh = yp/7, j = yp - nh*7;
    int nw = xp/7, k = xp - nw*7;
    lsrc[tid] = ((nd*4+nh)*4+nw)*NTOK + (i*7+j)*7 + k;
  }
  __syncthreads();
  #pragma unroll
  for (int it=0; it<16; it++) xs[it*192 + tid] = ctx[(size_t)lsrc[it]*192 + tid];
  __syncthreads();
  float acc[16];
  #pragma unroll
  for (int u=0;u<16;u++) acc[u]=0.f;
  const float4* wrow = (const float4*)(Wt + (size_t)tid*192);
  for (int kc=0; kc<24; kc++){
    float4 wa = wrow[kc*2], wbv = wrow[kc*2+1];
    #pragma unroll
    for (int rr2=0; rr2<16; rr2++){
      const float4* xp = (const float4*)(xs + rr2*192 + kc*8);
      float4 x0 = xp[0], x1 = xp[1];
      acc[rr2] += x0.x*wa.x + x0.y*wa.y + x0.z*wa.z + x0.w*wa.w
                + x1.x*wbv.x + x1.y*wbv.y + x1.z*wbv.z + x1.w*wbv.w;
    }
  }
  float bb = bias[tid];
  #pragma unroll
  for (int rr2=0; rr2<16; rr2++){
    size_t o = (size_t)(r0 + rr2)*192 + tid;
    outp[o] = acc[rr2] + bb + resid[o];
  }
}

// ------- fc1 + gelu: x_ln [L,192] -> hs [L,768], 16-token tiles ------------
__global__ __launch_bounds__(384) void k_fc1(const float* __restrict__ xin,
                                             const float* __restrict__ w1, const float* __restrict__ b1,
                                             float* __restrict__ hs){
  __shared__ float xs[16*192];
  int tid = threadIdx.x; int l0 = blockIdx.x*16;
  for (int idx=tid; idx<16*192; idx+=384) xs[idx] = xin[(size_t)l0*192 + idx];
  __syncthreads();
  float a0[16], a1[16];
  #pragma unroll
  for (int t=0;t<16;t++){ a0[t]=0.f; a1[t]=0.f; }
  int j0 = tid, j1 = tid + 384;
  const float4* wr0 = (const float4*)(w1 + (size_t)j0*192);
  const float4* wr1 = (const float4*)(w1 + (size_t)j1*192);
  for (int kc=0; kc<48; kc++){
    float4 wa = wr0[kc], wb = wr1[kc];
    #pragma unroll
    for (int t=0;t<16;t++){
      const float4* xp = (const float4*)(xs + t*192 + kc*4);
      float4 x4 = xp[0];
      a0[t] += x4.x*wa.x + x4.y*wa.y + x4.z*wa.z + x4.w*wa.w;
      a1[t] += x4.x*wb.x + x4.y*wb.y + x4.z*wb.z + x4.w*wb.w;
    }
  }
  float bv0 = b1[j0], bv1 = b1[j1];
  #pragma unroll
  for (int t=0;t<16;t++){
    float v0 = a0[t] + bv0, v1 = a1[t] + bv1;
    hs[(size_t)(l0+t)*768 + j0] = 0.5f*v0*(1.f + erff(v0*0.70710678118f));
    hs[(size_t)(l0+t)*768 + j1] = 0.5f*v1*(1.f + erff(v1*0.70710678118f));
  }
}

// ------- fc2 + residual: hs [L,768] -> out [L,192] (adds resid) ------------
__global__ __launch_bounds__(192) void k_fc2(const float* __restrict__ hs,
                                             const float* __restrict__ w2, const float* __restrict__ b2,
                                             const float* __restrict__ resid, float* __restrict__ outp){
  __shared__ float hl[16*768];
  int tid = threadIdx.x; int l0 = blockIdx.x*16;
  for (int idx=tid; idx<16*768; idx+=192) hl[idx] = hs[(size_t)l0*768 + idx];
  __syncthreads();
  float acc[16];
  #pragma unroll
  for (int t=0;t<16;t++) acc[t]=0.f;
  const float4* wr = (const float4*)(w2 + (size_t)tid*768);
  for (int kc=0; kc<192; kc++){
    float4 wa = wr[kc];
    #pragma unroll
    for (int t=0;t<16;t++){
      const float4* hp = (const float4*)(hl + t*768 + kc*4);
      float4 h4 = hp[0];
      acc[t] += h4.x*wa.x + h4.y*wa.y + h4.z*wa.z + h4.w*wa.w;
    }
  }
  float bb = b2[tid];
  #pragma unroll
  for (int t=0;t<16;t++){
    size_t o = (size_t)(l0+t)*192 + tid;
    outp[o] = acc[t] + bb + resid[o];
  }
}

// ===========================================================================
extern "C" void kernel_launch(void* const* d_in, const int* in_sizes, int n_in,
                              void* d_out, int out_size, void* d_ws, size_t ws_size,
                              hipStream_t stream){
  const float* mov     = (const float*)d_in[0];
  const float* fix     = (const float*)d_in[1];
  const float* n1g     = (const float*)d_in[2];
  const float* n1b     = (const float*)d_in[3];
  const float* offm_w1 = (const float*)d_in[4];
  const float* offm_g1 = (const float*)d_in[5];
  const float* offm_b1 = (const float*)d_in[6];
  const float* offm_w2 = (const float*)d_in[7];
  const float* offm_g2 = (const float*)d_in[8];
  const float* offm_b2 = (const float*)d_in[9];
  const float* offm_w3 = (const float*)d_in[10];
  const float* offf_w1 = (const float*)d_in[11];
  const float* offf_g1 = (const float*)d_in[12];
  const float* offf_b1 = (const float*)d_in[13];
  const float* offf_w2 = (const float*)d_in[14];
  const float* offf_g2 = (const float*)d_in[15];
  const float* offf_b2 = (const float*)d_in[16];
  const float* offf_w3 = (const float*)d_in[17];
  const float* mq_w    = (const float*)d_in[18];
  const float* mkv_w   = (const float*)d_in[19];
  const float* fq_w    = (const float*)d_in[20];
  const float* fkv_w   = (const float*)d_in[21];
  const float* mproj_w = (const float*)d_in[22];
  const float* fproj_w = (const float*)d_in[23];
  const float* mq_b    = (const float*)d_in[24];
  const float* mkv_b   = (const float*)d_in[25];
  const float* fq_b    = (const float*)d_in[26];
  const float* fkv_b   = (const float*)d_in[27];
  const float* mproj_b = (const float*)d_in[28];
  const float* fproj_b = (const float*)d_in[29];
  const float* rpbt    = (const float*)d_in[30];
  const float* n2g     = (const float*)d_in[31];
  const float* n2b     = (const float*)d_in[32];
  const float* fc1_w   = (const float*)d_in[33];
  const float* fc1_b   = (const float*)d_in[34];
  const float* fc2_w   = (const float*)d_in[35];
  const float* fc2_b   = (const float*)d_in[36];
  float* outp = (float*)d_out;

  float* W = (float*)d_ws;
  const size_t L192 = (size_t)LTOT*192;
  float* m_   = W;
  float* f_   = W + 1*L192;
  float* t1   = W + 2*L192;
  float* t2   = W + 3*L192;
  float* dmov = W + 4*L192;
  float* dfix = W + 5*L192;
  float* QM   = W + 6*L192;
  float* QF   = W + 7*L192;
  float* Kf   = W + 8*L192;
  float* Vf   = W + 9*L192;
  float* Km = t1;  float* Vm = t2;
  float* ctxm = dmov; float* ctxf = dfix;
  float* mout = m_;   float* fout = f_;
  // transient aliases (lifetimes end before the hosting regions are written):
  float* a1v = QM;        float* b1v = QM + 192;   // BN params (dead before QM write)
  float* a2v = QM + 384;  float* b2v = QM + 480;
  float* flowm = QF;      float* flowf = QF + (size_t)LTOT*18;  // dead before QF write
  float* wt1m = Kf;                       // prepped conv1 weights (f32, 7.96MB each) in Kf
  float* wt1f = wt1m + 27*384*192;
  float* wt2m = Vf;                       // prepped conv2 weights in Vf
  float* wt2f = wt2m + 27*192*96;
  // MLP-phase aliases (regions 2..5 and 6 are dead after k_proj):
  float* hsbuf = t1;                      // 21952*768 f32 = regions 2..5 exactly
  float* lnbuf = QM;                      // region 6

  // weight re-layout
  {
    int tot1 = 27*384*192;
    k_prepw<<<(tot1+255)/256, 256, 0, stream>>>(offm_w1, wt1m, 384, 192);
    k_prepw<<<(tot1+255)/256, 256, 0, stream>>>(offf_w1, wt1f, 384, 192);
    int tot2 = 27*192*96;
    k_prepw<<<(tot2+255)/256, 256, 0, stream>>>(offm_w2, wt2m, 192, 96);
    k_prepw<<<(tot2+255)/256, 256, 0, stream>>>(offf_w2, wt2f, 192, 96);
  }
  // layernorm1
  k_ln<<<2*LTOT, 64, 0, stream>>>(mov, fix, n1g, n1b, m_, f_);
  // offset block (moving): input concat(m, f)
  k_conv1<<<1568, 192, 0, stream>>>(m_, f_, wt1m, t1);
  k_bnstats<<<192, 256, 0, stream>>>(t1, 192, offm_g1, offm_b1, a1v, b1v);
  k_conv2<<<1568, 96, 0, stream>>>(t1, a1v, b1v, wt2m, t2);
  k_bnstats<<<96, 256, 0, stream>>>(t2, 96, offm_g2, offm_b2, a2v, b2v);
  k_flow<<<LTOT, 96, 0, stream>>>(t2, a2v, b2v, offm_w3, flowm);
  // offset block (fixed): input concat(f, m)
  k_conv1<<<1568, 192, 0, stream>>>(f_, m_, wt1f, t1);
  k_bnstats<<<192, 256, 0, stream>>>(t1, 192, offf_g1, offf_b1, a1v, b1v);
  k_conv2<<<1568, 96, 0, stream>>>(t1, a1v, b1v, wt2f, t2);
  k_bnstats<<<96, 256, 0, stream>>>(t2, 96, offf_g2, offf_b2, a2v, b2v);
  k_flow<<<LTOT, 96, 0, stream>>>(t2, a2v, b2v, offf_w3, flowf);
  // deformable warp
  k_warp<<<LTOT, 192, 0, stream>>>(m_, flowm, dmov);
  k_warp<<<LTOT, 192, 0, stream>>>(f_, flowf, dfix);
  // windowed projections (roll folded into gather)
  const float scale = 0.17677669529663687f; // 32^-0.5
  k_qkv<<<1372, 192, 0, stream>>>(dmov, mq_w,  mq_b,  QM, scale);   // dmQ
  k_qkv<<<1372, 192, 0, stream>>>(dfix, fq_w,  fq_b,  QF, scale);   // dfQ
  k_qkv<<<1372, 192, 0, stream>>>(m_, mkv_w,          mkv_b,     Km, 1.f);
  k_qkv<<<1372, 192, 0, stream>>>(m_, mkv_w+192*192,  mkv_b+192, Vm, 1.f);
  k_qkv<<<1372, 192, 0, stream>>>(f_, fkv_w,          fkv_b,     Kf, 1.f);
  k_qkv<<<1372, 192, 0, stream>>>(f_, fkv_w+192*192,  fkv_b+192, Vf, 1.f);
  // attention: mo = attend(dfQ, mK, mV); fo = attend(dmQ, fK, fV)
  k_attend<<<384, 256, 0, stream>>>(QF, Km, Vm, ctxm, rpbt);
  k_attend<<<384, 256, 0, stream>>>(QM, Kf, Vf, ctxf, rpbt);
  // proj + residual + window-reverse/unroll
  k_proj<<<1372, 192, 0, stream>>>(ctxm, mproj_w, mproj_b, mov, mout);
  k_proj<<<1372, 192, 0, stream>>>(ctxf, fproj_w, fproj_b, fix, fout);
  // MLP (mov half): LN -> fc1+gelu -> fc2+residual
  k_ln1<<<LTOT, 64, 0, stream>>>(mout, n2g, n2b, lnbuf);
  k_fc1<<<1372, 384, 0, stream>>>(lnbuf, fc1_w, fc1_b, hsbuf);
  k_fc2<<<1372, 192, 0, stream>>>(hsbuf, fc2_w, fc2_b, mout, outp);
  // MLP (fix half)
  k_ln1<<<LTOT, 64, 0, stream>>>(fout, n2g, n2b, lnbuf);
  k_fc1<<<1372, 384, 0, stream>>>(lnbuf, fc1_w, fc1_b, hsbuf);
  k_fc2<<<1372, 192, 0, stream>>>(hsbuf, fc2_w, fc2_b, fout, outp + L192);
}

// Round 4
// 3902.173 us; speedup vs baseline: 4.3283x; 2.6212x over previous
//
#include <hip/hip_runtime.h>

#define LTOT 21952      // 28^3
#define NTOK 343        // 7^3

typedef unsigned short u16;
typedef unsigned int   u32;
typedef __attribute__((ext_vector_type(8))) short short8;
typedef __attribute__((ext_vector_type(4))) float float4v;

__device__ __forceinline__ u16 f2b(float f){
  u32 x = __float_as_uint(f);
  u32 r = (x + 0x7fffu + ((x>>16)&1u)) >> 16;
  return (u16)r;
}

// ---------------- LayerNorm (norm1) : f32 in -> f32 out --------------------
__global__ __launch_bounds__(64) void k_ln(const float* __restrict__ mov, const float* __restrict__ fix,
                                           const float* __restrict__ g, const float* __restrict__ b,
                                           float* __restrict__ om, float* __restrict__ of){
  int row = blockIdx.x;
  const float* src; float* dst;
  if (row < LTOT){ src = mov + (size_t)row*192; dst = om + (size_t)row*192; }
  else          { src = fix + (size_t)(row-LTOT)*192; dst = of + (size_t)(row-LTOT)*192; }
  int t = threadIdx.x;
  float x0 = src[t], x1 = src[t+64], x2 = src[t+128];
  float s = x0+x1+x2, s2 = x0*x0 + x1*x1 + x2*x2;
  for (int o=32;o;o>>=1){ s += __shfl_xor(s,o); s2 += __shfl_xor(s2,o); }
  float mu = s*(1.f/192.f);
  float var = s2*(1.f/192.f) - mu*mu;
  float rs = rsqrtf(var + 1e-5f);
  dst[t]     = (x0-mu)*rs*g[t]     + b[t];
  dst[t+64]  = (x1-mu)*rs*g[t+64]  + b[t+64];
  dst[t+128] = (x2-mu)*rs*g[t+128] + b[t+128];
}

// ---------------- LayerNorm (norm2), single buffer -------------------------
__global__ __launch_bounds__(64) void k_ln1(const float* __restrict__ x,
                                            const float* __restrict__ g, const float* __restrict__ b,
                                            float* __restrict__ y){
  int row = blockIdx.x;
  const float* src = x + (size_t)row*192;
  float* dst = y + (size_t)row*192;
  int t = threadIdx.x;
  float x0 = src[t], x1 = src[t+64], x2 = src[t+128];
  float s = x0+x1+x2, s2 = x0*x0 + x1*x1 + x2*x2;
  for (int o=32;o;o>>=1){ s += __shfl_xor(s,o); s2 += __shfl_xor(s2,o); }
  float mu = s*(1.f/192.f);
  float var = s2*(1.f/192.f) - mu*mu;
  float rs = rsqrtf(var + 1e-5f);
  dst[t]     = (x0-mu)*rs*g[t]     + b[t];
  dst[t+64]  = (x1-mu)*rs*g[t+64]  + b[t+64];
  dst[t+128] = (x2-mu)*rs*g[t+128] + b[t+128];
}

// ------ conv1 weight prep: (192,384,27) f32 -> [n][t*384+c] bf16 -----------
__global__ void k_prepw1b(const float* __restrict__ src, u16* __restrict__ dst, int swap){
  int idx = blockIdx.x*256 + threadIdx.x;
  if (idx >= 192*10368) return;
  int n = idx / 10368; int k = idx - n*10368;
  int t = k / 384; int c = k - t*384;
  int cs = c + swap; if (cs >= 384) cs -= 384;
  dst[idx] = f2b(src[((size_t)n*384 + cs)*27 + t]);
}
// ------ conv2 weight prep: (96,192,27) f32 -> [n][t*192+c] bf16 ------------
__global__ void k_prepw2b(const float* __restrict__ src, u16* __restrict__ dst){
  int idx = blockIdx.x*256 + threadIdx.x;
  if (idx >= 96*5184) return;
  int n = idx / 5184; int k = idx - n*5184;
  int t = k / 192; int c = k - t*192;
  dst[idx] = f2b(src[((size_t)n*192 + c)*27 + t]);
}

// ------ padded volume builders (30^3, zero borders), bf16 ------------------
__global__ __launch_bounds__(192) void k_pad1(const float* __restrict__ m_, const float* __restrict__ f_,
                                              u16* __restrict__ xp){
  int p = blockIdx.x; int t = threadIdx.x;
  int pd = p/900; int r = p - pd*900; int ph = r/30; int pw = r - ph*30;
  int d = pd-1, h = ph-1, w = pw-1;
  u16 vm = 0, vf = 0;
  if ((unsigned)d < 28u && (unsigned)h < 28u && (unsigned)w < 28u){
    size_t l = (size_t)((d*28+h)*28+w)*192 + t;
    vm = f2b(m_[l]); vf = f2b(f_[l]);
  }
  xp[(size_t)p*384 + t] = vm;
  xp[(size_t)p*384 + 192 + t] = vf;
}
__global__ __launch_bounds__(192) void k_pad2(const float* __restrict__ t1,
                                              const float* __restrict__ a1, const float* __restrict__ b1,
                                              u16* __restrict__ xp2){
  int p = blockIdx.x; int t = threadIdx.x;
  int pd = p/900; int r = p - pd*900; int ph = r/30; int pw = r - ph*30;
  int d = pd-1, h = ph-1, w = pw-1;
  u16 v = 0;
  if ((unsigned)d < 28u && (unsigned)h < 28u && (unsigned)w < 28u){
    float xv = t1[(size_t)((d*28+h)*28+w)*192 + t];
    v = f2b(fmaxf(xv*a1[t] + b1[t], 0.f));
  }
  xp2[(size_t)p*192 + t] = v;
}

// ------ implicit-GEMM MFMA conv 3x3x3 on padded bf16 volume ----------------
// xp: [30^3][CIN] bf16 (zero borders); wt: [COUT][27*CIN] bf16; out: [L][COUT] f32
// block: 64 voxels x COUT, 256 thr (4 waves: wave = (m-half 32) x (n-half COUT/2))
template<int CIN, int COUT>
__global__ __launch_bounds__(256) void k_convmfma(const u16* __restrict__ xp,
                                                  const u16* __restrict__ wt,
                                                  float* __restrict__ out){
  constexpr int K = 27*CIN;
  constexpr int CH = CIN/32;          // chunks per tap
  constexpr int STEPS = 27*CH;
  constexpr int NT2 = COUT/32;        // N-tiles per wave
  __shared__ __align__(16) u16 As[2][64*40];
  __shared__ __align__(16) u16 Bs[2][COUT*40];
  int tid = threadIdx.x;
  int wave = tid>>6, lane = tid&63;
  int lm = lane&15, lq = lane>>4;
  int v0 = blockIdx.x*64;
  // A staging: one 16B load per thread per step
  int sv = tid>>2;                    // voxel slot 0..63
  int sc8 = (tid&3)*8;                // chunk sub-offset (bf16)
  int av = v0 + sv;
  int d = av/784; int rm2 = av - d*784; int hh = rm2/28; int ww = rm2 - hh*28;
  int pbase = (d*30 + hh)*30 + ww;    // corner (tap 0) in padded raster
  int mbase = (wave>>1)*32;
  int nbase = (wave&1)*(COUT/2);

  float4v acc[2][NT2];
  #pragma unroll
  for (int mt=0; mt<2; mt++)
    #pragma unroll
    for (int nt=0; nt<NT2; nt++) acc[mt][nt] = (float4v)0.f;

  auto stage = [&](int buf, int s){
    int t = s/CH, cc = s - t*CH;
    int td = t/9; int tr = t - td*9; int th = tr/3; int tw = tr - th*3;
    int toff = td*900 + th*30 + tw;
    // A
    {
      uint4 val = *(const uint4*)(xp + (size_t)(pbase + toff)*CIN + cc*32 + sc8);
      *(uint4*)(&As[buf][sv*40 + sc8]) = val;
    }
    // B
    #pragma unroll
    for (int bi = tid; bi < COUT*4; bi += 256){
      int n = bi>>2, c8 = (bi&3)*8;
      uint4 val = *(const uint4*)(wt + (size_t)n*K + t*CIN + cc*32 + c8);
      *(uint4*)(&Bs[buf][n*40 + c8]) = val;
    }
  };

  stage(0, 0);
  __syncthreads();
  for (int s = 0; s < STEPS; s++){
    if (s+1 < STEPS) stage((s+1)&1, s+1);
    int buf = s&1;
    short8 a0 = *(const short8*)(&As[buf][(mbase + lm)*40 + lq*8]);
    short8 a1 = *(const short8*)(&As[buf][(mbase + 16 + lm)*40 + lq*8]);
    short8 bfr[NT2];
    #pragma unroll
    for (int nt=0; nt<NT2; nt++)
      bfr[nt] = *(const short8*)(&Bs[buf][(nbase + nt*16 + lm)*40 + lq*8]);
    #pragma unroll
    for (int nt=0; nt<NT2; nt++){
      acc[0][nt] = __builtin_amdgcn_mfma_f32_16x16x32_bf16(a0, bfr[nt], acc[0][nt], 0, 0, 0);
      acc[1][nt] = __builtin_amdgcn_mfma_f32_16x16x32_bf16(a1, bfr[nt], acc[1][nt], 0, 0, 0);
    }
    __syncthreads();
  }
  // C/D: col = lane&15 (n), row = lq*4 + r (m)
  #pragma unroll
  for (int mt=0; mt<2; mt++)
    #pragma unroll
    for (int nt=0; nt<NT2; nt++)
      #pragma unroll
      for (int r=0; r<4; r++){
        int row = v0 + mbase + mt*16 + lq*4 + r;
        int col = nbase + nt*16 + lm;
        out[(size_t)row*COUT + col] = acc[mt][nt][r];
      }
}

// per-channel BN stats -> fused scale/shift (a*x+b)
__global__ __launch_bounds__(256) void k_bnstats(const float* __restrict__ x, int C,
                                                 const float* __restrict__ g, const float* __restrict__ b,
                                                 float* __restrict__ a_out, float* __restrict__ b_out){
  int c = blockIdx.x;
  float s=0.f, s2=0.f;
  for (int l = threadIdx.x; l < LTOT; l += 256){
    float v = x[(size_t)l*C + c]; s += v; s2 += v*v;
  }
  for (int o=32;o;o>>=1){ s += __shfl_xor(s,o); s2 += __shfl_xor(s2,o); }
  __shared__ float rs_[4], rs2_[4];
  int wv = threadIdx.x>>6;
  if ((threadIdx.x&63)==0){ rs_[wv]=s; rs2_[wv]=s2; }
  __syncthreads();
  if (threadIdx.x==0){
    s = rs_[0]+rs_[1]+rs_[2]+rs_[3]; s2 = rs2_[0]+rs2_[1]+rs2_[2]+rs2_[3];
    float mu = s/(float)LTOT;
    float var = s2/(float)LTOT - mu*mu;
    float rstd = rsqrtf(var + 1e-5f);
    float aa = rstd * g[c];
    a_out[c] = aa;
    b_out[c] = b[c] - mu*aa;
  }
}

// ------------- conv3 1x1x1: 96 -> 18 flow channels, layout (18, L) ---------
__global__ __launch_bounds__(96) void k_flow(const float* __restrict__ t2,
                                             const float* __restrict__ a2, const float* __restrict__ b2,
                                             const float* __restrict__ w3, float* __restrict__ flow){
  __shared__ float xr[96];
  int l = blockIdx.x; int t = threadIdx.x;
  float xv = t2[(size_t)l*96 + t];
  xr[t] = fmaxf(xv*a2[t] + b2[t], 0.f);
  __syncthreads();
  if (t < 18){
    float acc = 0.f;
    for (int c=0;c<96;c++) acc += xr[c]*w3[t*96 + c];
    flow[(size_t)t*LTOT + l] = acc;
  }
}

// ------------- trilinear warp (per-head flow), border clamp ----------------
__global__ __launch_bounds__(192) void k_warp(const float* __restrict__ src,
                                              const float* __restrict__ flow, float* __restrict__ dst){
  int l = blockIdx.x; int tid = threadIdx.x; int hh = tid>>5;
  int d = l/784; int rm = l - d*784; int y = rm/28; int x = rm - y*28;
  float fd = flow[(size_t)(hh*3+0)*LTOT + l];
  float fy = flow[(size_t)(hh*3+1)*LTOT + l];
  float fx = flow[(size_t)(hh*3+2)*LTOT + l];
  float cd = fminf(fmaxf((float)d + fd, 0.f), 27.f);
  float cy = fminf(fmaxf((float)y + fy, 0.f), 27.f);
  float cx = fminf(fmaxf((float)x + fx, 0.f), 27.f);
  int d0 = (int)floorf(cd); int d1 = min(d0+1, 27);
  int y0 = (int)floorf(cy); int y1 = min(y0+1, 27);
  int x0 = (int)floorf(cx); int x1 = min(x0+1, 27);
  float wd = cd - (float)d0, wy = cy - (float)y0, wx = cx - (float)x0;
  #define SMP(di,yi,xi) src[(size_t)(((di)*28+(yi))*28+(xi))*192 + tid]
  float v000 = SMP(d0,y0,x0), v001 = SMP(d0,y0,x1), v010 = SMP(d0,y1,x0), v011 = SMP(d0,y1,x1);
  float v100 = SMP(d1,y0,x0), v101 = SMP(d1,y0,x1), v110 = SMP(d1,y1,x0), v111 = SMP(d1,y1,x1);
  #undef SMP
  float o = v000*(1-wd)*(1-wy)*(1-wx) + v001*(1-wd)*(1-wy)*wx
          + v010*(1-wd)*wy*(1-wx)     + v011*(1-wd)*wy*wx
          + v100*wd*(1-wy)*(1-wx)     + v101*wd*(1-wy)*wx
          + v110*wd*wy*(1-wx)         + v111*wd*wy*wx;
  dst[(size_t)l*192 + tid] = o;
}

// ------- windowed GEMV: out[(w*6+h)*343+n][c] = (A[roll-map]*W^T + b)*scale -
__global__ __launch_bounds__(192) void k_qkv(const float* __restrict__ A,
                                             const float* __restrict__ Wt, const float* __restrict__ bias,
                                             float* __restrict__ outp, float scale){
  __shared__ float xs[16*192];
  __shared__ int lsrc[16];
  int tid = threadIdx.x; int r0 = blockIdx.x*16;
  if (tid < 16){
    int r = r0 + tid; int w = r/343; int n = r - w*343;
    int nd = w>>4, nh = (w>>2)&3, nw = w&3;
    int i = n/49; int rr = n - i*49; int j = rr/7; int k = rr - j*7;
    int dd = nd*7 + i + 3; if (dd >= 28) dd -= 28;
    int hh = nh*7 + j + 3; if (hh >= 28) hh -= 28;
    int ww = nw*7 + k + 3; if (ww >= 28) ww -= 28;
    lsrc[tid] = (dd*28 + hh)*28 + ww;
  }
  __syncthreads();
  #pragma unroll
  for (int it=0; it<16; it++) xs[it*192 + tid] = A[(size_t)lsrc[it]*192 + tid];
  __syncthreads();
  float acc[16];
  #pragma unroll
  for (int u=0;u<16;u++) acc[u]=0.f;
  const float4* wrow = (const float4*)(Wt + (size_t)tid*192);
  for (int kc=0; kc<24; kc++){
    float4 wa = wrow[kc*2], wbv = wrow[kc*2+1];
    #pragma unroll
    for (int rr2=0; rr2<16; rr2++){
      const float4* xp = (const float4*)(xs + rr2*192 + kc*8);
      float4 x0 = xp[0], x1 = xp[1];
      acc[rr2] += x0.x*wa.x + x0.y*wa.y + x0.z*wa.z + x0.w*wa.w
                + x1.x*wbv.x + x1.y*wbv.y + x1.z*wbv.z + x1.w*wbv.w;
    }
  }
  float bb = bias[tid];
  int h = tid>>5, c = tid&31;
  #pragma unroll
  for (int rr2=0; rr2<16; rr2++){
    int r = r0 + rr2; int w = r/343; int n = r - w*343;
    outp[((size_t)(w*6 + h)*343 + n)*32 + c] = (acc[rr2] + bb)*scale;
  }
}

// ------------ attention: per (window, head), online softmax ----------------
__device__ __forceinline__ int seg3(int nd, int i){ return (nd==3) ? ((i<4)?1:2) : 0; }

__global__ __launch_bounds__(256) void k_attend(const float* __restrict__ Q,
                                                const float* __restrict__ K, const float* __restrict__ V,
                                                float* __restrict__ ctx, const float* __restrict__ rpt){
  __shared__ float kl[NTOK*32];
  int wh = blockIdx.x; int w = wh/6, h = wh - w*6;
  int tid = threadIdx.x;
  const float* kb = K + (size_t)wh*10976;
  for (int idx=tid; idx<10976; idx+=256) kl[idx] = kb[idx];
  __syncthreads();
  int nd = w>>4, nh = (w>>2)&3, nw = w&3;
  const float* vb = V + (size_t)wh*10976;
  for (int rep=0; rep<2; rep++){
    int n = tid + rep*256;
    if (n >= NTOK) break;
    float q[32];
    {
      const float4* qp = (const float4*)(Q + (size_t)wh*10976 + n*32);
      #pragma unroll
      for (int u=0;u<8;u++){ float4 t4 = qp[u]; q[u*4]=t4.x; q[u*4+1]=t4.y; q[u*4+2]=t4.z; q[u*4+3]=t4.w; }
    }
    int i1 = n/49; int r1 = n - i1*49; int j1 = r1/7; int k1 = r1 - j1*7;
    int lab1 = seg3(nd,i1)*9 + seg3(nh,j1)*3 + seg3(nw,k1);
    float mx = -1e30f, sm = 0.f;
    int i2=0, j2=0, k2=0;
    for (int m=0;m<NTOK;m++){
      const float4* kp = (const float4*)(kl + m*32);
      float s = 0.f;
      #pragma unroll
      for (int u=0;u<8;u++){ float4 kk = kp[u];
        s += q[u*4]*kk.x + q[u*4+1]*kk.y + q[u*4+2]*kk.z + q[u*4+3]*kk.w; }
      int ridx = ((i1-i2+6)*13 + (j1-j2+6))*13 + (k1-k2+6);
      s += rpt[ridx*6 + h];
      int lab2 = seg3(nd,i2)*9 + seg3(nh,j2)*3 + seg3(nw,k2);
      s += (lab2==lab1) ? 0.f : -100.f;
      float nm = fmaxf(mx, s);
      sm = sm*__expf(mx-nm) + __expf(s-nm);
      mx = nm;
      k2++; if (k2==7){ k2=0; j2++; if (j2==7){ j2=0; i2++; } }
    }
    float inv = 1.f/sm;
    float acc[32];
    #pragma unroll
    for (int u=0;u<32;u++) acc[u]=0.f;
    i2=0; j2=0; k2=0;
    for (int m=0;m<NTOK;m++){
      const float4* kp = (const float4*)(kl + m*32);
      float s = 0.f;
      #pragma unroll
      for (int u=0;u<8;u++){ float4 kk = kp[u];
        s += q[u*4]*kk.x + q[u*4+1]*kk.y + q[u*4+2]*kk.z + q[u*4+3]*kk.w; }
      int ridx = ((i1-i2+6)*13 + (j1-j2+6))*13 + (k1-k2+6);
      s += rpt[ridx*6 + h];
      int lab2 = seg3(nd,i2)*9 + seg3(nh,j2)*3 + seg3(nw,k2);
      s += (lab2==lab1) ? 0.f : -100.f;
      float p = __expf(s-mx)*inv;
      const float4* vp = (const float4*)(vb + m*32);
      #pragma unroll
      for (int u=0;u<8;u++){ float4 vv = vp[u];
        acc[u*4] += p*vv.x; acc[u*4+1] += p*vv.y; acc[u*4+2] += p*vv.z; acc[u*4+3] += p*vv.w; }
      k2++; if (k2==7){ k2=0; j2++; if (j2==7){ j2=0; i2++; } }
    }
    float4* o4 = (float4*)(ctx + ((size_t)(w*NTOK + n))*192 + h*32);
    #pragma unroll
    for (int u=0;u<8;u++){ float4 t4; t4.x=acc[u*4]; t4.y=acc[u*4+1]; t4.z=acc[u*4+2]; t4.w=acc[u*4+3]; o4[u]=t4; }
  }
}

// ---- proj + residual + window-reverse/unroll: out f32 (L,192) -------------
__global__ __launch_bounds__(192) void k_proj(const float* __restrict__ ctx,
                                              const float* __restrict__ Wt, const float* __restrict__ bias,
                                              const float* __restrict__ resid, float* __restrict__ outp){
  __shared__ float xs[16*192];
  __shared__ int lsrc[16];
  int tid = threadIdx.x; int r0 = blockIdx.x*16;
  if (tid < 16){
    int l = r0 + tid;
    int d = l/784; int rm = l - d*784; int y = rm/28; int x = rm - y*28;
    int dp = d-3; if (dp<0) dp+=28;
    int yp = y-3; if (yp<0) yp+=28;
    int xp = x-3; if (xp<0) xp+=28;
    int nd = dp/7, i = dp - nd*7;
    int nh = yp/7, j = yp - nh*7;
    int nw = xp/7, k = xp - nw*7;
    lsrc[tid] = ((nd*4+nh)*4+nw)*NTOK + (i*7+j)*7 + k;
  }
  __syncthreads();
  #pragma unroll
  for (int it=0; it<16; it++) xs[it*192 + tid] = ctx[(size_t)lsrc[it]*192 + tid];
  __syncthreads();
  float acc[16];
  #pragma unroll
  for (int u=0;u<16;u++) acc[u]=0.f;
  const float4* wrow = (const float4*)(Wt + (size_t)tid*192);
  for (int kc=0; kc<24; kc++){
    float4 wa = wrow[kc*2], wbv = wrow[kc*2+1];
    #pragma unroll
    for (int rr2=0; rr2<16; rr2++){
      const float4* xp = (const float4*)(xs + rr2*192 + kc*8);
      float4 x0 = xp[0], x1 = xp[1];
      acc[rr2] += x0.x*wa.x + x0.y*wa.y + x0.z*wa.z + x0.w*wa.w
                + x1.x*wbv.x + x1.y*wbv.y + x1.z*wbv.z + x1.w*wbv.w;
    }
  }
  float bb = bias[tid];
  #pragma unroll
  for (int rr2=0; rr2<16; rr2++){
    size_t o = (size_t)(r0 + rr2)*192 + tid;
    outp[o] = acc[rr2] + bb + resid[o];
  }
}

// ------- fc1 + gelu: x_ln [L,192] -> hs [L,768], 16-token tiles ------------
__global__ __launch_bounds__(384) void k_fc1(const float* __restrict__ xin,
                                             const float* __restrict__ w1, const float* __restrict__ b1,
                                             float* __restrict__ hs){
  __shared__ float xs[16*192];
  int tid = threadIdx.x; int l0 = blockIdx.x*16;
  for (int idx=tid; idx<16*192; idx+=384) xs[idx] = xin[(size_t)l0*192 + idx];
  __syncthreads();
  float a0[16], a1[16];
  #pragma unroll
  for (int t=0;t<16;t++){ a0[t]=0.f; a1[t]=0.f; }
  int j0 = tid, j1 = tid + 384;
  const float4* wr0 = (const float4*)(w1 + (size_t)j0*192);
  const float4* wr1 = (const float4*)(w1 + (size_t)j1*192);
  for (int kc=0; kc<48; kc++){
    float4 wa = wr0[kc], wb = wr1[kc];
    #pragma unroll
    for (int t=0;t<16;t++){
      const float4* xp = (const float4*)(xs + t*192 + kc*4);
      float4 x4 = xp[0];
      a0[t] += x4.x*wa.x + x4.y*wa.y + x4.z*wa.z + x4.w*wa.w;
      a1[t] += x4.x*wb.x + x4.y*wb.y + x4.z*wb.z + x4.w*wb.w;
    }
  }
  float bv0 = b1[j0], bv1 = b1[j1];
  #pragma unroll
  for (int t=0;t<16;t++){
    float v0 = a0[t] + bv0, v1 = a1[t] + bv1;
    hs[(size_t)(l0+t)*768 + j0] = 0.5f*v0*(1.f + erff(v0*0.70710678118f));
    hs[(size_t)(l0+t)*768 + j1] = 0.5f*v1*(1.f + erff(v1*0.70710678118f));
  }
}

// ------- fc2 + residual: hs [L,768] -> out [L,192] (adds resid) ------------
__global__ __launch_bounds__(192) void k_fc2(const float* __restrict__ hs,
                                             const float* __restrict__ w2, const float* __restrict__ b2,
                                             const float* __restrict__ resid, float* __restrict__ outp){
  __shared__ float hl[16*768];
  int tid = threadIdx.x; int l0 = blockIdx.x*16;
  for (int idx=tid; idx<16*768; idx+=192) hl[idx] = hs[(size_t)l0*768 + idx];
  __syncthreads();
  float acc[16];
  #pragma unroll
  for (int t=0;t<16;t++) acc[t]=0.f;
  const float4* wr = (const float4*)(w2 + (size_t)tid*768);
  for (int kc=0; kc<192; kc++){
    float4 wa = wr[kc];
    #pragma unroll
    for (int t=0;t<16;t++){
      const float4* hp = (const float4*)(hl + t*768 + kc*4);
      float4 h4 = hp[0];
      acc[t] += h4.x*wa.x + h4.y*wa.y + h4.z*wa.z + h4.w*wa.w;
    }
  }
  float bb = b2[tid];
  #pragma unroll
  for (int t=0;t<16;t++){
    size_t o = (size_t)(l0+t)*192 + tid;
    outp[o] = acc[t] + bb + resid[o];
  }
}

// ===========================================================================
extern "C" void kernel_launch(void* const* d_in, const int* in_sizes, int n_in,
                              void* d_out, int out_size, void* d_ws, size_t ws_size,
                              hipStream_t stream){
  const float* mov     = (const float*)d_in[0];
  const float* fix     = (const float*)d_in[1];
  const float* n1g     = (const float*)d_in[2];
  const float* n1b     = (const float*)d_in[3];
  const float* offm_w1 = (const float*)d_in[4];
  const float* offm_g1 = (const float*)d_in[5];
  const float* offm_b1 = (const float*)d_in[6];
  const float* offm_w2 = (const float*)d_in[7];
  const float* offm_g2 = (const float*)d_in[8];
  const float* offm_b2 = (const float*)d_in[9];
  const float* offm_w3 = (const float*)d_in[10];
  const float* offf_w1 = (const float*)d_in[11];
  const float* offf_g1 = (const float*)d_in[12];
  const float* offf_b1 = (const float*)d_in[13];
  const float* offf_w2 = (const float*)d_in[14];
  const float* offf_g2 = (const float*)d_in[15];
  const float* offf_b2 = (const float*)d_in[16];
  const float* offf_w3 = (const float*)d_in[17];
  const float* mq_w    = (const float*)d_in[18];
  const float* mkv_w   = (const float*)d_in[19];
  const float* fq_w    = (const float*)d_in[20];
  const float* fkv_w   = (const float*)d_in[21];
  const float* mproj_w = (const float*)d_in[22];
  const float* fproj_w = (const float*)d_in[23];
  const float* mq_b    = (const float*)d_in[24];
  const float* mkv_b   = (const float*)d_in[25];
  const float* fq_b    = (const float*)d_in[26];
  const float* fkv_b   = (const float*)d_in[27];
  const float* mproj_b = (const float*)d_in[28];
  const float* fproj_b = (const float*)d_in[29];
  const float* rpbt    = (const float*)d_in[30];
  const float* n2g     = (const float*)d_in[31];
  const float* n2b     = (const float*)d_in[32];
  const float* fc1_w   = (const float*)d_in[33];
  const float* fc1_b   = (const float*)d_in[34];
  const float* fc2_w   = (const float*)d_in[35];
  const float* fc2_b   = (const float*)d_in[36];
  float* outp = (float*)d_out;

  float* W = (float*)d_ws;
  const size_t L192 = (size_t)LTOT*192;   // 4,214,784 floats per region
  float* m_   = W;
  float* f_   = W + 1*L192;
  float* t1   = W + 2*L192;
  float* t2   = W + 3*L192;
  float* dmov = W + 4*L192;
  float* dfix = W + 5*L192;
  float* QM   = W + 6*L192;
  float* QF   = W + 7*L192;
  float* Kf   = W + 8*L192;
  float* Vf   = W + 9*L192;
  float* Km = t1;  float* Vm = t2;
  float* ctxm = dmov; float* ctxf = dfix;
  float* mout = m_;   float* fout = f_;
  // conv-phase transient aliases:
  float* a1v = QM;        float* b1v = QM + 192;   // BN params (region 6, dead before QM write)
  float* a2v = QM + 384;  float* b2v = QM + 480;
  float* flowm = QF;      float* flowf = QF + (size_t)LTOT*18;  // region 7, dead before QF write
  u16* xp   = (u16*)(W + 4*L192);                 // padded conv1 input (20.7MB, regions 4..5; dead before warp)
  u16* xp2  = (u16*)(W + 5*L192 + 2000000);       // padded conv2 input (10.4MB, region 5 tail)
  u16* wt1m = (u16*)(W + 8*L192);                 // bf16 weights in region 8 (dead before Kf write)
  u16* wt1f = wt1m + 192*10368;
  u16* wt2m = wt1f + 192*10368;
  u16* wt2f = wt2m + 96*5184;
  // MLP-phase aliases (regions 2..5 and 6 dead after k_proj):
  float* hsbuf = t1;
  float* lnbuf = QM;

  // weight prep (bf16, [cout][27*cin]; fixed conv gets channel-swapped cin)
  k_prepw1b<<<(192*10368+255)/256, 256, 0, stream>>>(offm_w1, wt1m, 0);
  k_prepw1b<<<(192*10368+255)/256, 256, 0, stream>>>(offf_w1, wt1f, 192);
  k_prepw2b<<<(96*5184+255)/256, 256, 0, stream>>>(offm_w2, wt2m);
  k_prepw2b<<<(96*5184+255)/256, 256, 0, stream>>>(offf_w2, wt2f);
  // layernorm1
  k_ln<<<2*LTOT, 64, 0, stream>>>(mov, fix, n1g, n1b, m_, f_);
  // padded bf16 volume [m|f] (serves both conv1 calls)
  k_pad1<<<27000, 192, 0, stream>>>(m_, f_, xp);
  // offset block (moving)
  k_convmfma<384,192><<<343, 256, 0, stream>>>(xp, wt1m, t1);
  k_bnstats<<<192, 256, 0, stream>>>(t1, 192, offm_g1, offm_b1, a1v, b1v);
  k_pad2<<<27000, 192, 0, stream>>>(t1, a1v, b1v, xp2);
  k_convmfma<192,96><<<343, 256, 0, stream>>>(xp2, wt2m, t2);
  k_bnstats<<<96, 256, 0, stream>>>(t2, 96, offm_g2, offm_b2, a2v, b2v);
  k_flow<<<LTOT, 96, 0, stream>>>(t2, a2v, b2v, offm_w3, flowm);
  // offset block (fixed)
  k_convmfma<384,192><<<343, 256, 0, stream>>>(xp, wt1f, t1);
  k_bnstats<<<192, 256, 0, stream>>>(t1, 192, offf_g1, offf_b1, a1v, b1v);
  k_pad2<<<27000, 192, 0, stream>>>(t1, a1v, b1v, xp2);
  k_convmfma<192,96><<<343, 256, 0, stream>>>(xp2, wt2f, t2);
  k_bnstats<<<96, 256, 0, stream>>>(t2, 96, offf_g2, offf_b2, a2v, b2v);
  k_flow<<<LTOT, 96, 0, stream>>>(t2, a2v, b2v, offf_w3, flowf);
  // deformable warp (xp/xp2 dead now)
  k_warp<<<LTOT, 192, 0, stream>>>(m_, flowm, dmov);
  k_warp<<<LTOT, 192, 0, stream>>>(f_, flowf, dfix);
  // windowed projections (roll folded into gather)
  const float scale = 0.17677669529663687f; // 32^-0.5
  k_qkv<<<1372, 192, 0, stream>>>(dmov, mq_w,  mq_b,  QM, scale);   // dmQ
  k_qkv<<<1372, 192, 0, stream>>>(dfix, fq_w,  fq_b,  QF, scale);   // dfQ
  k_qkv<<<1372, 192, 0, stream>>>(m_, mkv_w,          mkv_b,     Km, 1.f);
  k_qkv<<<1372, 192, 0, stream>>>(m_, mkv_w+192*192,  mkv_b+192, Vm, 1.f);
  k_qkv<<<1372, 192, 0, stream>>>(f_, fkv_w,          fkv_b,     Kf, 1.f);
  k_qkv<<<1372, 192, 0, stream>>>(f_, fkv_w+192*192,  fkv_b+192, Vf, 1.f);
  // attention: mo = attend(dfQ, mK, mV); fo = attend(dmQ, fK, fV)
  k_attend<<<384, 256, 0, stream>>>(QF, Km, Vm, ctxm, rpbt);
  k_attend<<<384, 256, 0, stream>>>(QM, Kf, Vf, ctxf, rpbt);
  // proj + residual + window-reverse/unroll
  k_proj<<<1372, 192, 0, stream>>>(ctxm, mproj_w, mproj_b, mov, mout);
  k_proj<<<1372, 192, 0, stream>>>(ctxf, fproj_w, fproj_b, fix, fout);
  // MLP (mov half): LN -> fc1+gelu -> fc2+residual
  k_ln1<<<LTOT, 64, 0, stream>>>(mout, n2g, n2b, lnbuf);
  k_fc1<<<1372, 384, 0, stream>>>(lnbuf, fc1_w, fc1_b, hsbuf);
  k_fc2<<<1372, 192, 0, stream>>>(hsbuf, fc2_w, fc2_b, mout, outp);
  // MLP (fix half)
  k_ln1<<<LTOT, 64, 0, stream>>>(fout, n2g, n2b, lnbuf);
  k_fc1<<<1372, 384, 0, stream>>>(lnbuf, fc1_w, fc1_b, hsbuf);
  k_fc2<<<1372, 192, 0, stream>>>(hsbuf, fc2_w, fc2_b, fout, outp + L192);
}

// Round 5
// 3389.680 us; speedup vs baseline: 4.9827x; 1.1512x over previous
//
#include <hip/hip_runtime.h>

#define LTOT 21952      // 28^3
#define NTOK 343        // 7^3

typedef unsigned short u16;
typedef unsigned int   u32;
typedef __attribute__((ext_vector_type(8))) short short8;
typedef __attribute__((ext_vector_type(4))) float float4v;

__device__ __forceinline__ u16 f2b(float f){
  u32 x = __float_as_uint(f);
  u32 r = (x + 0x7fffu + ((x>>16)&1u)) >> 16;
  return (u16)r;
}

// ---------------- LayerNorm (norm1) : f32 in -> f32 out --------------------
__global__ __launch_bounds__(64) void k_ln(const float* __restrict__ mov, const float* __restrict__ fix,
                                           const float* __restrict__ g, const float* __restrict__ b,
                                           float* __restrict__ om, float* __restrict__ of){
  int row = blockIdx.x;
  const float* src; float* dst;
  if (row < LTOT){ src = mov + (size_t)row*192; dst = om + (size_t)row*192; }
  else          { src = fix + (size_t)(row-LTOT)*192; dst = of + (size_t)(row-LTOT)*192; }
  int t = threadIdx.x;
  float x0 = src[t], x1 = src[t+64], x2 = src[t+128];
  float s = x0+x1+x2, s2 = x0*x0 + x1*x1 + x2*x2;
  for (int o=32;o;o>>=1){ s += __shfl_xor(s,o); s2 += __shfl_xor(s2,o); }
  float mu = s*(1.f/192.f);
  float var = s2*(1.f/192.f) - mu*mu;
  float rs = rsqrtf(var + 1e-5f);
  dst[t]     = (x0-mu)*rs*g[t]     + b[t];
  dst[t+64]  = (x1-mu)*rs*g[t+64]  + b[t+64];
  dst[t+128] = (x2-mu)*rs*g[t+128] + b[t+128];
}

// ---------------- LayerNorm (norm2), single buffer -------------------------
__global__ __launch_bounds__(64) void k_ln1(const float* __restrict__ x,
                                            const float* __restrict__ g, const float* __restrict__ b,
                                            float* __restrict__ y){
  int row = blockIdx.x;
  const float* src = x + (size_t)row*192;
  float* dst = y + (size_t)row*192;
  int t = threadIdx.x;
  float x0 = src[t], x1 = src[t+64], x2 = src[t+128];
  float s = x0+x1+x2, s2 = x0*x0 + x1*x1 + x2*x2;
  for (int o=32;o;o>>=1){ s += __shfl_xor(s,o); s2 += __shfl_xor(s2,o); }
  float mu = s*(1.f/192.f);
  float var = s2*(1.f/192.f) - mu*mu;
  float rs = rsqrtf(var + 1e-5f);
  dst[t]     = (x0-mu)*rs*g[t]     + b[t];
  dst[t+64]  = (x1-mu)*rs*g[t+64]  + b[t+64];
  dst[t+128] = (x2-mu)*rs*g[t+128] + b[t+128];
}

// ------ conv1 weight prep: (192,384,27) f32 -> [n][t*384+c] bf16 -----------
__global__ void k_prepw1b(const float* __restrict__ src, u16* __restrict__ dst, int swap){
  int idx = blockIdx.x*256 + threadIdx.x;
  if (idx >= 192*10368) return;
  int n = idx / 10368; int k = idx - n*10368;
  int t = k / 384; int c = k - t*384;
  int cs = c + swap; if (cs >= 384) cs -= 384;
  dst[idx] = f2b(src[((size_t)n*384 + cs)*27 + t]);
}
// ------ conv2 weight prep: (96,192,27) f32 -> [n][t*192+c] bf16 ------------
__global__ void k_prepw2b(const float* __restrict__ src, u16* __restrict__ dst){
  int idx = blockIdx.x*256 + threadIdx.x;
  if (idx >= 96*5184) return;
  int n = idx / 5184; int k = idx - n*5184;
  int t = k / 192; int c = k - t*192;
  dst[idx] = f2b(src[((size_t)n*192 + c)*27 + t]);
}

// ------ bias matrix prep: [type 8][head 6][key 352][query 352] f32 ---------
__global__ void k_prepbias(const float* __restrict__ rpt, float* __restrict__ bm){
  int idx = blockIdx.x*256 + threadIdx.x;
  if (idx >= 48*123904) return;
  int th = idx / 123904; int r = idx - th*123904;
  int key = r / 352; int q = r - key*352;
  int type = th / 6; int h = th - type*6;
  float v;
  if (key >= 343 || q >= 343){
    v = -30000.f;
  } else {
    int ki = key/49, kj = (key/7)%7, kk = key%7;
    int qi = q/49,   qj = (q/7)%7,   qk = q%7;
    int ridx = ((qi-ki+6)*13 + (qj-kj+6))*13 + (qk-kk+6);
    float rv = rpt[ridx*6 + h];
    int bd = (type>>2)&1, bh = (type>>1)&1, bw = type&1;
    int lq_ = (bd?((qi<4)?1:2):0)*9 + (bh?((qj<4)?1:2):0)*3 + (bw?((qk<4)?1:2):0);
    int lk_ = (bd?((ki<4)?1:2):0)*9 + (bh?((kj<4)?1:2):0)*3 + (bw?((kk<4)?1:2):0);
    v = rv + ((lq_==lk_) ? 0.f : -100.f);
  }
  bm[idx] = v;
}

// ------ padded volume builders (30^3, zero borders), bf16 ------------------
__global__ __launch_bounds__(192) void k_pad1(const float* __restrict__ m_, const float* __restrict__ f_,
                                              u16* __restrict__ xp){
  int p = blockIdx.x; int t = threadIdx.x;
  int pd = p/900; int r = p - pd*900; int ph = r/30; int pw = r - ph*30;
  int d = pd-1, h = ph-1, w = pw-1;
  u16 vm = 0, vf = 0;
  if ((unsigned)d < 28u && (unsigned)h < 28u && (unsigned)w < 28u){
    size_t l = (size_t)((d*28+h)*28+w)*192 + t;
    vm = f2b(m_[l]); vf = f2b(f_[l]);
  }
  xp[(size_t)p*384 + t] = vm;
  xp[(size_t)p*384 + 192 + t] = vf;
}
__global__ __launch_bounds__(192) void k_pad2(const float* __restrict__ t1,
                                              const float* __restrict__ a1, const float* __restrict__ b1,
                                              u16* __restrict__ xp2){
  int p = blockIdx.x; int t = threadIdx.x;
  int pd = p/900; int r = p - pd*900; int ph = r/30; int pw = r - ph*30;
  int d = pd-1, h = ph-1, w = pw-1;
  u16 v = 0;
  if ((unsigned)d < 28u && (unsigned)h < 28u && (unsigned)w < 28u){
    float xv = t1[(size_t)((d*28+h)*28+w)*192 + t];
    v = f2b(fmaxf(xv*a1[t] + b1[t], 0.f));
  }
  xp2[(size_t)p*192 + t] = v;
}

// ------ implicit-GEMM MFMA conv 3x3x3 on padded bf16 volume ----------------
template<int CIN, int COUT>
__global__ __launch_bounds__(256) void k_convmfma(const u16* __restrict__ xp,
                                                  const u16* __restrict__ wt,
                                                  float* __restrict__ out){
  constexpr int K = 27*CIN;
  constexpr int CH = CIN/32;          // chunks per tap
  constexpr int STEPS = 27*CH;
  constexpr int NT2 = COUT/32;        // N-tiles per wave
  __shared__ __align__(16) u16 As[2][64*40];
  __shared__ __align__(16) u16 Bs[2][COUT*40];
  int tid = threadIdx.x;
  int wave = tid>>6, lane = tid&63;
  int lm = lane&15, lq = lane>>4;
  int v0 = blockIdx.x*64;
  int sv = tid>>2;
  int sc8 = (tid&3)*8;
  int av = v0 + sv;
  int d = av/784; int rm2 = av - d*784; int hh = rm2/28; int ww = rm2 - hh*28;
  int pbase = (d*30 + hh)*30 + ww;
  int mbase = (wave>>1)*32;
  int nbase = (wave&1)*(COUT/2);

  float4v acc[2][NT2];
  #pragma unroll
  for (int mt=0; mt<2; mt++)
    #pragma unroll
    for (int nt=0; nt<NT2; nt++) acc[mt][nt] = (float4v)0.f;

  auto stage = [&](int buf, int s){
    int t = s/CH, cc = s - t*CH;
    int td = t/9; int tr = t - td*9; int th = tr/3; int tw = tr - th*3;
    int toff = td*900 + th*30 + tw;
    {
      uint4 val = *(const uint4*)(xp + (size_t)(pbase + toff)*CIN + cc*32 + sc8);
      *(uint4*)(&As[buf][sv*40 + sc8]) = val;
    }
    #pragma unroll
    for (int bi = tid; bi < COUT*4; bi += 256){
      int n = bi>>2, c8 = (bi&3)*8;
      uint4 val = *(const uint4*)(wt + (size_t)n*K + t*CIN + cc*32 + c8);
      *(uint4*)(&Bs[buf][n*40 + c8]) = val;
    }
  };

  stage(0, 0);
  __syncthreads();
  for (int s = 0; s < STEPS; s++){
    if (s+1 < STEPS) stage((s+1)&1, s+1);
    int buf = s&1;
    short8 a0 = *(const short8*)(&As[buf][(mbase + lm)*40 + lq*8]);
    short8 a1 = *(const short8*)(&As[buf][(mbase + 16 + lm)*40 + lq*8]);
    short8 bfr[NT2];
    #pragma unroll
    for (int nt=0; nt<NT2; nt++)
      bfr[nt] = *(const short8*)(&Bs[buf][(nbase + nt*16 + lm)*40 + lq*8]);
    #pragma unroll
    for (int nt=0; nt<NT2; nt++){
      acc[0][nt] = __builtin_amdgcn_mfma_f32_16x16x32_bf16(a0, bfr[nt], acc[0][nt], 0, 0, 0);
      acc[1][nt] = __builtin_amdgcn_mfma_f32_16x16x32_bf16(a1, bfr[nt], acc[1][nt], 0, 0, 0);
    }
    __syncthreads();
  }
  #pragma unroll
  for (int mt=0; mt<2; mt++)
    #pragma unroll
    for (int nt=0; nt<NT2; nt++)
      #pragma unroll
      for (int r=0; r<4; r++){
        int row = v0 + mbase + mt*16 + lq*4 + r;
        int col = nbase + nt*16 + lm;
        out[(size_t)row*COUT + col] = acc[mt][nt][r];
      }
}

// per-channel BN stats -> fused scale/shift (a*x+b)
__global__ __launch_bounds__(256) void k_bnstats(const float* __restrict__ x, int C,
                                                 const float* __restrict__ g, const float* __restrict__ b,
                                                 float* __restrict__ a_out, float* __restrict__ b_out){
  int c = blockIdx.x;
  float s=0.f, s2=0.f;
  for (int l = threadIdx.x; l < LTOT; l += 256){
    float v = x[(size_t)l*C + c]; s += v; s2 += v*v;
  }
  for (int o=32;o;o>>=1){ s += __shfl_xor(s,o); s2 += __shfl_xor(s2,o); }
  __shared__ float rs_[4], rs2_[4];
  int wv = threadIdx.x>>6;
  if ((threadIdx.x&63)==0){ rs_[wv]=s; rs2_[wv]=s2; }
  __syncthreads();
  if (threadIdx.x==0){
    s = rs_[0]+rs_[1]+rs_[2]+rs_[3]; s2 = rs2_[0]+rs2_[1]+rs2_[2]+rs2_[3];
    float mu = s/(float)LTOT;
    float var = s2/(float)LTOT - mu*mu;
    float rstd = rsqrtf(var + 1e-5f);
    float aa = rstd * g[c];
    a_out[c] = aa;
    b_out[c] = b[c] - mu*aa;
  }
}

// ------------- conv3 1x1x1: 96 -> 18 flow channels, layout (18, L) ---------
__global__ __launch_bounds__(96) void k_flow(const float* __restrict__ t2,
                                             const float* __restrict__ a2, const float* __restrict__ b2,
                                             const float* __restrict__ w3, float* __restrict__ flow){
  __shared__ float xr[96];
  int l = blockIdx.x; int t = threadIdx.x;
  float xv = t2[(size_t)l*96 + t];
  xr[t] = fmaxf(xv*a2[t] + b2[t], 0.f);
  __syncthreads();
  if (t < 18){
    float acc = 0.f;
    for (int c=0;c<96;c++) acc += xr[c]*w3[t*96 + c];
    flow[(size_t)t*LTOT + l] = acc;
  }
}

// ------------- trilinear warp (per-head flow), border clamp ----------------
__global__ __launch_bounds__(192) void k_warp(const float* __restrict__ src,
                                              const float* __restrict__ flow, float* __restrict__ dst){
  int l = blockIdx.x; int tid = threadIdx.x; int hh = tid>>5;
  int d = l/784; int rm = l - d*784; int y = rm/28; int x = rm - y*28;
  float fd = flow[(size_t)(hh*3+0)*LTOT + l];
  float fy = flow[(size_t)(hh*3+1)*LTOT + l];
  float fx = flow[(size_t)(hh*3+2)*LTOT + l];
  float cd = fminf(fmaxf((float)d + fd, 0.f), 27.f);
  float cy = fminf(fmaxf((float)y + fy, 0.f), 27.f);
  float cx = fminf(fmaxf((float)x + fx, 0.f), 27.f);
  int d0 = (int)floorf(cd); int d1 = min(d0+1, 27);
  int y0 = (int)floorf(cy); int y1 = min(y0+1, 27);
  int x0 = (int)floorf(cx); int x1 = min(x0+1, 27);
  float wd = cd - (float)d0, wy = cy - (float)y0, wx = cx - (float)x0;
  #define SMP(di,yi,xi) src[(size_t)(((di)*28+(yi))*28+(xi))*192 + tid]
  float v000 = SMP(d0,y0,x0), v001 = SMP(d0,y0,x1), v010 = SMP(d0,y1,x0), v011 = SMP(d0,y1,x1);
  float v100 = SMP(d1,y0,x0), v101 = SMP(d1,y0,x1), v110 = SMP(d1,y1,x0), v111 = SMP(d1,y1,x1);
  #undef SMP
  float o = v000*(1-wd)*(1-wy)*(1-wx) + v001*(1-wd)*(1-wy)*wx
          + v010*(1-wd)*wy*(1-wx)     + v011*(1-wd)*wy*wx
          + v100*wd*(1-wy)*(1-wx)     + v101*wd*(1-wy)*wx
          + v110*wd*wy*(1-wx)         + v111*wd*wy*wx;
  dst[(size_t)l*192 + tid] = o;
}

// ------- windowed GEMV -> bf16 out: out[(w*6+h)*343+n][c] ------------------
__global__ __launch_bounds__(192) void k_qkv(const float* __restrict__ A,
                                             const float* __restrict__ Wt, const float* __restrict__ bias,
                                             u16* __restrict__ outp, float scale){
  __shared__ float xs[16*192];
  __shared__ int lsrc[16];
  int tid = threadIdx.x; int r0 = blockIdx.x*16;
  if (tid < 16){
    int r = r0 + tid; int w = r/343; int n = r - w*343;
    int nd = w>>4, nh = (w>>2)&3, nw = w&3;
    int i = n/49; int rr = n - i*49; int j = rr/7; int k = rr - j*7;
    int dd = nd*7 + i + 3; if (dd >= 28) dd -= 28;
    int hh = nh*7 + j + 3; if (hh >= 28) hh -= 28;
    int ww = nw*7 + k + 3; if (ww >= 28) ww -= 28;
    lsrc[tid] = (dd*28 + hh)*28 + ww;
  }
  __syncthreads();
  #pragma unroll
  for (int it=0; it<16; it++) xs[it*192 + tid] = A[(size_t)lsrc[it]*192 + tid];
  __syncthreads();
  float acc[16];
  #pragma unroll
  for (int u=0;u<16;u++) acc[u]=0.f;
  const float4* wrow = (const float4*)(Wt + (size_t)tid*192);
  for (int kc=0; kc<24; kc++){
    float4 wa = wrow[kc*2], wbv = wrow[kc*2+1];
    #pragma unroll
    for (int rr2=0; rr2<16; rr2++){
      const float4* xp = (const float4*)(xs + rr2*192 + kc*8);
      float4 x0 = xp[0], x1 = xp[1];
      acc[rr2] += x0.x*wa.x + x0.y*wa.y + x0.z*wa.z + x0.w*wa.w
                + x1.x*wbv.x + x1.y*wbv.y + x1.z*wbv.z + x1.w*wbv.w;
    }
  }
  float bb = bias[tid];
  int h = tid>>5, c = tid&31;
  #pragma unroll
  for (int rr2=0; rr2<16; rr2++){
    int r = r0 + rr2; int w = r/343; int n = r - w*343;
    outp[((size_t)(w*6 + h)*343 + n)*32 + c] = f2b((acc[rr2] + bb)*scale);
  }
}

// ------------ MFMA attention: block = (window, head) -----------------------
// S^T = K*Q^T via 16x16x32 bf16 MFMA; softmax per C-column (query);
// P -> per-wave LDS [query][key] (b64 writes); O^T = V^T * P; f32 ctx out.
__global__ __launch_bounds__(256) void k_attmfma(const u16* __restrict__ Q,
                                                 const u16* __restrict__ K,
                                                 const u16* __restrict__ V,
                                                 const float* __restrict__ bm,
                                                 float* __restrict__ ctx){
  __shared__ __align__(16) u16 Kl[352*40];      // [key][40]
  __shared__ __align__(16) u16 Vt[32*360];      // [dim][360]
  __shared__ __align__(16) u16 Pl[4][2][16*40]; // per-wave, dbuf: [query16][40]
  int wh = blockIdx.x; int w = wh/6, h = wh - w*6;
  int tid = threadIdx.x;
  int nd = w>>4, nh = (w>>2)&3, nw = w&3;
  int type = ((nd==3)?4:0) | ((nh==3)?2:0) | ((nw==3)?1:0);
  const u16* kb = K + (size_t)wh*10976;
  const u16* vbp = V + (size_t)wh*10976;
  // stage K rows
  for (int idx=tid; idx<343*4; idx+=256){
    int row = idx>>2, c8 = (idx&3)*8;
    uint4 val = *(const uint4*)(kb + row*32 + c8);
    *(uint4*)(&Kl[row*40 + c8]) = val;
  }
  for (int idx=tid; idx<9*40; idx+=256) Kl[343*40 + idx] = 0;
  // stage V transposed
  for (int idx=tid; idx<343*4; idx+=256){
    int row = idx>>2, c8 = (idx&3)*8;
    uint4 val = *(const uint4*)(vbp + row*32 + c8);
    const u16* pv = (const u16*)&val;
    #pragma unroll
    for (int j=0;j<8;j++) Vt[(c8+j)*360 + row] = pv[j];
  }
  for (int idx=tid; idx<32*17; idx+=256){
    int dd = idx/17, cc = 343 + idx - (idx/17)*17;
    Vt[dd*360 + cc] = 0;
  }
  __syncthreads();
  int lane = tid&63, wv = tid>>6;
  int lm = lane&15, lq = lane>>4;
  const float* bmh = bm + (size_t)(type*6 + h)*123904;
  for (int qt=wv; qt<22; qt+=4){
    int q0 = qt*16;
    short8 bq = *(const short8*)(Q + (size_t)wh*10976 + (q0+lm)*32 + lq*8);
    float4v sc[22];
    #pragma unroll
    for (int kt=0; kt<22; kt++){
      short8 ak = *(const short8*)(&Kl[(kt*16+lm)*40 + lq*8]);
      sc[kt] = __builtin_amdgcn_mfma_f32_16x16x32_bf16(ak, bq, (float4v)0.f, 0, 0, 0);
    }
    // bias + max (lane: query = q0+lm fixed; keys = kt*16+lq*4+r)
    const float* bcol = bmh + q0 + lm;
    float mx = -3.0e38f;
    #pragma unroll
    for (int kt=0; kt<22; kt++){
      #pragma unroll
      for (int r=0; r<4; r++){
        int key = kt*16 + lq*4 + r;
        float s = sc[kt][r] + bcol[(size_t)key*352];
        sc[kt][r] = s;
        mx = fmaxf(mx, s);
      }
    }
    mx = fmaxf(mx, __shfl_xor(mx, 16));
    mx = fmaxf(mx, __shfl_xor(mx, 32));
    float sm = 0.f;
    #pragma unroll
    for (int kt=0; kt<22; kt++){
      #pragma unroll
      for (int r=0; r<4; r++){
        float p = __expf(sc[kt][r] - mx);
        sc[kt][r] = p;
        sm += p;
      }
    }
    sm += __shfl_xor(sm, 16);
    sm += __shfl_xor(sm, 32);
    float inv = 1.f/sm;
    // PV: O^T = V^T * P, 32-key chunks
    float4v o0 = (float4v)0.f, o1 = (float4v)0.f;
    #pragma unroll
    for (int s=0; s<11; s++){
      u16* pw = &Pl[wv][s&1][0];
      #pragma unroll
      for (int half=0; half<2; half++){
        int kt = 2*s + half;
        uint2 pv2;
        pv2.x = (u32)f2b(sc[kt][0]) | ((u32)f2b(sc[kt][1])<<16);
        pv2.y = (u32)f2b(sc[kt][2]) | ((u32)f2b(sc[kt][3])<<16);
        *(uint2*)(&pw[lm*40 + half*16 + lq*4]) = pv2;
      }
      short8 bp = *(const short8*)(&pw[lm*40 + lq*8]);
      short8 a0 = *(const short8*)(&Vt[lm*360 + s*32 + lq*8]);
      short8 a1 = *(const short8*)(&Vt[(16+lm)*360 + s*32 + lq*8]);
      o0 = __builtin_amdgcn_mfma_f32_16x16x32_bf16(a0, bp, o0, 0, 0, 0);
      o1 = __builtin_amdgcn_mfma_f32_16x16x32_bf16(a1, bp, o1, 0, 0, 0);
    }
    int query = q0 + lm;
    if (query < 343){
      float* ob = ctx + ((size_t)w*NTOK + query)*192 + h*32;
      float4 t0, t1v;
      t0.x = o0[0]*inv; t0.y = o0[1]*inv; t0.z = o0[2]*inv; t0.w = o0[3]*inv;
      t1v.x = o1[0]*inv; t1v.y = o1[1]*inv; t1v.z = o1[2]*inv; t1v.w = o1[3]*inv;
      *(float4*)(ob + lq*4) = t0;
      *(float4*)(ob + 16 + lq*4) = t1v;
    }
  }
}

// ---- proj + residual + window-reverse/unroll: out f32 (L,192) -------------
__global__ __launch_bounds__(192) void k_proj(const float* __restrict__ ctx,
                                              const float* __restrict__ Wt, const float* __restrict__ bias,
                                              const float* __restrict__ resid, float* __restrict__ outp){
  __shared__ float xs[16*192];
  __shared__ int lsrc[16];
  int tid = threadIdx.x; int r0 = blockIdx.x*16;
  if (tid < 16){
    int l = r0 + tid;
    int d = l/784; int rm = l - d*784; int y = rm/28; int x = rm - y*28;
    int dp = d-3; if (dp<0) dp+=28;
    int yp = y-3; if (yp<0) yp+=28;
    int xp = x-3; if (xp<0) xp+=28;
    int nd = dp/7, i = dp - nd*7;
    int nh = yp/7, j = yp - nh*7;
    int nw = xp/7, k = xp - nw*7;
    lsrc[tid] = ((nd*4+nh)*4+nw)*NTOK + (i*7+j)*7 + k;
  }
  __syncthreads();
  #pragma unroll
  for (int it=0; it<16; it++) xs[it*192 + tid] = ctx[(size_t)lsrc[it]*192 + tid];
  __syncthreads();
  float acc[16];
  #pragma unroll
  for (int u=0;u<16;u++) acc[u]=0.f;
  const float4* wrow = (const float4*)(Wt + (size_t)tid*192);
  for (int kc=0; kc<24; kc++){
    float4 wa = wrow[kc*2], wbv = wrow[kc*2+1];
    #pragma unroll
    for (int rr2=0; rr2<16; rr2++){
      const float4* xp = (const float4*)(xs + rr2*192 + kc*8);
      float4 x0 = xp[0], x1 = xp[1];
      acc[rr2] += x0.x*wa.x + x0.y*wa.y + x0.z*wa.z + x0.w*wa.w
                + x1.x*wbv.x + x1.y*wbv.y + x1.z*wbv.z + x1.w*wbv.w;
    }
  }
  float bb = bias[tid];
  #pragma unroll
  for (int rr2=0; rr2<16; rr2++){
    size_t o = (size_t)(r0 + rr2)*192 + tid;
    outp[o] = acc[rr2] + bb + resid[o];
  }
}

// ------- fc1 + gelu: x_ln [L,192] -> hs [L,768], 16-token tiles ------------
__global__ __launch_bounds__(384) void k_fc1(const float* __restrict__ xin,
                                             const float* __restrict__ w1, const float* __restrict__ b1,
                                             float* __restrict__ hs){
  __shared__ float xs[16*192];
  int tid = threadIdx.x; int l0 = blockIdx.x*16;
  for (int idx=tid; idx<16*192; idx+=384) xs[idx] = xin[(size_t)l0*192 + idx];
  __syncthreads();
  float a0[16], a1[16];
  #pragma unroll
  for (int t=0;t<16;t++){ a0[t]=0.f; a1[t]=0.f; }
  int j0 = tid, j1 = tid + 384;
  const float4* wr0 = (const float4*)(w1 + (size_t)j0*192);
  const float4* wr1 = (const float4*)(w1 + (size_t)j1*192);
  for (int kc=0; kc<48; kc++){
    float4 wa = wr0[kc], wb = wr1[kc];
    #pragma unroll
    for (int t=0;t<16;t++){
      const float4* xp = (const float4*)(xs + t*192 + kc*4);
      float4 x4 = xp[0];
      a0[t] += x4.x*wa.x + x4.y*wa.y + x4.z*wa.z + x4.w*wa.w;
      a1[t] += x4.x*wb.x + x4.y*wb.y + x4.z*wb.z + x4.w*wb.w;
    }
  }
  float bv0 = b1[j0], bv1 = b1[j1];
  #pragma unroll
  for (int t=0;t<16;t++){
    float v0 = a0[t] + bv0, v1 = a1[t] + bv1;
    hs[(size_t)(l0+t)*768 + j0] = 0.5f*v0*(1.f + erff(v0*0.70710678118f));
    hs[(size_t)(l0+t)*768 + j1] = 0.5f*v1*(1.f + erff(v1*0.70710678118f));
  }
}

// ------- fc2 + residual: hs [L,768] -> out [L,192] (adds resid) ------------
__global__ __launch_bounds__(192) void k_fc2(const float* __restrict__ hs,
                                             const float* __restrict__ w2, const float* __restrict__ b2,
                                             const float* __restrict__ resid, float* __restrict__ outp){
  __shared__ float hl[16*768];
  int tid = threadIdx.x; int l0 = blockIdx.x*16;
  for (int idx=tid; idx<16*768; idx+=192) hl[idx] = hs[(size_t)l0*768 + idx];
  __syncthreads();
  float acc[16];
  #pragma unroll
  for (int t=0;t<16;t++) acc[t]=0.f;
  const float4* wr = (const float4*)(w2 + (size_t)tid*768);
  for (int kc=0; kc<192; kc++){
    float4 wa = wr[kc];
    #pragma unroll
    for (int t=0;t<16;t++){
      const float4* hp = (const float4*)(hl + t*768 + kc*4);
      float4 h4 = hp[0];
      acc[t] += h4.x*wa.x + h4.y*wa.y + h4.z*wa.z + h4.w*wa.w;
    }
  }
  float bb = b2[tid];
  #pragma unroll
  for (int t=0;t<16;t++){
    size_t o = (size_t)(l0+t)*192 + tid;
    outp[o] = acc[t] + bb + resid[o];
  }
}

// ===========================================================================
extern "C" void kernel_launch(void* const* d_in, const int* in_sizes, int n_in,
                              void* d_out, int out_size, void* d_ws, size_t ws_size,
                              hipStream_t stream){
  const float* mov     = (const float*)d_in[0];
  const float* fix     = (const float*)d_in[1];
  const float* n1g     = (const float*)d_in[2];
  const float* n1b     = (const float*)d_in[3];
  const float* offm_w1 = (const float*)d_in[4];
  const float* offm_g1 = (const float*)d_in[5];
  const float* offm_b1 = (const float*)d_in[6];
  const float* offm_w2 = (const float*)d_in[7];
  const float* offm_g2 = (const float*)d_in[8];
  const float* offm_b2 = (const float*)d_in[9];
  const float* offm_w3 = (const float*)d_in[10];
  const float* offf_w1 = (const float*)d_in[11];
  const float* offf_g1 = (const float*)d_in[12];
  const float* offf_b1 = (const float*)d_in[13];
  const float* offf_w2 = (const float*)d_in[14];
  const float* offf_g2 = (const float*)d_in[15];
  const float* offf_b2 = (const float*)d_in[16];
  const float* offf_w3 = (const float*)d_in[17];
  const float* mq_w    = (const float*)d_in[18];
  const float* mkv_w   = (const float*)d_in[19];
  const float* fq_w    = (const float*)d_in[20];
  const float* fkv_w   = (const float*)d_in[21];
  const float* mproj_w = (const float*)d_in[22];
  const float* fproj_w = (const float*)d_in[23];
  const float* mq_b    = (const float*)d_in[24];
  const float* mkv_b   = (const float*)d_in[25];
  const float* fq_b    = (const float*)d_in[26];
  const float* fkv_b   = (const float*)d_in[27];
  const float* mproj_b = (const float*)d_in[28];
  const float* fproj_b = (const float*)d_in[29];
  const float* rpbt    = (const float*)d_in[30];
  const float* n2g     = (const float*)d_in[31];
  const float* n2b     = (const float*)d_in[32];
  const float* fc1_w   = (const float*)d_in[33];
  const float* fc1_b   = (const float*)d_in[34];
  const float* fc2_w   = (const float*)d_in[35];
  const float* fc2_b   = (const float*)d_in[36];
  float* outp = (float*)d_out;

  float* W = (float*)d_ws;
  const size_t L192 = (size_t)LTOT*192;   // floats per region
  float* m_   = W;
  float* f_   = W + 1*L192;
  float* t1   = W + 2*L192;
  float* t2   = W + 3*L192;
  float* dmov = W + 4*L192;
  float* dfix = W + 5*L192;
  float* ctxm = dmov; float* ctxf = dfix;
  float* mout = m_;   float* fout = f_;
  // bf16 QKV buffers (each 8.43MB in a 16.86MB region)
  u16* QMb = (u16*)(W + 6*L192);
  u16* QFb = (u16*)(W + 7*L192);
  u16* Kmb = (u16*)(W + 2*L192);   // t1 region, after conv phase
  u16* Vmb = (u16*)(W + 3*L192);   // t2 region
  u16* Kfb = (u16*)(W + 8*L192);
  u16* Vfb = (u16*)(W + 9*L192);
  // conv-phase transient aliases:
  float* a1v = W + 6*L192;        float* b1v = a1v + 192;   // region 6 head (dead before QM write)
  float* a2v = a1v + 384;         float* b2v = a1v + 480;
  float* flowm = W + 7*L192;      float* flowf = flowm + (size_t)LTOT*18; // region 7
  u16* xp   = (u16*)(W + 4*L192);             // padded conv1 input (regions 4..5, dead before warp)
  u16* xp2  = (u16*)(W + 5*L192 + 2000000);   // padded conv2 input
  u16* wt1m = (u16*)(W + 8*L192);             // bf16 conv weights (region 8, dead before Kf)
  u16* wt1f = wt1m + 192*10368;
  u16* wt2m = wt1f + 192*10368;
  u16* wt2f = wt2m + 96*5184;
  // attention bias matrix: 48*352*352 f32 = 23.8MB in regions 0..1 (built after
  // last use of m_/f_, dead before k_proj writes mout/fout)
  float* bm = W;
  // MLP-phase aliases (regions 2..5 and 6 dead after k_proj):
  float* hsbuf = t1;
  float* lnbuf = W + 6*L192;

  // conv weight prep
  k_prepw1b<<<(192*10368+255)/256, 256, 0, stream>>>(offm_w1, wt1m, 0);
  k_prepw1b<<<(192*10368+255)/256, 256, 0, stream>>>(offf_w1, wt1f, 192);
  k_prepw2b<<<(96*5184+255)/256, 256, 0, stream>>>(offm_w2, wt2m);
  k_prepw2b<<<(96*5184+255)/256, 256, 0, stream>>>(offf_w2, wt2f);
  // layernorm1
  k_ln<<<2*LTOT, 64, 0, stream>>>(mov, fix, n1g, n1b, m_, f_);
  // padded bf16 volume [m|f]
  k_pad1<<<27000, 192, 0, stream>>>(m_, f_, xp);
  // offset block (moving)
  k_convmfma<384,192><<<343, 256, 0, stream>>>(xp, wt1m, t1);
  k_bnstats<<<192, 256, 0, stream>>>(t1, 192, offm_g1, offm_b1, a1v, b1v);
  k_pad2<<<27000, 192, 0, stream>>>(t1, a1v, b1v, xp2);
  k_convmfma<192,96><<<343, 256, 0, stream>>>(xp2, wt2m, t2);
  k_bnstats<<<96, 256, 0, stream>>>(t2, 96, offm_g2, offm_b2, a2v, b2v);
  k_flow<<<LTOT, 96, 0, stream>>>(t2, a2v, b2v, offm_w3, flowm);
  // offset block (fixed)
  k_convmfma<384,192><<<343, 256, 0, stream>>>(xp, wt1f, t1);
  k_bnstats<<<192, 256, 0, stream>>>(t1, 192, offf_g1, offf_b1, a1v, b1v);
  k_pad2<<<27000, 192, 0, stream>>>(t1, a1v, b1v, xp2);
  k_convmfma<192,96><<<343, 256, 0, stream>>>(xp2, wt2f, t2);
  k_bnstats<<<96, 256, 0, stream>>>(t2, 96, offf_g2, offf_b2, a2v, b2v);
  k_flow<<<LTOT, 96, 0, stream>>>(t2, a2v, b2v, offf_w3, flowf);
  // deformable warp
  k_warp<<<LTOT, 192, 0, stream>>>(m_, flowm, dmov);
  k_warp<<<LTOT, 192, 0, stream>>>(f_, flowf, dfix);
  // windowed projections -> bf16
  const float scale = 0.17677669529663687f; // 32^-0.5
  k_qkv<<<1372, 192, 0, stream>>>(dmov, mq_w,  mq_b,  QMb, scale);   // dmQ
  k_qkv<<<1372, 192, 0, stream>>>(dfix, fq_w,  fq_b,  QFb, scale);   // dfQ
  k_qkv<<<1372, 192, 0, stream>>>(m_, mkv_w,          mkv_b,     Kmb, 1.f);
  k_qkv<<<1372, 192, 0, stream>>>(m_, mkv_w+192*192,  mkv_b+192, Vmb, 1.f);
  k_qkv<<<1372, 192, 0, stream>>>(f_, fkv_w,          fkv_b,     Kfb, 1.f);
  k_qkv<<<1372, 192, 0, stream>>>(f_, fkv_w+192*192,  fkv_b+192, Vfb, 1.f);
  // bias matrix (m_/f_ now dead)
  k_prepbias<<<(48*123904+255)/256, 256, 0, stream>>>(rpbt, bm);
  // attention: mo = attend(dfQ, mK, mV); fo = attend(dmQ, fK, fV)
  k_attmfma<<<384, 256, 0, stream>>>(QFb, Kmb, Vmb, bm, ctxm);
  k_attmfma<<<384, 256, 0, stream>>>(QMb, Kfb, Vfb, bm, ctxf);
  // proj + residual + window-reverse/unroll (overwrites bias matrix regions)
  k_proj<<<1372, 192, 0, stream>>>(ctxm, mproj_w, mproj_b, mov, mout);
  k_proj<<<1372, 192, 0, stream>>>(ctxf, fproj_w, fproj_b, fix, fout);
  // MLP (mov half): LN -> fc1+gelu -> fc2+residual
  k_ln1<<<LTOT, 64, 0, stream>>>(mout, n2g, n2b, lnbuf);
  k_fc1<<<1372, 384, 0, stream>>>(lnbuf, fc1_w, fc1_b, hsbuf);
  k_fc2<<<1372, 192, 0, stream>>>(hsbuf, fc2_w, fc2_b, mout, outp);
  // MLP (fix half)
  k_ln1<<<LTOT, 64, 0, stream>>>(fout, n2g, n2b, lnbuf);
  k_fc1<<<1372, 384, 0, stream>>>(lnbuf, fc1_w, fc1_b, hsbuf);
  k_fc2<<<1372, 192, 0, stream>>>(hsbuf, fc2_w, fc2_b, fout, outp + L192);
}

// Round 6
// 3240.074 us; speedup vs baseline: 5.2128x; 1.0462x over previous
//
#include <hip/hip_runtime.h>

#define LTOT 21952      // 28^3
#define NTOK 343        // 7^3

typedef unsigned short u16;
typedef unsigned int   u32;
typedef __attribute__((ext_vector_type(8))) short short8;
typedef __attribute__((ext_vector_type(4))) float float4v;

__device__ __forceinline__ u16 f2b(float f){
  u32 x = __float_as_uint(f);
  u32 r = (x + 0x7fffu + ((x>>16)&1u)) >> 16;
  return (u16)r;
}

// ---------------- LayerNorm (norm1) : f32 in -> f32 out --------------------
__global__ __launch_bounds__(64) void k_ln(const float* __restrict__ mov, const float* __restrict__ fix,
                                           const float* __restrict__ g, const float* __restrict__ b,
                                           float* __restrict__ om, float* __restrict__ of){
  int row = blockIdx.x;
  const float* src; float* dst;
  if (row < LTOT){ src = mov + (size_t)row*192; dst = om + (size_t)row*192; }
  else          { src = fix + (size_t)(row-LTOT)*192; dst = of + (size_t)(row-LTOT)*192; }
  int t = threadIdx.x;
  float x0 = src[t], x1 = src[t+64], x2 = src[t+128];
  float s = x0+x1+x2, s2 = x0*x0 + x1*x1 + x2*x2;
  for (int o=32;o;o>>=1){ s += __shfl_xor(s,o); s2 += __shfl_xor(s2,o); }
  float mu = s*(1.f/192.f);
  float var = s2*(1.f/192.f) - mu*mu;
  float rs = rsqrtf(var + 1e-5f);
  dst[t]     = (x0-mu)*rs*g[t]     + b[t];
  dst[t+64]  = (x1-mu)*rs*g[t+64]  + b[t+64];
  dst[t+128] = (x2-mu)*rs*g[t+128] + b[t+128];
}

// ---------------- LayerNorm (norm2), single buffer -------------------------
__global__ __launch_bounds__(64) void k_ln1(const float* __restrict__ x,
                                            const float* __restrict__ g, const float* __restrict__ b,
                                            float* __restrict__ y){
  int row = blockIdx.x;
  const float* src = x + (size_t)row*192;
  float* dst = y + (size_t)row*192;
  int t = threadIdx.x;
  float x0 = src[t], x1 = src[t+64], x2 = src[t+128];
  float s = x0+x1+x2, s2 = x0*x0 + x1*x1 + x2*x2;
  for (int o=32;o;o>>=1){ s += __shfl_xor(s,o); s2 += __shfl_xor(s2,o); }
  float mu = s*(1.f/192.f);
  float var = s2*(1.f/192.f) - mu*mu;
  float rs = rsqrtf(var + 1e-5f);
  dst[t]     = (x0-mu)*rs*g[t]     + b[t];
  dst[t+64]  = (x1-mu)*rs*g[t+64]  + b[t+64];
  dst[t+128] = (x2-mu)*rs*g[t+128] + b[t+128];
}

// ------ conv1 weight prep: (192,384,27) f32 -> [n][t*384+c] bf16 -----------
__global__ void k_prepw1b(const float* __restrict__ src, u16* __restrict__ dst, int swap){
  int idx = blockIdx.x*256 + threadIdx.x;
  if (idx >= 192*10368) return;
  int n = idx / 10368; int k = idx - n*10368;
  int t = k / 384; int c = k - t*384;
  int cs = c + swap; if (cs >= 384) cs -= 384;
  dst[idx] = f2b(src[((size_t)n*384 + cs)*27 + t]);
}
// ------ conv2 weight prep: (96,192,27) f32 -> [n][t*192+c] bf16 ------------
__global__ void k_prepw2b(const float* __restrict__ src, u16* __restrict__ dst){
  int idx = blockIdx.x*256 + threadIdx.x;
  if (idx >= 96*5184) return;
  int n = idx / 5184; int k = idx - n*5184;
  int t = k / 192; int c = k - t*192;
  dst[idx] = f2b(src[((size_t)n*192 + c)*27 + t]);
}

// ------ bias matrix prep: [type 8][head 6][key 352][query 352] f32 ---------
__global__ void k_prepbias(const float* __restrict__ rpt, float* __restrict__ bm){
  int idx = blockIdx.x*256 + threadIdx.x;
  if (idx >= 48*123904) return;
  int th = idx / 123904; int r = idx - th*123904;
  int key = r / 352; int q = r - key*352;
  int type = th / 6; int h = th - type*6;
  float v;
  if (key >= 343 || q >= 343){
    v = -30000.f;
  } else {
    int ki = key/49, kj = (key/7)%7, kk = key%7;
    int qi = q/49,   qj = (q/7)%7,   qk = q%7;
    int ridx = ((qi-ki+6)*13 + (qj-kj+6))*13 + (qk-kk+6);
    float rv = rpt[ridx*6 + h];
    int bd = (type>>2)&1, bh = (type>>1)&1, bw = type&1;
    int lq_ = (bd?((qi<4)?1:2):0)*9 + (bh?((qj<4)?1:2):0)*3 + (bw?((qk<4)?1:2):0);
    int lk_ = (bd?((ki<4)?1:2):0)*9 + (bh?((kj<4)?1:2):0)*3 + (bw?((kk<4)?1:2):0);
    v = rv + ((lq_==lk_) ? 0.f : -100.f);
  }
  bm[idx] = v;
}

// ------ padded volume builders (30^3, zero borders), bf16 ------------------
__global__ __launch_bounds__(192) void k_pad1(const float* __restrict__ m_, const float* __restrict__ f_,
                                              u16* __restrict__ xp){
  int p = blockIdx.x; int t = threadIdx.x;
  int pd = p/900; int r = p - pd*900; int ph = r/30; int pw = r - ph*30;
  int d = pd-1, h = ph-1, w = pw-1;
  u16 vm = 0, vf = 0;
  if ((unsigned)d < 28u && (unsigned)h < 28u && (unsigned)w < 28u){
    size_t l = (size_t)((d*28+h)*28+w)*192 + t;
    vm = f2b(m_[l]); vf = f2b(f_[l]);
  }
  xp[(size_t)p*384 + t] = vm;
  xp[(size_t)p*384 + 192 + t] = vf;
}
__global__ __launch_bounds__(192) void k_pad2(const float* __restrict__ t1,
                                              const float* __restrict__ a1, const float* __restrict__ b1,
                                              u16* __restrict__ xp2){
  int p = blockIdx.x; int t = threadIdx.x;
  int pd = p/900; int r = p - pd*900; int ph = r/30; int pw = r - ph*30;
  int d = pd-1, h = ph-1, w = pw-1;
  u16 v = 0;
  if ((unsigned)d < 28u && (unsigned)h < 28u && (unsigned)w < 28u){
    float xv = t1[(size_t)((d*28+h)*28+w)*192 + t];
    v = f2b(fmaxf(xv*a1[t] + b1[t], 0.f));
  }
  xp2[(size_t)p*192 + t] = v;
}

// ------ implicit-GEMM MFMA conv 3x3x3, N-split grid (2 halves) -------------
// xp: [30^3][CIN] bf16; wt: [COUTF][27*CIN]; out: [L][COUTF] f32
// grid = 343*2: bid>>1 = 64-voxel m-tile, bid&1 = N-half.
// NWN=2: waves (m 0/32)x(n 0/48); NWN=1: waves m 0/16/32/48, full n=48.
template<int CIN, int COUTB, int COUTF, int NWN>
__global__ __launch_bounds__(256) void k_convmfma(const u16* __restrict__ xp,
                                                  const u16* __restrict__ wt,
                                                  float* __restrict__ out){
  constexpr int K = 27*CIN;
  constexpr int CH = CIN/32;          // k-chunks per tap
  constexpr int STEPS = 27*CH;
  constexpr int MT = (NWN==2)?2:1;    // m-tiles per wave
  constexpr int NT = COUTB/16/NWN;    // n-tiles per wave (=3)
  __shared__ __align__(16) u16 As[2][64*40];
  __shared__ __align__(16) u16 Bs[2][COUTB*40];
  int tid = threadIdx.x;
  int wave = tid>>6, lane = tid&63;
  int lm = lane&15, lq = lane>>4;
  int bid = blockIdx.x;
  int v0 = (bid>>1)*64;
  int nh = bid&1;
  const u16* wtb = wt + (size_t)(nh*COUTB)*K;
  int ncol0 = nh*COUTB;
  int sv = tid>>2;
  int sc8 = (tid&3)*8;
  int av = v0 + sv;
  int d = av/784; int rm2 = av - d*784; int hh = rm2/28; int ww = rm2 - hh*28;
  int pbase = (d*30 + hh)*30 + ww;
  int wave_m = (NWN==2) ? (wave>>1) : wave;
  int wave_n = (NWN==2) ? (wave&1) : 0;
  int mbase = wave_m*16*MT;
  int nbase = wave_n*16*NT;

  float4v acc[MT][NT];
  #pragma unroll
  for (int mt=0; mt<MT; mt++)
    #pragma unroll
    for (int nt=0; nt<NT; nt++) acc[mt][nt] = (float4v)0.f;

  auto stage = [&](int buf, int s){
    int t = s/CH, cc = s - t*CH;
    int td = t/9; int tr = t - td*9; int th = tr/3; int tw = tr - th*3;
    int toff = td*900 + th*30 + tw;
    {
      uint4 val = *(const uint4*)(xp + (size_t)(pbase + toff)*CIN + cc*32 + sc8);
      *(uint4*)(&As[buf][sv*40 + sc8]) = val;
    }
    #pragma unroll
    for (int bi = tid; bi < COUTB*4; bi += 256){
      int n = bi>>2, c8 = (bi&3)*8;
      uint4 val = *(const uint4*)(wtb + (size_t)n*K + t*CIN + cc*32 + c8);
      *(uint4*)(&Bs[buf][n*40 + c8]) = val;
    }
  };

  stage(0, 0);
  __syncthreads();
  for (int s = 0; s < STEPS; s++){
    if (s+1 < STEPS) stage((s+1)&1, s+1);
    int buf = s&1;
    short8 aa[MT];
    #pragma unroll
    for (int mt=0; mt<MT; mt++)
      aa[mt] = *(const short8*)(&As[buf][(mbase + mt*16 + lm)*40 + lq*8]);
    short8 bfr[NT];
    #pragma unroll
    for (int nt=0; nt<NT; nt++)
      bfr[nt] = *(const short8*)(&Bs[buf][(nbase + nt*16 + lm)*40 + lq*8]);
    #pragma unroll
    for (int nt=0; nt<NT; nt++)
      #pragma unroll
      for (int mt=0; mt<MT; mt++)
        acc[mt][nt] = __builtin_amdgcn_mfma_f32_16x16x32_bf16(aa[mt], bfr[nt], acc[mt][nt], 0, 0, 0);
    __syncthreads();
  }
  #pragma unroll
  for (int mt=0; mt<MT; mt++)
    #pragma unroll
    for (int nt=0; nt<NT; nt++)
      #pragma unroll
      for (int r=0; r<4; r++){
        int row = v0 + mbase + mt*16 + lq*4 + r;
        int col = ncol0 + nbase + nt*16 + lm;
        out[(size_t)row*COUTF + col] = acc[mt][nt][r];
      }
}

// per-channel BN stats -> fused scale/shift (a*x+b)
__global__ __launch_bounds__(256) void k_bnstats(const float* __restrict__ x, int C,
                                                 const float* __restrict__ g, const float* __restrict__ b,
                                                 float* __restrict__ a_out, float* __restrict__ b_out){
  int c = blockIdx.x;
  float s=0.f, s2=0.f;
  for (int l = threadIdx.x; l < LTOT; l += 256){
    float v = x[(size_t)l*C + c]; s += v; s2 += v*v;
  }
  for (int o=32;o;o>>=1){ s += __shfl_xor(s,o); s2 += __shfl_xor(s2,o); }
  __shared__ float rs_[4], rs2_[4];
  int wv = threadIdx.x>>6;
  if ((threadIdx.x&63)==0){ rs_[wv]=s; rs2_[wv]=s2; }
  __syncthreads();
  if (threadIdx.x==0){
    s = rs_[0]+rs_[1]+rs_[2]+rs_[3]; s2 = rs2_[0]+rs2_[1]+rs2_[2]+rs2_[3];
    float mu = s/(float)LTOT;
    float var = s2/(float)LTOT - mu*mu;
    float rstd = rsqrtf(var + 1e-5f);
    float aa = rstd * g[c];
    a_out[c] = aa;
    b_out[c] = b[c] - mu*aa;
  }
}

// ------------- conv3 1x1x1: 96 -> 18 flow channels, layout (18, L) ---------
__global__ __launch_bounds__(96) void k_flow(const float* __restrict__ t2,
                                             const float* __restrict__ a2, const float* __restrict__ b2,
                                             const float* __restrict__ w3, float* __restrict__ flow){
  __shared__ float xr[96];
  int l = blockIdx.x; int t = threadIdx.x;
  float xv = t2[(size_t)l*96 + t];
  xr[t] = fmaxf(xv*a2[t] + b2[t], 0.f);
  __syncthreads();
  if (t < 18){
    float acc = 0.f;
    for (int c=0;c<96;c++) acc += xr[c]*w3[t*96 + c];
    flow[(size_t)t*LTOT + l] = acc;
  }
}

// ------------- trilinear warp (per-head flow), border clamp ----------------
__global__ __launch_bounds__(192) void k_warp(const float* __restrict__ src,
                                              const float* __restrict__ flow, float* __restrict__ dst){
  int l = blockIdx.x; int tid = threadIdx.x; int hh = tid>>5;
  int d = l/784; int rm = l - d*784; int y = rm/28; int x = rm - y*28;
  float fd = flow[(size_t)(hh*3+0)*LTOT + l];
  float fy = flow[(size_t)(hh*3+1)*LTOT + l];
  float fx = flow[(size_t)(hh*3+2)*LTOT + l];
  float cd = fminf(fmaxf((float)d + fd, 0.f), 27.f);
  float cy = fminf(fmaxf((float)y + fy, 0.f), 27.f);
  float cx = fminf(fmaxf((float)x + fx, 0.f), 27.f);
  int d0 = (int)floorf(cd); int d1 = min(d0+1, 27);
  int y0 = (int)floorf(cy); int y1 = min(y0+1, 27);
  int x0 = (int)floorf(cx); int x1 = min(x0+1, 27);
  float wd = cd - (float)d0, wy = cy - (float)y0, wx = cx - (float)x0;
  #define SMP(di,yi,xi) src[(size_t)(((di)*28+(yi))*28+(xi))*192 + tid]
  float v000 = SMP(d0,y0,x0), v001 = SMP(d0,y0,x1), v010 = SMP(d0,y1,x0), v011 = SMP(d0,y1,x1);
  float v100 = SMP(d1,y0,x0), v101 = SMP(d1,y0,x1), v110 = SMP(d1,y1,x0), v111 = SMP(d1,y1,x1);
  #undef SMP
  float o = v000*(1-wd)*(1-wy)*(1-wx) + v001*(1-wd)*(1-wy)*wx
          + v010*(1-wd)*wy*(1-wx)     + v011*(1-wd)*wy*wx
          + v100*wd*(1-wy)*(1-wx)     + v101*wd*(1-wy)*wx
          + v110*wd*wy*(1-wx)         + v111*wd*wy*wx;
  dst[(size_t)l*192 + tid] = o;
}

// ------- windowed GEMV -> bf16 out: out[(w*6+h)*343+n][c] ------------------
__global__ __launch_bounds__(192) void k_qkv(const float* __restrict__ A,
                                             const float* __restrict__ Wt, const float* __restrict__ bias,
                                             u16* __restrict__ outp, float scale){
  __shared__ float xs[16*192];
  __shared__ int lsrc[16];
  int tid = threadIdx.x; int r0 = blockIdx.x*16;
  if (tid < 16){
    int r = r0 + tid; int w = r/343; int n = r - w*343;
    int nd = w>>4, nh = (w>>2)&3, nw = w&3;
    int i = n/49; int rr = n - i*49; int j = rr/7; int k = rr - j*7;
    int dd = nd*7 + i + 3; if (dd >= 28) dd -= 28;
    int hh = nh*7 + j + 3; if (hh >= 28) hh -= 28;
    int ww = nw*7 + k + 3; if (ww >= 28) ww -= 28;
    lsrc[tid] = (dd*28 + hh)*28 + ww;
  }
  __syncthreads();
  #pragma unroll
  for (int it=0; it<16; it++) xs[it*192 + tid] = A[(size_t)lsrc[it]*192 + tid];
  __syncthreads();
  float acc[16];
  #pragma unroll
  for (int u=0;u<16;u++) acc[u]=0.f;
  const float4* wrow = (const float4*)(Wt + (size_t)tid*192);
  for (int kc=0; kc<24; kc++){
    float4 wa = wrow[kc*2], wbv = wrow[kc*2+1];
    #pragma unroll
    for (int rr2=0; rr2<16; rr2++){
      const float4* xp = (const float4*)(xs + rr2*192 + kc*8);
      float4 x0 = xp[0], x1 = xp[1];
      acc[rr2] += x0.x*wa.x + x0.y*wa.y + x0.z*wa.z + x0.w*wa.w
                + x1.x*wbv.x + x1.y*wbv.y + x1.z*wbv.z + x1.w*wbv.w;
    }
  }
  float bb = bias[tid];
  int h = tid>>5, c = tid&31;
  #pragma unroll
  for (int rr2=0; rr2<16; rr2++){
    int r = r0 + rr2; int w = r/343; int n = r - w*343;
    outp[((size_t)(w*6 + h)*343 + n)*32 + c] = f2b((acc[rr2] + bb)*scale);
  }
}

// ------------ MFMA attention: block = (window, head) -----------------------
__global__ __launch_bounds__(256) void k_attmfma(const u16* __restrict__ Q,
                                                 const u16* __restrict__ K,
                                                 const u16* __restrict__ V,
                                                 const float* __restrict__ bm,
                                                 float* __restrict__ ctx){
  __shared__ __align__(16) u16 Kl[352*40];      // [key][40]
  __shared__ __align__(16) u16 Vt[32*360];      // [dim][360]
  __shared__ __align__(16) u16 Pl[4][2][16*40]; // per-wave, dbuf: [query16][40]
  int wh = blockIdx.x; int w = wh/6, h = wh - w*6;
  int tid = threadIdx.x;
  int nd = w>>4, nh = (w>>2)&3, nw = w&3;
  int type = ((nd==3)?4:0) | ((nh==3)?2:0) | ((nw==3)?1:0);
  const u16* kb = K + (size_t)wh*10976;
  const u16* vbp = V + (size_t)wh*10976;
  for (int idx=tid; idx<343*4; idx+=256){
    int row = idx>>2, c8 = (idx&3)*8;
    uint4 val = *(const uint4*)(kb + row*32 + c8);
    *(uint4*)(&Kl[row*40 + c8]) = val;
  }
  for (int idx=tid; idx<9*40; idx+=256) Kl[343*40 + idx] = 0;
  for (int idx=tid; idx<343*4; idx+=256){
    int row = idx>>2, c8 = (idx&3)*8;
    uint4 val = *(const uint4*)(vbp + row*32 + c8);
    const u16* pv = (const u16*)&val;
    #pragma unroll
    for (int j=0;j<8;j++) Vt[(c8+j)*360 + row] = pv[j];
  }
  for (int idx=tid; idx<32*17; idx+=256){
    int dd = idx/17, cc = 343 + idx - (idx/17)*17;
    Vt[dd*360 + cc] = 0;
  }
  __syncthreads();
  int lane = tid&63, wv = tid>>6;
  int lm = lane&15, lq = lane>>4;
  const float* bmh = bm + (size_t)(type*6 + h)*123904;
  for (int qt=wv; qt<22; qt+=4){
    int q0 = qt*16;
    short8 bq = *(const short8*)(Q + (size_t)wh*10976 + (q0+lm)*32 + lq*8);
    float4v sc[22];
    #pragma unroll
    for (int kt=0; kt<22; kt++){
      short8 ak = *(const short8*)(&Kl[(kt*16+lm)*40 + lq*8]);
      sc[kt] = __builtin_amdgcn_mfma_f32_16x16x32_bf16(ak, bq, (float4v)0.f, 0, 0, 0);
    }
    const float* bcol = bmh + q0 + lm;
    float mx = -3.0e38f;
    #pragma unroll
    for (int kt=0; kt<22; kt++){
      #pragma unroll
      for (int r=0; r<4; r++){
        int key = kt*16 + lq*4 + r;
        float s = sc[kt][r] + bcol[(size_t)key*352];
        sc[kt][r] = s;
        mx = fmaxf(mx, s);
      }
    }
    mx = fmaxf(mx, __shfl_xor(mx, 16));
    mx = fmaxf(mx, __shfl_xor(mx, 32));
    float sm = 0.f;
    #pragma unroll
    for (int kt=0; kt<22; kt++){
      #pragma unroll
      for (int r=0; r<4; r++){
        float p = __expf(sc[kt][r] - mx);
        sc[kt][r] = p;
        sm += p;
      }
    }
    sm += __shfl_xor(sm, 16);
    sm += __shfl_xor(sm, 32);
    float inv = 1.f/sm;
    float4v o0 = (float4v)0.f, o1 = (float4v)0.f;
    #pragma unroll
    for (int s=0; s<11; s++){
      u16* pw = &Pl[wv][s&1][0];
      #pragma unroll
      for (int half=0; half<2; half++){
        int kt = 2*s + half;
        uint2 pv2;
        pv2.x = (u32)f2b(sc[kt][0]) | ((u32)f2b(sc[kt][1])<<16);
        pv2.y = (u32)f2b(sc[kt][2]) | ((u32)f2b(sc[kt][3])<<16);
        *(uint2*)(&pw[lm*40 + half*16 + lq*4]) = pv2;
      }
      short8 bp = *(const short8*)(&pw[lm*40 + lq*8]);
      short8 a0 = *(const short8*)(&Vt[lm*360 + s*32 + lq*8]);
      short8 a1 = *(const short8*)(&Vt[(16+lm)*360 + s*32 + lq*8]);
      o0 = __builtin_amdgcn_mfma_f32_16x16x32_bf16(a0, bp, o0, 0, 0, 0);
      o1 = __builtin_amdgcn_mfma_f32_16x16x32_bf16(a1, bp, o1, 0, 0, 0);
    }
    int query = q0 + lm;
    if (query < 343){
      float* ob = ctx + ((size_t)w*NTOK + query)*192 + h*32;
      float4 t0, t1v;
      t0.x = o0[0]*inv; t0.y = o0[1]*inv; t0.z = o0[2]*inv; t0.w = o0[3]*inv;
      t1v.x = o1[0]*inv; t1v.y = o1[1]*inv; t1v.z = o1[2]*inv; t1v.w = o1[3]*inv;
      *(float4*)(ob + lq*4) = t0;
      *(float4*)(ob + 16 + lq*4) = t1v;
    }
  }
}

// ---- proj + residual + window-reverse/unroll: out f32 (L,192) -------------
__global__ __launch_bounds__(192) void k_proj(const float* __restrict__ ctx,
                                              const float* __restrict__ Wt, const float* __restrict__ bias,
                                              const float* __restrict__ resid, float* __restrict__ outp){
  __shared__ float xs[16*192];
  __shared__ int lsrc[16];
  int tid = threadIdx.x; int r0 = blockIdx.x*16;
  if (tid < 16){
    int l = r0 + tid;
    int d = l/784; int rm = l - d*784; int y = rm/28; int x = rm - y*28;
    int dp = d-3; if (dp<0) dp+=28;
    int yp = y-3; if (yp<0) yp+=28;
    int xp = x-3; if (xp<0) xp+=28;
    int nd = dp/7, i = dp - nd*7;
    int nh = yp/7, j = yp - nh*7;
    int nw = xp/7, k = xp - nw*7;
    lsrc[tid] = ((nd*4+nh)*4+nw)*NTOK + (i*7+j)*7 + k;
  }
  __syncthreads();
  #pragma unroll
  for (int it=0; it<16; it++) xs[it*192 + tid] = ctx[(size_t)lsrc[it]*192 + tid];
  __syncthreads();
  float acc[16];
  #pragma unroll
  for (int u=0;u<16;u++) acc[u]=0.f;
  const float4* wrow = (const float4*)(Wt + (size_t)tid*192);
  for (int kc=0; kc<24; kc++){
    float4 wa = wrow[kc*2], wbv = wrow[kc*2+1];
    #pragma unroll
    for (int rr2=0; rr2<16; rr2++){
      const float4* xp = (const float4*)(xs + rr2*192 + kc*8);
      float4 x0 = xp[0], x1 = xp[1];
      acc[rr2] += x0.x*wa.x + x0.y*wa.y + x0.z*wa.z + x0.w*wa.w
                + x1.x*wbv.x + x1.y*wbv.y + x1.z*wbv.z + x1.w*wbv.w;
    }
  }
  float bb = bias[tid];
  #pragma unroll
  for (int rr2=0; rr2<16; rr2++){
    size_t o = (size_t)(r0 + rr2)*192 + tid;
    outp[o] = acc[rr2] + bb + resid[o];
  }
}

// ------- fc1 + gelu: x_ln [L,192] -> hs [L,768], 16-token tiles ------------
__global__ __launch_bounds__(384) void k_fc1(const float* __restrict__ xin,
                                             const float* __restrict__ w1, const float* __restrict__ b1,
                                             float* __restrict__ hs){
  __shared__ float xs[16*192];
  int tid = threadIdx.x; int l0 = blockIdx.x*16;
  for (int idx=tid; idx<16*192; idx+=384) xs[idx] = xin[(size_t)l0*192 + idx];
  __syncthreads();
  float a0[16], a1[16];
  #pragma unroll
  for (int t=0;t<16;t++){ a0[t]=0.f; a1[t]=0.f; }
  int j0 = tid, j1 = tid + 384;
  const float4* wr0 = (const float4*)(w1 + (size_t)j0*192);
  const float4* wr1 = (const float4*)(w1 + (size_t)j1*192);
  for (int kc=0; kc<48; kc++){
    float4 wa = wr0[kc], wb = wr1[kc];
    #pragma unroll
    for (int t=0;t<16;t++){
      const float4* xp = (const float4*)(xs + t*192 + kc*4);
      float4 x4 = xp[0];
      a0[t] += x4.x*wa.x + x4.y*wa.y + x4.z*wa.z + x4.w*wa.w;
      a1[t] += x4.x*wb.x + x4.y*wb.y + x4.z*wb.z + x4.w*wb.w;
    }
  }
  float bv0 = b1[j0], bv1 = b1[j1];
  #pragma unroll
  for (int t=0;t<16;t++){
    float v0 = a0[t] + bv0, v1 = a1[t] + bv1;
    hs[(size_t)(l0+t)*768 + j0] = 0.5f*v0*(1.f + erff(v0*0.70710678118f));
    hs[(size_t)(l0+t)*768 + j1] = 0.5f*v1*(1.f + erff(v1*0.70710678118f));
  }
}

// ------- fc2 + residual: hs [L,768] -> out [L,192] (adds resid) ------------
__global__ __launch_bounds__(192) void k_fc2(const float* __restrict__ hs,
                                             const float* __restrict__ w2, const float* __restrict__ b2,
                                             const float* __restrict__ resid, float* __restrict__ outp){
  __shared__ float hl[16*768];
  int tid = threadIdx.x; int l0 = blockIdx.x*16;
  for (int idx=tid; idx<16*768; idx+=192) hl[idx] = hs[(size_t)l0*768 + idx];
  __syncthreads();
  float acc[16];
  #pragma unroll
  for (int t=0;t<16;t++) acc[t]=0.f;
  const float4* wr = (const float4*)(w2 + (size_t)tid*768);
  for (int kc=0; kc<192; kc++){
    float4 wa = wr[kc];
    #pragma unroll
    for (int t=0;t<16;t++){
      const float4* hp = (const float4*)(hl + t*768 + kc*4);
      float4 h4 = hp[0];
      acc[t] += h4.x*wa.x + h4.y*wa.y + h4.z*wa.z + h4.w*wa.w;
    }
  }
  float bb = b2[tid];
  #pragma unroll
  for (int t=0;t<16;t++){
    size_t o = (size_t)(l0+t)*192 + tid;
    outp[o] = acc[t] + bb + resid[o];
  }
}

// ===========================================================================
extern "C" void kernel_launch(void* const* d_in, const int* in_sizes, int n_in,
                              void* d_out, int out_size, void* d_ws, size_t ws_size,
                              hipStream_t stream){
  const float* mov     = (const float*)d_in[0];
  const float* fix     = (const float*)d_in[1];
  const float* n1g     = (const float*)d_in[2];
  const float* n1b     = (const float*)d_in[3];
  const float* offm_w1 = (const float*)d_in[4];
  const float* offm_g1 = (const float*)d_in[5];
  const float* offm_b1 = (const float*)d_in[6];
  const float* offm_w2 = (const float*)d_in[7];
  const float* offm_g2 = (const float*)d_in[8];
  const float* offm_b2 = (const float*)d_in[9];
  const float* offm_w3 = (const float*)d_in[10];
  const float* offf_w1 = (const float*)d_in[11];
  const float* offf_g1 = (const float*)d_in[12];
  const float* offf_b1 = (const float*)d_in[13];
  const float* offf_w2 = (const float*)d_in[14];
  const float* offf_g2 = (const float*)d_in[15];
  const float* offf_b2 = (const float*)d_in[16];
  const float* offf_w3 = (const float*)d_in[17];
  const float* mq_w    = (const float*)d_in[18];
  const float* mkv_w   = (const float*)d_in[19];
  const float* fq_w    = (const float*)d_in[20];
  const float* fkv_w   = (const float*)d_in[21];
  const float* mproj_w = (const float*)d_in[22];
  const float* fproj_w = (const float*)d_in[23];
  const float* mq_b    = (const float*)d_in[24];
  const float* mkv_b   = (const float*)d_in[25];
  const float* fq_b    = (const float*)d_in[26];
  const float* fkv_b   = (const float*)d_in[27];
  const float* mproj_b = (const float*)d_in[28];
  const float* fproj_b = (const float*)d_in[29];
  const float* rpbt    = (const float*)d_in[30];
  const float* n2g     = (const float*)d_in[31];
  const float* n2b     = (const float*)d_in[32];
  const float* fc1_w   = (const float*)d_in[33];
  const float* fc1_b   = (const float*)d_in[34];
  const float* fc2_w   = (const float*)d_in[35];
  const float* fc2_b   = (const float*)d_in[36];
  float* outp = (float*)d_out;

  float* W = (float*)d_ws;
  const size_t L192 = (size_t)LTOT*192;   // floats per region
  float* m_   = W;
  float* f_   = W + 1*L192;
  float* t1   = W + 2*L192;
  float* t2   = W + 3*L192;
  float* dmov = W + 4*L192;
  float* dfix = W + 5*L192;
  float* ctxm = dmov; float* ctxf = dfix;
  float* mout = m_;   float* fout = f_;
  u16* QMb = (u16*)(W + 6*L192);
  u16* QFb = (u16*)(W + 7*L192);
  u16* Kmb = (u16*)(W + 2*L192);
  u16* Vmb = (u16*)(W + 3*L192);
  u16* Kfb = (u16*)(W + 8*L192);
  u16* Vfb = (u16*)(W + 9*L192);
  float* a1v = W + 6*L192;        float* b1v = a1v + 192;
  float* a2v = a1v + 384;         float* b2v = a1v + 480;
  float* flowm = W + 7*L192;      float* flowf = flowm + (size_t)LTOT*18;
  u16* xp   = (u16*)(W + 4*L192);
  u16* xp2  = (u16*)(W + 5*L192 + 2000000);
  u16* wt1m = (u16*)(W + 8*L192);
  u16* wt1f = wt1m + 192*10368;
  u16* wt2m = wt1f + 192*10368;
  u16* wt2f = wt2m + 96*5184;
  float* bm = W;
  float* hsbuf = t1;
  float* lnbuf = W + 6*L192;

  // conv weight prep
  k_prepw1b<<<(192*10368+255)/256, 256, 0, stream>>>(offm_w1, wt1m, 0);
  k_prepw1b<<<(192*10368+255)/256, 256, 0, stream>>>(offf_w1, wt1f, 192);
  k_prepw2b<<<(96*5184+255)/256, 256, 0, stream>>>(offm_w2, wt2m);
  k_prepw2b<<<(96*5184+255)/256, 256, 0, stream>>>(offf_w2, wt2f);
  // layernorm1
  k_ln<<<2*LTOT, 64, 0, stream>>>(mov, fix, n1g, n1b, m_, f_);
  // padded bf16 volume [m|f]
  k_pad1<<<27000, 192, 0, stream>>>(m_, f_, xp);
  // offset block (moving)
  k_convmfma<384,96,192,2><<<686, 256, 0, stream>>>(xp, wt1m, t1);
  k_bnstats<<<192, 256, 0, stream>>>(t1, 192, offm_g1, offm_b1, a1v, b1v);
  k_pad2<<<27000, 192, 0, stream>>>(t1, a1v, b1v, xp2);
  k_convmfma<192,48,96,1><<<686, 256, 0, stream>>>(xp2, wt2m, t2);
  k_bnstats<<<96, 256, 0, stream>>>(t2, 96, offm_g2, offm_b2, a2v, b2v);
  k_flow<<<LTOT, 96, 0, stream>>>(t2, a2v, b2v, offm_w3, flowm);
  // offset block (fixed)
  k_convmfma<384,96,192,2><<<686, 256, 0, stream>>>(xp, wt1f, t1);
  k_bnstats<<<192, 256, 0, stream>>>(t1, 192, offf_g1, offf_b1, a1v, b1v);
  k_pad2<<<27000, 192, 0, stream>>>(t1, a1v, b1v, xp2);
  k_convmfma<192,48,96,1><<<686, 256, 0, stream>>>(xp2, wt2f, t2);
  k_bnstats<<<96, 256, 0, stream>>>(t2, 96, offf_g2, offf_b2, a2v, b2v);
  k_flow<<<LTOT, 96, 0, stream>>>(t2, a2v, b2v, offf_w3, flowf);
  // deformable warp
  k_warp<<<LTOT, 192, 0, stream>>>(m_, flowm, dmov);
  k_warp<<<LTOT, 192, 0, stream>>>(f_, flowf, dfix);
  // windowed projections -> bf16
  const float scale = 0.17677669529663687f; // 32^-0.5
  k_qkv<<<1372, 192, 0, stream>>>(dmov, mq_w,  mq_b,  QMb, scale);   // dmQ
  k_qkv<<<1372, 192, 0, stream>>>(dfix, fq_w,  fq_b,  QFb, scale);   // dfQ
  k_qkv<<<1372, 192, 0, stream>>>(m_, mkv_w,          mkv_b,     Kmb, 1.f);
  k_qkv<<<1372, 192, 0, stream>>>(m_, mkv_w+192*192,  mkv_b+192, Vmb, 1.f);
  k_qkv<<<1372, 192, 0, stream>>>(f_, fkv_w,          fkv_b,     Kfb, 1.f);
  k_qkv<<<1372, 192, 0, stream>>>(f_, fkv_w+192*192,  fkv_b+192, Vfb, 1.f);
  // bias matrix (m_/f_ now dead)
  k_prepbias<<<(48*123904+255)/256, 256, 0, stream>>>(rpbt, bm);
  // attention: mo = attend(dfQ, mK, mV); fo = attend(dmQ, fK, fV)
  k_attmfma<<<384, 256, 0, stream>>>(QFb, Kmb, Vmb, bm, ctxm);
  k_attmfma<<<384, 256, 0, stream>>>(QMb, Kfb, Vfb, bm, ctxf);
  // proj + residual + window-reverse/unroll
  k_proj<<<1372, 192, 0, stream>>>(ctxm, mproj_w, mproj_b, mov, mout);
  k_proj<<<1372, 192, 0, stream>>>(ctxf, fproj_w, fproj_b, fix, fout);
  // MLP (mov half)
  k_ln1<<<LTOT, 64, 0, stream>>>(mout, n2g, n2b, lnbuf);
  k_fc1<<<1372, 384, 0, stream>>>(lnbuf, fc1_w, fc1_b, hsbuf);
  k_fc2<<<1372, 192, 0, stream>>>(hsbuf, fc2_w, fc2_b, mout, outp);
  // MLP (fix half)
  k_ln1<<<LTOT, 64, 0, stream>>>(fout, n2g, n2b, lnbuf);
  k_fc1<<<1372, 384, 0, stream>>>(lnbuf, fc1_w, fc1_b, hsbuf);
  k_fc2<<<1372, 192, 0, stream>>>(hsbuf, fc2_w, fc2_b, fout, outp + L192);
}

// Round 7
// 2947.017 us; speedup vs baseline: 5.7312x; 1.0994x over previous
//
#include <hip/hip_runtime.h>

#define LTOT 21952      // 28^3
#define NTOK 343        // 7^3

typedef unsigned short u16;
typedef unsigned int   u32;
typedef __attribute__((ext_vector_type(8))) short short8;
typedef __attribute__((ext_vector_type(4))) float float4v;

__device__ __forceinline__ u16 f2b(float f){
  u32 x = __float_as_uint(f);
  u32 r = (x + 0x7fffu + ((x>>16)&1u)) >> 16;
  return (u16)r;
}

// ---------------- LayerNorm (norm1) : f32 in -> f32 out --------------------
__global__ __launch_bounds__(64) void k_ln(const float* __restrict__ mov, const float* __restrict__ fix,
                                           const float* __restrict__ g, const float* __restrict__ b,
                                           float* __restrict__ om, float* __restrict__ of){
  int row = blockIdx.x;
  const float* src; float* dst;
  if (row < LTOT){ src = mov + (size_t)row*192; dst = om + (size_t)row*192; }
  else          { src = fix + (size_t)(row-LTOT)*192; dst = of + (size_t)(row-LTOT)*192; }
  int t = threadIdx.x;
  float x0 = src[t], x1 = src[t+64], x2 = src[t+128];
  float s = x0+x1+x2, s2 = x0*x0 + x1*x1 + x2*x2;
  for (int o=32;o;o>>=1){ s += __shfl_xor(s,o); s2 += __shfl_xor(s2,o); }
  float mu = s*(1.f/192.f);
  float var = s2*(1.f/192.f) - mu*mu;
  float rs = rsqrtf(var + 1e-5f);
  dst[t]     = (x0-mu)*rs*g[t]     + b[t];
  dst[t+64]  = (x1-mu)*rs*g[t+64]  + b[t+64];
  dst[t+128] = (x2-mu)*rs*g[t+128] + b[t+128];
}

// ---------------- LayerNorm (norm2), single buffer -------------------------
__global__ __launch_bounds__(64) void k_ln1(const float* __restrict__ x,
                                            const float* __restrict__ g, const float* __restrict__ b,
                                            float* __restrict__ y){
  int row = blockIdx.x;
  const float* src = x + (size_t)row*192;
  float* dst = y + (size_t)row*192;
  int t = threadIdx.x;
  float x0 = src[t], x1 = src[t+64], x2 = src[t+128];
  float s = x0+x1+x2, s2 = x0*x0 + x1*x1 + x2*x2;
  for (int o=32;o;o>>=1){ s += __shfl_xor(s,o); s2 += __shfl_xor(s2,o); }
  float mu = s*(1.f/192.f);
  float var = s2*(1.f/192.f) - mu*mu;
  float rs = rsqrtf(var + 1e-5f);
  dst[t]     = (x0-mu)*rs*g[t]     + b[t];
  dst[t+64]  = (x1-mu)*rs*g[t+64]  + b[t+64];
  dst[t+128] = (x2-mu)*rs*g[t+128] + b[t+128];
}

// ------ conv1 weight prep: (192,384,27) f32 -> [n][t*384+c] bf16 -----------
__global__ void k_prepw1b(const float* __restrict__ src, u16* __restrict__ dst, int swap){
  int idx = blockIdx.x*256 + threadIdx.x;
  if (idx >= 192*10368) return;
  int n = idx / 10368; int k = idx - n*10368;
  int t = k / 384; int c = k - t*384;
  int cs = c + swap; if (cs >= 384) cs -= 384;
  dst[idx] = f2b(src[((size_t)n*384 + cs)*27 + t]);
}
// ------ conv2 weight prep: (96,192,27) f32 -> [n][t*192+c] bf16 ------------
__global__ void k_prepw2b(const float* __restrict__ src, u16* __restrict__ dst){
  int idx = blockIdx.x*256 + threadIdx.x;
  if (idx >= 96*5184) return;
  int n = idx / 5184; int k = idx - n*5184;
  int t = k / 192; int c = k - t*192;
  dst[idx] = f2b(src[((size_t)n*192 + c)*27 + t]);
}

// ------ bias matrix prep: [type 8][head 6][key 352][query 352] f32 ---------
__global__ void k_prepbias(const float* __restrict__ rpt, float* __restrict__ bm){
  int idx = blockIdx.x*256 + threadIdx.x;
  if (idx >= 48*123904) return;
  int th = idx / 123904; int r = idx - th*123904;
  int key = r / 352; int q = r - key*352;
  int type = th / 6; int h = th - type*6;
  float v;
  if (key >= 343 || q >= 343){
    v = -30000.f;
  } else {
    int ki = key/49, kj = (key/7)%7, kk = key%7;
    int qi = q/49,   qj = (q/7)%7,   qk = q%7;
    int ridx = ((qi-ki+6)*13 + (qj-kj+6))*13 + (qk-kk+6);
    float rv = rpt[ridx*6 + h];
    int bd = (type>>2)&1, bh = (type>>1)&1, bw = type&1;
    int lq_ = (bd?((qi<4)?1:2):0)*9 + (bh?((qj<4)?1:2):0)*3 + (bw?((qk<4)?1:2):0);
    int lk_ = (bd?((ki<4)?1:2):0)*9 + (bh?((kj<4)?1:2):0)*3 + (bw?((kk<4)?1:2):0);
    v = rv + ((lq_==lk_) ? 0.f : -100.f);
  }
  bm[idx] = v;
}

// ------ padded volume builders (30^3, zero borders), bf16 ------------------
__global__ __launch_bounds__(192) void k_pad1(const float* __restrict__ m_, const float* __restrict__ f_,
                                              u16* __restrict__ xp){
  int p = blockIdx.x; int t = threadIdx.x;
  int pd = p/900; int r = p - pd*900; int ph = r/30; int pw = r - ph*30;
  int d = pd-1, h = ph-1, w = pw-1;
  u16 vm = 0, vf = 0;
  if ((unsigned)d < 28u && (unsigned)h < 28u && (unsigned)w < 28u){
    size_t l = (size_t)((d*28+h)*28+w)*192 + t;
    vm = f2b(m_[l]); vf = f2b(f_[l]);
  }
  xp[(size_t)p*384 + t] = vm;
  xp[(size_t)p*384 + 192 + t] = vf;
}
__global__ __launch_bounds__(192) void k_pad2(const float* __restrict__ t1,
                                              const float* __restrict__ a1, const float* __restrict__ b1,
                                              u16* __restrict__ xp2){
  int p = blockIdx.x; int t = threadIdx.x;
  int pd = p/900; int r = p - pd*900; int ph = r/30; int pw = r - ph*30;
  int d = pd-1, h = ph-1, w = pw-1;
  u16 v = 0;
  if ((unsigned)d < 28u && (unsigned)h < 28u && (unsigned)w < 28u){
    float xv = t1[(size_t)((d*28+h)*28+w)*192 + t];
    v = f2b(fmaxf(xv*a1[t] + b1[t], 0.f));
  }
  xp2[(size_t)p*192 + t] = v;
}

// ------ implicit-GEMM MFMA conv 3x3x3, N-split grid (2 halves) -------------
template<int CIN, int COUTB, int COUTF, int NWN>
__global__ __launch_bounds__(256) void k_convmfma(const u16* __restrict__ xp,
                                                  const u16* __restrict__ wt,
                                                  float* __restrict__ out){
  constexpr int K = 27*CIN;
  constexpr int CH = CIN/32;          // k-chunks per tap
  constexpr int STEPS = 27*CH;
  constexpr int MT = (NWN==2)?2:1;    // m-tiles per wave
  constexpr int NT = COUTB/16/NWN;    // n-tiles per wave (=3)
  __shared__ __align__(16) u16 As[2][64*40];
  __shared__ __align__(16) u16 Bs[2][COUTB*40];
  int tid = threadIdx.x;
  int wave = tid>>6, lane = tid&63;
  int lm = lane&15, lq = lane>>4;
  int bid = blockIdx.x;
  int v0 = (bid>>1)*64;
  int nh = bid&1;
  const u16* wtb = wt + (size_t)(nh*COUTB)*K;
  int ncol0 = nh*COUTB;
  int sv = tid>>2;
  int sc8 = (tid&3)*8;
  int av = v0 + sv;
  int d = av/784; int rm2 = av - d*784; int hh = rm2/28; int ww = rm2 - hh*28;
  int pbase = (d*30 + hh)*30 + ww;
  int wave_m = (NWN==2) ? (wave>>1) : wave;
  int wave_n = (NWN==2) ? (wave&1) : 0;
  int mbase = wave_m*16*MT;
  int nbase = wave_n*16*NT;

  float4v acc[MT][NT];
  #pragma unroll
  for (int mt=0; mt<MT; mt++)
    #pragma unroll
    for (int nt=0; nt<NT; nt++) acc[mt][nt] = (float4v)0.f;

  auto stage = [&](int buf, int s){
    int t = s/CH, cc = s - t*CH;
    int td = t/9; int tr = t - td*9; int th = tr/3; int tw = tr - th*3;
    int toff = td*900 + th*30 + tw;
    {
      uint4 val = *(const uint4*)(xp + (size_t)(pbase + toff)*CIN + cc*32 + sc8);
      *(uint4*)(&As[buf][sv*40 + sc8]) = val;
    }
    #pragma unroll
    for (int bi = tid; bi < COUTB*4; bi += 256){
      int n = bi>>2, c8 = (bi&3)*8;
      uint4 val = *(const uint4*)(wtb + (size_t)n*K + t*CIN + cc*32 + c8);
      *(uint4*)(&Bs[buf][n*40 + c8]) = val;
    }
  };

  stage(0, 0);
  __syncthreads();
  for (int s = 0; s < STEPS; s++){
    if (s+1 < STEPS) stage((s+1)&1, s+1);
    int buf = s&1;
    short8 aa[MT];
    #pragma unroll
    for (int mt=0; mt<MT; mt++)
      aa[mt] = *(const short8*)(&As[buf][(mbase + mt*16 + lm)*40 + lq*8]);
    short8 bfr[NT];
    #pragma unroll
    for (int nt=0; nt<NT; nt++)
      bfr[nt] = *(const short8*)(&Bs[buf][(nbase + nt*16 + lm)*40 + lq*8]);
    #pragma unroll
    for (int nt=0; nt<NT; nt++)
      #pragma unroll
      for (int mt=0; mt<MT; mt++)
        acc[mt][nt] = __builtin_amdgcn_mfma_f32_16x16x32_bf16(aa[mt], bfr[nt], acc[mt][nt], 0, 0, 0);
    __syncthreads();
  }
  #pragma unroll
  for (int mt=0; mt<MT; mt++)
    #pragma unroll
    for (int nt=0; nt<NT; nt++)
      #pragma unroll
      for (int r=0; r<4; r++){
        int row = v0 + mbase + mt*16 + lq*4 + r;
        int col = ncol0 + nbase + nt*16 + lm;
        out[(size_t)row*COUTF + col] = acc[mt][nt][r];
      }
}

// ---- BN stats, coalesced 2-stage: partial sums then finalize --------------
// grid 64, block 192: rows [bid*343, +343); thread -> (channel, row-slot)
__global__ __launch_bounds__(192) void k_bnsum(const float* __restrict__ x, int C,
                                               float* __restrict__ psum){
  int bid = blockIdx.x, t = threadIdx.x;
  int rpi = 192/C;                 // 1 for C=192, 2 for C=96
  int c  = (C==192) ? t : (t % 96);
  int ro = (C==192) ? 0 : (t / 96);
  float s=0.f, s2=0.f;
  int base = bid*343;
  for (int r = ro; r < 343; r += rpi){
    float v = x[(size_t)(base+r)*C + c];
    s += v; s2 += v*v;
  }
  psum[(size_t)bid*384 + t]       = s;
  psum[(size_t)bid*384 + 192 + t] = s2;
}
__global__ void k_bnfin(const float* __restrict__ psum, int C,
                        const float* __restrict__ g, const float* __restrict__ b,
                        float* __restrict__ a_out, float* __restrict__ b_out){
  int c = threadIdx.x;
  if (c >= C) return;
  int slots = 192/C;
  float s=0.f, s2=0.f;
  for (int bb=0; bb<64; bb++)
    for (int k=0; k<slots; k++){
      s  += psum[(size_t)bb*384 + k*C + c];
      s2 += psum[(size_t)bb*384 + 192 + k*C + c];
    }
  float mu = s/(float)LTOT;
  float var = s2/(float)LTOT - mu*mu;
  float rstd = rsqrtf(var + 1e-5f);
  float aa = rstd * g[c];
  a_out[c] = aa;
  b_out[c] = b[c] - mu*aa;
}

// ------------- conv3 1x1x1: 96 -> 18 flow channels, layout (18, L) ---------
__global__ __launch_bounds__(96) void k_flow(const float* __restrict__ t2,
                                             const float* __restrict__ a2, const float* __restrict__ b2,
                                             const float* __restrict__ w3, float* __restrict__ flow){
  __shared__ float xr[96];
  int l = blockIdx.x; int t = threadIdx.x;
  float xv = t2[(size_t)l*96 + t];
  xr[t] = fmaxf(xv*a2[t] + b2[t], 0.f);
  __syncthreads();
  if (t < 18){
    float acc = 0.f;
    for (int c=0;c<96;c++) acc += xr[c]*w3[t*96 + c];
    flow[(size_t)t*LTOT + l] = acc;
  }
}

// ------------- trilinear warp (per-head flow), border clamp ----------------
__global__ __launch_bounds__(192) void k_warp(const float* __restrict__ src,
                                              const float* __restrict__ flow, float* __restrict__ dst){
  int l = blockIdx.x; int tid = threadIdx.x; int hh = tid>>5;
  int d = l/784; int rm = l - d*784; int y = rm/28; int x = rm - y*28;
  float fd = flow[(size_t)(hh*3+0)*LTOT + l];
  float fy = flow[(size_t)(hh*3+1)*LTOT + l];
  float fx = flow[(size_t)(hh*3+2)*LTOT + l];
  float cd = fminf(fmaxf((float)d + fd, 0.f), 27.f);
  float cy = fminf(fmaxf((float)y + fy, 0.f), 27.f);
  float cx = fminf(fmaxf((float)x + fx, 0.f), 27.f);
  int d0 = (int)floorf(cd); int d1 = min(d0+1, 27);
  int y0 = (int)floorf(cy); int y1 = min(y0+1, 27);
  int x0 = (int)floorf(cx); int x1 = min(x0+1, 27);
  float wd = cd - (float)d0, wy = cy - (float)y0, wx = cx - (float)x0;
  #define SMP(di,yi,xi) src[(size_t)(((di)*28+(yi))*28+(xi))*192 + tid]
  float v000 = SMP(d0,y0,x0), v001 = SMP(d0,y0,x1), v010 = SMP(d0,y1,x0), v011 = SMP(d0,y1,x1);
  float v100 = SMP(d1,y0,x0), v101 = SMP(d1,y0,x1), v110 = SMP(d1,y1,x0), v111 = SMP(d1,y1,x1);
  #undef SMP
  float o = v000*(1-wd)*(1-wy)*(1-wx) + v001*(1-wd)*(1-wy)*wx
          + v010*(1-wd)*wy*(1-wx)     + v011*(1-wd)*wy*wx
          + v100*wd*(1-wy)*(1-wx)     + v101*wd*(1-wy)*wx
          + v110*wd*wy*(1-wx)         + v111*wd*wy*wx;
  dst[(size_t)l*192 + tid] = o;
}

// ------- windowed GEMV -> bf16 out: out[(w*6+h)*343+n][c] ------------------
__global__ __launch_bounds__(192) void k_qkv(const float* __restrict__ A,
                                             const float* __restrict__ Wt, const float* __restrict__ bias,
                                             u16* __restrict__ outp, float scale){
  __shared__ float xs[16*192];
  __shared__ int lsrc[16];
  int tid = threadIdx.x; int r0 = blockIdx.x*16;
  if (tid < 16){
    int r = r0 + tid; int w = r/343; int n = r - w*343;
    int nd = w>>4, nh = (w>>2)&3, nw = w&3;
    int i = n/49; int rr = n - i*49; int j = rr/7; int k = rr - j*7;
    int dd = nd*7 + i + 3; if (dd >= 28) dd -= 28;
    int hh = nh*7 + j + 3; if (hh >= 28) hh -= 28;
    int ww = nw*7 + k + 3; if (ww >= 28) ww -= 28;
    lsrc[tid] = (dd*28 + hh)*28 + ww;
  }
  __syncthreads();
  #pragma unroll
  for (int it=0; it<16; it++) xs[it*192 + tid] = A[(size_t)lsrc[it]*192 + tid];
  __syncthreads();
  float acc[16];
  #pragma unroll
  for (int u=0;u<16;u++) acc[u]=0.f;
  const float4* wrow = (const float4*)(Wt + (size_t)tid*192);
  for (int kc=0; kc<24; kc++){
    float4 wa = wrow[kc*2], wbv = wrow[kc*2+1];
    #pragma unroll
    for (int rr2=0; rr2<16; rr2++){
      const float4* xp = (const float4*)(xs + rr2*192 + kc*8);
      float4 x0 = xp[0], x1 = xp[1];
      acc[rr2] += x0.x*wa.x + x0.y*wa.y + x0.z*wa.z + x0.w*wa.w
                + x1.x*wbv.x + x1.y*wbv.y + x1.z*wbv.z + x1.w*wbv.w;
    }
  }
  float bb = bias[tid];
  int h = tid>>5, c = tid&31;
  #pragma unroll
  for (int rr2=0; rr2<16; rr2++){
    int r = r0 + rr2; int w = r/343; int n = r - w*343;
    outp[((size_t)(w*6 + h)*343 + n)*32 + c] = f2b((acc[rr2] + bb)*scale);
  }
}

// ------------ MFMA attention: block = (window, head, q-group) --------------
// grid = 384*6; each wave handles ONE 16-query tile (qt = qg*4 + wave).
__global__ __launch_bounds__(256) void k_attmfma(const u16* __restrict__ Q,
                                                 const u16* __restrict__ K,
                                                 const u16* __restrict__ V,
                                                 const float* __restrict__ bm,
                                                 float* __restrict__ ctx){
  __shared__ __align__(16) u16 Kl[352*40];      // [key][40]
  __shared__ __align__(16) u16 Vt[32*360];      // [dim][360]
  __shared__ __align__(16) u16 Pl[4][2][16*40]; // per-wave, dbuf: [query16][40]
  int bid = blockIdx.x;
  int wh = bid/6, qg = bid - (bid/6)*6;
  int w = wh/6, h = wh - w*6;
  int tid = threadIdx.x;
  int nd = w>>4, nh = (w>>2)&3, nw = w&3;
  int type = ((nd==3)?4:0) | ((nh==3)?2:0) | ((nw==3)?1:0);
  const u16* kb = K + (size_t)wh*10976;
  const u16* vbp = V + (size_t)wh*10976;
  for (int idx=tid; idx<343*4; idx+=256){
    int row = idx>>2, c8 = (idx&3)*8;
    uint4 val = *(const uint4*)(kb + row*32 + c8);
    *(uint4*)(&Kl[row*40 + c8]) = val;
  }
  for (int idx=tid; idx<9*40; idx+=256) Kl[343*40 + idx] = 0;
  for (int idx=tid; idx<343*4; idx+=256){
    int row = idx>>2, c8 = (idx&3)*8;
    uint4 val = *(const uint4*)(vbp + row*32 + c8);
    const u16* pv = (const u16*)&val;
    #pragma unroll
    for (int j=0;j<8;j++) Vt[(c8+j)*360 + row] = pv[j];
  }
  for (int idx=tid; idx<32*17; idx+=256){
    int dd = idx/17, cc = 343 + idx - (idx/17)*17;
    Vt[dd*360 + cc] = 0;
  }
  __syncthreads();
  int lane = tid&63, wv = tid>>6;
  int lm = lane&15, lq = lane>>4;
  const float* bmh = bm + (size_t)(type*6 + h)*123904;
  int qt = qg*4 + wv;
  if (qt < 22){
    int q0 = qt*16;
    short8 bq = *(const short8*)(Q + (size_t)wh*10976 + (q0+lm)*32 + lq*8);
    float4v sc[22];
    #pragma unroll
    for (int kt=0; kt<22; kt++){
      short8 ak = *(const short8*)(&Kl[(kt*16+lm)*40 + lq*8]);
      sc[kt] = __builtin_amdgcn_mfma_f32_16x16x32_bf16(ak, bq, (float4v)0.f, 0, 0, 0);
    }
    const float* bcol = bmh + q0 + lm;
    float mx = -3.0e38f;
    #pragma unroll
    for (int kt=0; kt<22; kt++){
      #pragma unroll
      for (int r=0; r<4; r++){
        int key = kt*16 + lq*4 + r;
        float s = sc[kt][r] + bcol[(size_t)key*352];
        sc[kt][r] = s;
        mx = fmaxf(mx, s);
      }
    }
    mx = fmaxf(mx, __shfl_xor(mx, 16));
    mx = fmaxf(mx, __shfl_xor(mx, 32));
    float sm = 0.f;
    #pragma unroll
    for (int kt=0; kt<22; kt++){
      #pragma unroll
      for (int r=0; r<4; r++){
        float p = __expf(sc[kt][r] - mx);
        sc[kt][r] = p;
        sm += p;
      }
    }
    sm += __shfl_xor(sm, 16);
    sm += __shfl_xor(sm, 32);
    float inv = 1.f/sm;
    float4v o0 = (float4v)0.f, o1 = (float4v)0.f;
    #pragma unroll
    for (int s=0; s<11; s++){
      u16* pw = &Pl[wv][s&1][0];
      #pragma unroll
      for (int half=0; half<2; half++){
        int kt = 2*s + half;
        uint2 pv2;
        pv2.x = (u32)f2b(sc[kt][0]) | ((u32)f2b(sc[kt][1])<<16);
        pv2.y = (u32)f2b(sc[kt][2]) | ((u32)f2b(sc[kt][3])<<16);
        *(uint2*)(&pw[lm*40 + half*16 + lq*4]) = pv2;
      }
      short8 bp = *(const short8*)(&pw[lm*40 + lq*8]);
      short8 a0 = *(const short8*)(&Vt[lm*360 + s*32 + lq*8]);
      short8 a1 = *(const short8*)(&Vt[(16+lm)*360 + s*32 + lq*8]);
      o0 = __builtin_amdgcn_mfma_f32_16x16x32_bf16(a0, bp, o0, 0, 0, 0);
      o1 = __builtin_amdgcn_mfma_f32_16x16x32_bf16(a1, bp, o1, 0, 0, 0);
    }
    int query = q0 + lm;
    if (query < 343){
      float* ob = ctx + ((size_t)w*NTOK + query)*192 + h*32;
      float4 t0, t1v;
      t0.x = o0[0]*inv; t0.y = o0[1]*inv; t0.z = o0[2]*inv; t0.w = o0[3]*inv;
      t1v.x = o1[0]*inv; t1v.y = o1[1]*inv; t1v.z = o1[2]*inv; t1v.w = o1[3]*inv;
      *(float4*)(ob + lq*4) = t0;
      *(float4*)(ob + 16 + lq*4) = t1v;
    }
  }
}

// ---- proj + residual + window-reverse/unroll: out f32 (L,192) -------------
__global__ __launch_bounds__(192) void k_proj(const float* __restrict__ ctx,
                                              const float* __restrict__ Wt, const float* __restrict__ bias,
                                              const float* __restrict__ resid, float* __restrict__ outp){
  __shared__ float xs[16*192];
  __shared__ int lsrc[16];
  int tid = threadIdx.x; int r0 = blockIdx.x*16;
  if (tid < 16){
    int l = r0 + tid;
    int d = l/784; int rm = l - d*784; int y = rm/28; int x = rm - y*28;
    int dp = d-3; if (dp<0) dp+=28;
    int yp = y-3; if (yp<0) yp+=28;
    int xp = x-3; if (xp<0) xp+=28;
    int nd = dp/7, i = dp - nd*7;
    int nh = yp/7, j = yp - nh*7;
    int nw = xp/7, k = xp - nw*7;
    lsrc[tid] = ((nd*4+nh)*4+nw)*NTOK + (i*7+j)*7 + k;
  }
  __syncthreads();
  #pragma unroll
  for (int it=0; it<16; it++) xs[it*192 + tid] = ctx[(size_t)lsrc[it]*192 + tid];
  __syncthreads();
  float acc[16];
  #pragma unroll
  for (int u=0;u<16;u++) acc[u]=0.f;
  const float4* wrow = (const float4*)(Wt + (size_t)tid*192);
  for (int kc=0; kc<24; kc++){
    float4 wa = wrow[kc*2], wbv = wrow[kc*2+1];
    #pragma unroll
    for (int rr2=0; rr2<16; rr2++){
      const float4* xp = (const float4*)(xs + rr2*192 + kc*8);
      float4 x0 = xp[0], x1 = xp[1];
      acc[rr2] += x0.x*wa.x + x0.y*wa.y + x0.z*wa.z + x0.w*wa.w
                + x1.x*wbv.x + x1.y*wbv.y + x1.z*wbv.z + x1.w*wbv.w;
    }
  }
  float bb = bias[tid];
  #pragma unroll
  for (int rr2=0; rr2<16; rr2++){
    size_t o = (size_t)(r0 + rr2)*192 + tid;
    outp[o] = acc[rr2] + bb + resid[o];
  }
}

// ------- fc1 + gelu: x_ln [L,192] -> hs [L,768], 16-token tiles ------------
__global__ __launch_bounds__(384) void k_fc1(const float* __restrict__ xin,
                                             const float* __restrict__ w1, const float* __restrict__ b1,
                                             float* __restrict__ hs){
  __shared__ float xs[16*192];
  int tid = threadIdx.x; int l0 = blockIdx.x*16;
  for (int idx=tid; idx<16*192; idx+=384) xs[idx] = xin[(size_t)l0*192 + idx];
  __syncthreads();
  float a0[16], a1[16];
  #pragma unroll
  for (int t=0;t<16;t++){ a0[t]=0.f; a1[t]=0.f; }
  int j0 = tid, j1 = tid + 384;
  const float4* wr0 = (const float4*)(w1 + (size_t)j0*192);
  const float4* wr1 = (const float4*)(w1 + (size_t)j1*192);
  for (int kc=0; kc<48; kc++){
    float4 wa = wr0[kc], wb = wr1[kc];
    #pragma unroll
    for (int t=0;t<16;t++){
      const float4* xp = (const float4*)(xs + t*192 + kc*4);
      float4 x4 = xp[0];
      a0[t] += x4.x*wa.x + x4.y*wa.y + x4.z*wa.z + x4.w*wa.w;
      a1[t] += x4.x*wb.x + x4.y*wb.y + x4.z*wb.z + x4.w*wb.w;
    }
  }
  float bv0 = b1[j0], bv1 = b1[j1];
  #pragma unroll
  for (int t=0;t<16;t++){
    float v0 = a0[t] + bv0, v1 = a1[t] + bv1;
    hs[(size_t)(l0+t)*768 + j0] = 0.5f*v0*(1.f + erff(v0*0.70710678118f));
    hs[(size_t)(l0+t)*768 + j1] = 0.5f*v1*(1.f + erff(v1*0.70710678118f));
  }
}

// ------- fc2 + residual: hs [L,768] -> out [L,192] (adds resid) ------------
__global__ __launch_bounds__(192) void k_fc2(const float* __restrict__ hs,
                                             const float* __restrict__ w2, const float* __restrict__ b2,
                                             const float* __restrict__ resid, float* __restrict__ outp){
  __shared__ float hl[16*768];
  int tid = threadIdx.x; int l0 = blockIdx.x*16;
  for (int idx=tid; idx<16*768; idx+=192) hl[idx] = hs[(size_t)l0*768 + idx];
  __syncthreads();
  float acc[16];
  #pragma unroll
  for (int t=0;t<16;t++) acc[t]=0.f;
  const float4* wr = (const float4*)(w2 + (size_t)tid*768);
  for (int kc=0; kc<192; kc++){
    float4 wa = wr[kc];
    #pragma unroll
    for (int t=0;t<16;t++){
      const float4* hp = (const float4*)(hl + t*768 + kc*4);
      float4 h4 = hp[0];
      acc[t] += h4.x*wa.x + h4.y*wa.y + h4.z*wa.z + h4.w*wa.w;
    }
  }
  float bb = b2[tid];
  #pragma unroll
  for (int t=0;t<16;t++){
    size_t o = (size_t)(l0+t)*192 + tid;
    outp[o] = acc[t] + bb + resid[o];
  }
}

// ===========================================================================
extern "C" void kernel_launch(void* const* d_in, const int* in_sizes, int n_in,
                              void* d_out, int out_size, void* d_ws, size_t ws_size,
                              hipStream_t stream){
  const float* mov     = (const float*)d_in[0];
  const float* fix     = (const float*)d_in[1];
  const float* n1g     = (const float*)d_in[2];
  const float* n1b     = (const float*)d_in[3];
  const float* offm_w1 = (const float*)d_in[4];
  const float* offm_g1 = (const float*)d_in[5];
  const float* offm_b1 = (const float*)d_in[6];
  const float* offm_w2 = (const float*)d_in[7];
  const float* offm_g2 = (const float*)d_in[8];
  const float* offm_b2 = (const float*)d_in[9];
  const float* offm_w3 = (const float*)d_in[10];
  const float* offf_w1 = (const float*)d_in[11];
  const float* offf_g1 = (const float*)d_in[12];
  const float* offf_b1 = (const float*)d_in[13];
  const float* offf_w2 = (const float*)d_in[14];
  const float* offf_g2 = (const float*)d_in[15];
  const float* offf_b2 = (const float*)d_in[16];
  const float* offf_w3 = (const float*)d_in[17];
  const float* mq_w    = (const float*)d_in[18];
  const float* mkv_w   = (const float*)d_in[19];
  const float* fq_w    = (const float*)d_in[20];
  const float* fkv_w   = (const float*)d_in[21];
  const float* mproj_w = (const float*)d_in[22];
  const float* fproj_w = (const float*)d_in[23];
  const float* mq_b    = (const float*)d_in[24];
  const float* mkv_b   = (const float*)d_in[25];
  const float* fq_b    = (const float*)d_in[26];
  const float* fkv_b   = (const float*)d_in[27];
  const float* mproj_b = (const float*)d_in[28];
  const float* fproj_b = (const float*)d_in[29];
  const float* rpbt    = (const float*)d_in[30];
  const float* n2g     = (const float*)d_in[31];
  const float* n2b     = (const float*)d_in[32];
  const float* fc1_w   = (const float*)d_in[33];
  const float* fc1_b   = (const float*)d_in[34];
  const float* fc2_w   = (const float*)d_in[35];
  const float* fc2_b   = (const float*)d_in[36];
  float* outp = (float*)d_out;

  float* W = (float*)d_ws;
  const size_t L192 = (size_t)LTOT*192;   // floats per region
  float* m_   = W;
  float* f_   = W + 1*L192;
  float* t1   = W + 2*L192;
  float* t2   = W + 3*L192;
  float* dmov = W + 4*L192;
  float* dfix = W + 5*L192;
  float* ctxm = dmov; float* ctxf = dfix;
  float* mout = m_;   float* fout = f_;
  u16* QMb = (u16*)(W + 6*L192);
  u16* QFb = (u16*)(W + 7*L192);
  u16* Kmb = (u16*)(W + 2*L192);
  u16* Vmb = (u16*)(W + 3*L192);
  u16* Kfb = (u16*)(W + 8*L192);
  u16* Vfb = (u16*)(W + 9*L192);
  float* a1v = W + 6*L192;        float* b1v = a1v + 192;
  float* a2v = a1v + 384;         float* b2v = a1v + 480;
  float* psum = a1v + 512;        // 64*384 floats
  float* flowm = W + 7*L192;      float* flowf = flowm + (size_t)LTOT*18;
  u16* xp   = (u16*)(W + 4*L192);
  u16* xp2  = (u16*)(W + 5*L192 + 2000000);
  u16* wt1m = (u16*)(W + 8*L192);
  u16* wt1f = wt1m + 192*10368;
  u16* wt2m = wt1f + 192*10368;
  u16* wt2f = wt2m + 96*5184;
  float* bm = W;
  float* hsbuf = t1;
  float* lnbuf = W + 6*L192;

  // conv weight prep
  k_prepw1b<<<(192*10368+255)/256, 256, 0, stream>>>(offm_w1, wt1m, 0);
  k_prepw1b<<<(192*10368+255)/256, 256, 0, stream>>>(offf_w1, wt1f, 192);
  k_prepw2b<<<(96*5184+255)/256, 256, 0, stream>>>(offm_w2, wt2m);
  k_prepw2b<<<(96*5184+255)/256, 256, 0, stream>>>(offf_w2, wt2f);
  // layernorm1
  k_ln<<<2*LTOT, 64, 0, stream>>>(mov, fix, n1g, n1b, m_, f_);
  // padded bf16 volume [m|f]
  k_pad1<<<27000, 192, 0, stream>>>(m_, f_, xp);
  // offset block (moving)
  k_convmfma<384,96,192,2><<<686, 256, 0, stream>>>(xp, wt1m, t1);
  k_bnsum<<<64, 192, 0, stream>>>(t1, 192, psum);
  k_bnfin<<<1, 192, 0, stream>>>(psum, 192, offm_g1, offm_b1, a1v, b1v);
  k_pad2<<<27000, 192, 0, stream>>>(t1, a1v, b1v, xp2);
  k_convmfma<192,48,96,1><<<686, 256, 0, stream>>>(xp2, wt2m, t2);
  k_bnsum<<<64, 192, 0, stream>>>(t2, 96, psum);
  k_bnfin<<<1, 96, 0, stream>>>(psum, 96, offm_g2, offm_b2, a2v, b2v);
  k_flow<<<LTOT, 96, 0, stream>>>(t2, a2v, b2v, offm_w3, flowm);
  // offset block (fixed)
  k_convmfma<384,96,192,2><<<686, 256, 0, stream>>>(xp, wt1f, t1);
  k_bnsum<<<64, 192, 0, stream>>>(t1, 192, psum);
  k_bnfin<<<1, 192, 0, stream>>>(psum, 192, offf_g1, offf_b1, a1v, b1v);
  k_pad2<<<27000, 192, 0, stream>>>(t1, a1v, b1v, xp2);
  k_convmfma<192,48,96,1><<<686, 256, 0, stream>>>(xp2, wt2f, t2);
  k_bnsum<<<64, 192, 0, stream>>>(t2, 96, psum);
  k_bnfin<<<1, 96, 0, stream>>>(psum, 96, offf_g2, offf_b2, a2v, b2v);
  k_flow<<<LTOT, 96, 0, stream>>>(t2, a2v, b2v, offf_w3, flowf);
  // deformable warp
  k_warp<<<LTOT, 192, 0, stream>>>(m_, flowm, dmov);
  k_warp<<<LTOT, 192, 0, stream>>>(f_, flowf, dfix);
  // windowed projections -> bf16
  const float scale = 0.17677669529663687f; // 32^-0.5
  k_qkv<<<1372, 192, 0, stream>>>(dmov, mq_w,  mq_b,  QMb, scale);   // dmQ
  k_qkv<<<1372, 192, 0, stream>>>(dfix, fq_w,  fq_b,  QFb, scale);   // dfQ
  k_qkv<<<1372, 192, 0, stream>>>(m_, mkv_w,          mkv_b,     Kmb, 1.f);
  k_qkv<<<1372, 192, 0, stream>>>(m_, mkv_w+192*192,  mkv_b+192, Vmb, 1.f);
  k_qkv<<<1372, 192, 0, stream>>>(f_, fkv_w,          fkv_b,     Kfb, 1.f);
  k_qkv<<<1372, 192, 0, stream>>>(f_, fkv_w+192*192,  fkv_b+192, Vfb, 1.f);
  // bias matrix (m_/f_ now dead)
  k_prepbias<<<(48*123904+255)/256, 256, 0, stream>>>(rpbt, bm);
  // attention: mo = attend(dfQ, mK, mV); fo = attend(dmQ, fK, fV)
  k_attmfma<<<2304, 256, 0, stream>>>(QFb, Kmb, Vmb, bm, ctxm);
  k_attmfma<<<2304, 256, 0, stream>>>(QMb, Kfb, Vfb, bm, ctxf);
  // proj + residual + window-reverse/unroll
  k_proj<<<1372, 192, 0, stream>>>(ctxm, mproj_w, mproj_b, mov, mout);
  k_proj<<<1372, 192, 0, stream>>>(ctxf, fproj_w, fproj_b, fix, fout);
  // MLP (mov half)
  k_ln1<<<LTOT, 64, 0, stream>>>(mout, n2g, n2b, lnbuf);
  k_fc1<<<1372, 384, 0, stream>>>(lnbuf, fc1_w, fc1_b, hsbuf);
  k_fc2<<<1372, 192, 0, stream>>>(hsbuf, fc2_w, fc2_b, mout, outp);
  // MLP (fix half)
  k_ln1<<<LTOT, 64, 0, stream>>>(fout, n2g, n2b, lnbuf);
  k_fc1<<<1372, 384, 0, stream>>>(lnbuf, fc1_w, fc1_b, hsbuf);
  k_fc2<<<1372, 192, 0, stream>>>(hsbuf, fc2_w, fc2_b, fout, outp + L192);
}

// Round 8
// 1811.619 us; speedup vs baseline: 9.3231x; 1.6267x over previous
//
#include <hip/hip_runtime.h>

#define LTOT 21952      // 28^3
#define NTOK 343        // 7^3

typedef unsigned short u16;
typedef unsigned int   u32;
typedef __attribute__((ext_vector_type(8))) short short8;
typedef __attribute__((ext_vector_type(4))) float float4v;

__device__ __forceinline__ u16 f2b(float f){
  u32 x = __float_as_uint(f);
  u32 r = (x + 0x7fffu + ((x>>16)&1u)) >> 16;
  return (u16)r;
}

// ---------------- LayerNorm (norm1) : f32 in -> f32 out --------------------
__global__ __launch_bounds__(64) void k_ln(const float* __restrict__ mov, const float* __restrict__ fix,
                                           const float* __restrict__ g, const float* __restrict__ b,
                                           float* __restrict__ om, float* __restrict__ of){
  int row = blockIdx.x;
  const float* src; float* dst;
  if (row < LTOT){ src = mov + (size_t)row*192; dst = om + (size_t)row*192; }
  else          { src = fix + (size_t)(row-LTOT)*192; dst = of + (size_t)(row-LTOT)*192; }
  int t = threadIdx.x;
  float x0 = src[t], x1 = src[t+64], x2 = src[t+128];
  float s = x0+x1+x2, s2 = x0*x0 + x1*x1 + x2*x2;
  for (int o=32;o;o>>=1){ s += __shfl_xor(s,o); s2 += __shfl_xor(s2,o); }
  float mu = s*(1.f/192.f);
  float var = s2*(1.f/192.f) - mu*mu;
  float rs = rsqrtf(var + 1e-5f);
  dst[t]     = (x0-mu)*rs*g[t]     + b[t];
  dst[t+64]  = (x1-mu)*rs*g[t+64]  + b[t+64];
  dst[t+128] = (x2-mu)*rs*g[t+128] + b[t+128];
}

// ---------------- LayerNorm (norm2), single buffer -------------------------
__global__ __launch_bounds__(64) void k_ln1(const float* __restrict__ x,
                                            const float* __restrict__ g, const float* __restrict__ b,
                                            float* __restrict__ y){
  int row = blockIdx.x;
  const float* src = x + (size_t)row*192;
  float* dst = y + (size_t)row*192;
  int t = threadIdx.x;
  float x0 = src[t], x1 = src[t+64], x2 = src[t+128];
  float s = x0+x1+x2, s2 = x0*x0 + x1*x1 + x2*x2;
  for (int o=32;o;o>>=1){ s += __shfl_xor(s,o); s2 += __shfl_xor(s2,o); }
  float mu = s*(1.f/192.f);
  float var = s2*(1.f/192.f) - mu*mu;
  float rs = rsqrtf(var + 1e-5f);
  dst[t]     = (x0-mu)*rs*g[t]     + b[t];
  dst[t+64]  = (x1-mu)*rs*g[t+64]  + b[t+64];
  dst[t+128] = (x2-mu)*rs*g[t+128] + b[t+128];
}

// ------ conv1 weight prep: (192,384,27) f32 -> [n][t*384+c] bf16 -----------
__global__ void k_prepw1b(const float* __restrict__ src, u16* __restrict__ dst, int swap){
  int idx = blockIdx.x*256 + threadIdx.x;
  if (idx >= 192*10368) return;
  int n = idx / 10368; int k = idx - n*10368;
  int t = k / 384; int c = k - t*384;
  int cs = c + swap; if (cs >= 384) cs -= 384;
  dst[idx] = f2b(src[((size_t)n*384 + cs)*27 + t]);
}
// ------ conv2 weight prep: (96,192,27) f32 -> [n][t*192+c] bf16 ------------
__global__ void k_prepw2b(const float* __restrict__ src, u16* __restrict__ dst){
  int idx = blockIdx.x*256 + threadIdx.x;
  if (idx >= 96*5184) return;
  int n = idx / 5184; int k = idx - n*5184;
  int t = k / 192; int c = k - t*192;
  dst[idx] = f2b(src[((size_t)n*192 + c)*27 + t]);
}
// ------ generic f32 -> bf16 copy (row-major weights) -----------------------
__global__ void k_prepwb(const float* __restrict__ src, u16* __restrict__ dst, int count){
  int idx = blockIdx.x*256 + threadIdx.x;
  if (idx < count) dst[idx] = f2b(src[idx]);
}

// ------ bias matrix prep: [type 8][head 6][key 352][query 352] f32 ---------
__global__ void k_prepbias(const float* __restrict__ rpt, float* __restrict__ bm){
  int idx = blockIdx.x*256 + threadIdx.x;
  if (idx >= 48*123904) return;
  int th = idx / 123904; int r = idx - th*123904;
  int key = r / 352; int q = r - key*352;
  int type = th / 6; int h = th - type*6;
  float v;
  if (key >= 343 || q >= 343){
    v = -30000.f;
  } else {
    int ki = key/49, kj = (key/7)%7, kk = key%7;
    int qi = q/49,   qj = (q/7)%7,   qk = q%7;
    int ridx = ((qi-ki+6)*13 + (qj-kj+6))*13 + (qk-kk+6);
    float rv = rpt[ridx*6 + h];
    int bd = (type>>2)&1, bh = (type>>1)&1, bw = type&1;
    int lq_ = (bd?((qi<4)?1:2):0)*9 + (bh?((qj<4)?1:2):0)*3 + (bw?((qk<4)?1:2):0);
    int lk_ = (bd?((ki<4)?1:2):0)*9 + (bh?((kj<4)?1:2):0)*3 + (bw?((kk<4)?1:2):0);
    v = rv + ((lq_==lk_) ? 0.f : -100.f);
  }
  bm[idx] = v;
}

// ------ padded volume builders (30^3, zero borders), bf16 ------------------
__global__ __launch_bounds__(192) void k_pad1(const float* __restrict__ m_, const float* __restrict__ f_,
                                              u16* __restrict__ xp){
  int p = blockIdx.x; int t = threadIdx.x;
  int pd = p/900; int r = p - pd*900; int ph = r/30; int pw = r - ph*30;
  int d = pd-1, h = ph-1, w = pw-1;
  u16 vm = 0, vf = 0;
  if ((unsigned)d < 28u && (unsigned)h < 28u && (unsigned)w < 28u){
    size_t l = (size_t)((d*28+h)*28+w)*192 + t;
    vm = f2b(m_[l]); vf = f2b(f_[l]);
  }
  xp[(size_t)p*384 + t] = vm;
  xp[(size_t)p*384 + 192 + t] = vf;
}
__global__ __launch_bounds__(192) void k_pad2(const float* __restrict__ t1,
                                              const float* __restrict__ a1, const float* __restrict__ b1,
                                              u16* __restrict__ xp2){
  int p = blockIdx.x; int t = threadIdx.x;
  int pd = p/900; int r = p - pd*900; int ph = r/30; int pw = r - ph*30;
  int d = pd-1, h = ph-1, w = pw-1;
  u16 v = 0;
  if ((unsigned)d < 28u && (unsigned)h < 28u && (unsigned)w < 28u){
    float xv = t1[(size_t)((d*28+h)*28+w)*192 + t];
    v = f2b(fmaxf(xv*a1[t] + b1[t], 0.f));
  }
  xp2[(size_t)p*192 + t] = v;
}

// ------ implicit-GEMM MFMA conv 3x3x3, N-split grid (2 halves) -------------
template<int CIN, int COUTB, int COUTF, int NWN>
__global__ __launch_bounds__(256) void k_convmfma(const u16* __restrict__ xp,
                                                  const u16* __restrict__ wt,
                                                  float* __restrict__ out){
  constexpr int K = 27*CIN;
  constexpr int CH = CIN/32;          // k-chunks per tap
  constexpr int STEPS = 27*CH;
  constexpr int MT = (NWN==2)?2:1;    // m-tiles per wave
  constexpr int NT = COUTB/16/NWN;    // n-tiles per wave (=3)
  __shared__ __align__(16) u16 As[2][64*40];
  __shared__ __align__(16) u16 Bs[2][COUTB*40];
  int tid = threadIdx.x;
  int wave = tid>>6, lane = tid&63;
  int lm = lane&15, lq = lane>>4;
  int bid = blockIdx.x;
  int v0 = (bid>>1)*64;
  int nh = bid&1;
  const u16* wtb = wt + (size_t)(nh*COUTB)*K;
  int ncol0 = nh*COUTB;
  int sv = tid>>2;
  int sc8 = (tid&3)*8;
  int av = v0 + sv;
  int d = av/784; int rm2 = av - d*784; int hh = rm2/28; int ww = rm2 - hh*28;
  int pbase = (d*30 + hh)*30 + ww;
  int wave_m = (NWN==2) ? (wave>>1) : wave;
  int wave_n = (NWN==2) ? (wave&1) : 0;
  int mbase = wave_m*16*MT;
  int nbase = wave_n*16*NT;

  float4v acc[MT][NT];
  #pragma unroll
  for (int mt=0; mt<MT; mt++)
    #pragma unroll
    for (int nt=0; nt<NT; nt++) acc[mt][nt] = (float4v)0.f;

  auto stage = [&](int buf, int s){
    int t = s/CH, cc = s - t*CH;
    int td = t/9; int tr = t - td*9; int th = tr/3; int tw = tr - th*3;
    int toff = td*900 + th*30 + tw;
    {
      uint4 val = *(const uint4*)(xp + (size_t)(pbase + toff)*CIN + cc*32 + sc8);
      *(uint4*)(&As[buf][sv*40 + sc8]) = val;
    }
    #pragma unroll
    for (int bi = tid; bi < COUTB*4; bi += 256){
      int n = bi>>2, c8 = (bi&3)*8;
      uint4 val = *(const uint4*)(wtb + (size_t)n*K + t*CIN + cc*32 + c8);
      *(uint4*)(&Bs[buf][n*40 + c8]) = val;
    }
  };

  stage(0, 0);
  __syncthreads();
  for (int s = 0; s < STEPS; s++){
    if (s+1 < STEPS) stage((s+1)&1, s+1);
    int buf = s&1;
    short8 aa[MT];
    #pragma unroll
    for (int mt=0; mt<MT; mt++)
      aa[mt] = *(const short8*)(&As[buf][(mbase + mt*16 + lm)*40 + lq*8]);
    short8 bfr[NT];
    #pragma unroll
    for (int nt=0; nt<NT; nt++)
      bfr[nt] = *(const short8*)(&Bs[buf][(nbase + nt*16 + lm)*40 + lq*8]);
    #pragma unroll
    for (int nt=0; nt<NT; nt++)
      #pragma unroll
      for (int mt=0; mt<MT; mt++)
        acc[mt][nt] = __builtin_amdgcn_mfma_f32_16x16x32_bf16(aa[mt], bfr[nt], acc[mt][nt], 0, 0, 0);
    __syncthreads();
  }
  #pragma unroll
  for (int mt=0; mt<MT; mt++)
    #pragma unroll
    for (int nt=0; nt<NT; nt++)
      #pragma unroll
      for (int r=0; r<4; r++){
        int row = v0 + mbase + mt*16 + lq*4 + r;
        int col = ncol0 + nbase + nt*16 + lm;
        out[(size_t)row*COUTF + col] = acc[mt][nt][r];
      }
}

// ---- generic MFMA GEMM: out[M=21952 rows][NF] = A[map(row)][K] * B[NF][K]^T
// GATHER: 0=identity, 1=qkv window-roll, 2=proj window-reverse
// ASRC: 0 = f32 A (convert), 1 = bf16 A
// EPI: 0 = qkv u16 out ((w*6+h)*343+tok)*32+c, (acc+bias)*scale
//      1 = f32 out stride NF: acc + bias + resid
//      2 = bf16 out stride NF: gelu(acc + bias)
//      3 = KV split: col<192 -> out16 (K), else out16b (V); (acc+bias)
template<int K, int NF, int GATHER, int ASRC, int EPI>
__global__ __launch_bounds__(256) void k_gemm(const float* __restrict__ Af,
                                              const u16* __restrict__ Ab,
                                              const u16* __restrict__ B,
                                              const float* __restrict__ bias,
                                              const float* __restrict__ resid,
                                              float* __restrict__ outf,
                                              u16* __restrict__ out16,
                                              u16* __restrict__ out16b,
                                              float scale){
  constexpr int STEPS = K/32;
  constexpr int NB = NF/64;
  __shared__ __align__(16) u16 As[2][64*40];
  __shared__ __align__(16) u16 Bs[2][64*40];
  __shared__ int map[64];
  int tid = threadIdx.x;
  int bid = blockIdx.x;
  int mb = bid / NB, nb = bid - mb*NB;
  int v0 = mb*64, ncol0 = nb*64;
  if (tid < 64){
    int r = v0 + tid;
    int src;
    if (GATHER == 0){
      src = r;
    } else if (GATHER == 1){
      int w = r/343; int n = r - w*343;
      int nd = w>>4, nh = (w>>2)&3, nw = w&3;
      int i = n/49; int rr = n - i*49; int j = rr/7; int k2 = rr - j*7;
      int dd = nd*7 + i + 3; if (dd >= 28) dd -= 28;
      int hh = nh*7 + j + 3; if (hh >= 28) hh -= 28;
      int ww = nw*7 + k2 + 3; if (ww >= 28) ww -= 28;
      src = (dd*28 + hh)*28 + ww;
    } else {
      int l = r;
      int d = l/784; int rm = l - d*784; int y = rm/28; int x = rm - y*28;
      int dp = d-3; if (dp<0) dp+=28;
      int yp = y-3; if (yp<0) yp+=28;
      int xq = x-3; if (xq<0) xq+=28;
      int nd = dp/7, i = dp - nd*7;
      int nh = yp/7, j = yp - nh*7;
      int nw = xq/7, k2 = xq - nw*7;
      src = ((nd*4+nh)*4+nw)*NTOK + (i*7+j)*7 + k2;
    }
    map[tid] = src;
  }
  __syncthreads();
  int sv = tid>>2, c8 = (tid&3)*8;
  int lane = tid&63, wv = tid>>6;
  int lm = lane&15, lq = lane>>4;
  int mbase = (wv>>1)*32, nbase = (wv&1)*32;

  float4v acc[2][2];
  #pragma unroll
  for (int mt=0; mt<2; mt++)
    #pragma unroll
    for (int nt=0; nt<2; nt++) acc[mt][nt] = (float4v)0.f;

  auto stage = [&](int buf, int s){
    if (ASRC == 0){
      const float* ap = Af + (size_t)map[sv]*K + s*32 + c8;
      float4 a0 = *(const float4*)ap;
      float4 a1 = *(const float4*)(ap+4);
      uint4 pk;
      pk.x = (u32)f2b(a0.x) | ((u32)f2b(a0.y)<<16);
      pk.y = (u32)f2b(a0.z) | ((u32)f2b(a0.w)<<16);
      pk.z = (u32)f2b(a1.x) | ((u32)f2b(a1.y)<<16);
      pk.w = (u32)f2b(a1.z) | ((u32)f2b(a1.w)<<16);
      *(uint4*)(&As[buf][sv*40 + c8]) = pk;
    } else {
      uint4 val = *(const uint4*)(Ab + (size_t)map[sv]*K + s*32 + c8);
      *(uint4*)(&As[buf][sv*40 + c8]) = val;
    }
    uint4 bv = *(const uint4*)(B + (size_t)(ncol0 + sv)*K + s*32 + c8);
    *(uint4*)(&Bs[buf][sv*40 + c8]) = bv;
  };

  stage(0, 0);
  __syncthreads();
  for (int s = 0; s < STEPS; s++){
    if (s+1 < STEPS) stage((s+1)&1, s+1);
    int buf = s&1;
    short8 aa[2], bb[2];
    #pragma unroll
    for (int mt=0; mt<2; mt++)
      aa[mt] = *(const short8*)(&As[buf][(mbase + mt*16 + lm)*40 + lq*8]);
    #pragma unroll
    for (int nt=0; nt<2; nt++)
      bb[nt] = *(const short8*)(&Bs[buf][(nbase + nt*16 + lm)*40 + lq*8]);
    #pragma unroll
    for (int nt=0; nt<2; nt++)
      #pragma unroll
      for (int mt=0; mt<2; mt++)
        acc[mt][nt] = __builtin_amdgcn_mfma_f32_16x16x32_bf16(aa[mt], bb[nt], acc[mt][nt], 0, 0, 0);
    __syncthreads();
  }
  // epilogue
  float bv[2];
  #pragma unroll
  for (int nt=0; nt<2; nt++) bv[nt] = bias ? bias[ncol0 + nbase + nt*16 + lm] : 0.f;
  #pragma unroll
  for (int mt=0; mt<2; mt++){
    #pragma unroll
    for (int r=0; r<4; r++){
      int row = v0 + mbase + mt*16 + lq*4 + r;
      if (EPI == 0 || EPI == 3){
        int w = row/343; int tok = row - w*343;
        #pragma unroll
        for (int nt=0; nt<2; nt++){
          int col = ncol0 + nbase + nt*16 + lm;
          float val = (acc[mt][nt][r] + bv[nt]) * scale;
          if (EPI == 0){
            int h = col>>5, c = col&31;
            out16[((size_t)(w*6 + h)*343 + tok)*32 + c] = f2b(val);
          } else {
            u16* dst = (col < 192) ? out16 : out16b;
            int cc = (col < 192) ? col : col - 192;
            int h = cc>>5, c = cc&31;
            dst[((size_t)(w*6 + h)*343 + tok)*32 + c] = f2b(val);
          }
        }
      } else if (EPI == 1){
        #pragma unroll
        for (int nt=0; nt<2; nt++){
          int col = ncol0 + nbase + nt*16 + lm;
          size_t o = (size_t)row*NF + col;
          outf[o] = acc[mt][nt][r] + bv[nt] + resid[o];
        }
      } else {
        #pragma unroll
        for (int nt=0; nt<2; nt++){
          int col = ncol0 + nbase + nt*16 + lm;
          float v = acc[mt][nt][r] + bv[nt];
          float gl = 0.5f*v*(1.f + erff(v*0.70710678118f));
          out16[(size_t)row*NF + col] = f2b(gl);
        }
      }
    }
  }
}

// ---- BN stats, coalesced 2-stage: partial sums then finalize --------------
__global__ __launch_bounds__(192) void k_bnsum(const float* __restrict__ x, int C,
                                               float* __restrict__ psum){
  int bid = blockIdx.x, t = threadIdx.x;
  int rpi = 192/C;
  int c  = (C==192) ? t : (t % 96);
  int ro = (C==192) ? 0 : (t / 96);
  float s=0.f, s2=0.f;
  int base = bid*343;
  for (int r = ro; r < 343; r += rpi){
    float v = x[(size_t)(base+r)*C + c];
    s += v; s2 += v*v;
  }
  psum[(size_t)bid*384 + t]       = s;
  psum[(size_t)bid*384 + 192 + t] = s2;
}
__global__ void k_bnfin(const float* __restrict__ psum, int C,
                        const float* __restrict__ g, const float* __restrict__ b,
                        float* __restrict__ a_out, float* __restrict__ b_out){
  int c = threadIdx.x;
  if (c >= C) return;
  int slots = 192/C;
  float s=0.f, s2=0.f;
  for (int bb=0; bb<64; bb++)
    for (int k=0; k<slots; k++){
      s  += psum[(size_t)bb*384 + k*C + c];
      s2 += psum[(size_t)bb*384 + 192 + k*C + c];
    }
  float mu = s/(float)LTOT;
  float var = s2/(float)LTOT - mu*mu;
  float rstd = rsqrtf(var + 1e-5f);
  float aa = rstd * g[c];
  a_out[c] = aa;
  b_out[c] = b[c] - mu*aa;
}

// ------------- conv3 1x1x1: 96 -> 18 flow channels, layout (18, L) ---------
__global__ __launch_bounds__(96) void k_flow(const float* __restrict__ t2,
                                             const float* __restrict__ a2, const float* __restrict__ b2,
                                             const float* __restrict__ w3, float* __restrict__ flow){
  __shared__ float xr[96];
  int l = blockIdx.x; int t = threadIdx.x;
  float xv = t2[(size_t)l*96 + t];
  xr[t] = fmaxf(xv*a2[t] + b2[t], 0.f);
  __syncthreads();
  if (t < 18){
    float acc = 0.f;
    for (int c=0;c<96;c++) acc += xr[c]*w3[t*96 + c];
    flow[(size_t)t*LTOT + l] = acc;
  }
}

// ------------- trilinear warp (per-head flow), border clamp ----------------
__global__ __launch_bounds__(192) void k_warp(const float* __restrict__ src,
                                              const float* __restrict__ flow, float* __restrict__ dst){
  int l = blockIdx.x; int tid = threadIdx.x; int hh = tid>>5;
  int d = l/784; int rm = l - d*784; int y = rm/28; int x = rm - y*28;
  float fd = flow[(size_t)(hh*3+0)*LTOT + l];
  float fy = flow[(size_t)(hh*3+1)*LTOT + l];
  float fx = flow[(size_t)(hh*3+2)*LTOT + l];
  float cd = fminf(fmaxf((float)d + fd, 0.f), 27.f);
  float cy = fminf(fmaxf((float)y + fy, 0.f), 27.f);
  float cx = fminf(fmaxf((float)x + fx, 0.f), 27.f);
  int d0 = (int)floorf(cd); int d1 = min(d0+1, 27);
  int y0 = (int)floorf(cy); int y1 = min(y0+1, 27);
  int x0 = (int)floorf(cx); int x1 = min(x0+1, 27);
  float wd = cd - (float)d0, wy = cy - (float)y0, wx = cx - (float)x0;
  #define SMP(di,yi,xi) src[(size_t)(((di)*28+(yi))*28+(xi))*192 + tid]
  float v000 = SMP(d0,y0,x0), v001 = SMP(d0,y0,x1), v010 = SMP(d0,y1,x0), v011 = SMP(d0,y1,x1);
  float v100 = SMP(d1,y0,x0), v101 = SMP(d1,y0,x1), v110 = SMP(d1,y1,x0), v111 = SMP(d1,y1,x1);
  #undef SMP
  float o = v000*(1-wd)*(1-wy)*(1-wx) + v001*(1-wd)*(1-wy)*wx
          + v010*(1-wd)*wy*(1-wx)     + v011*(1-wd)*wy*wx
          + v100*wd*(1-wy)*(1-wx)     + v101*wd*(1-wy)*wx
          + v110*wd*wy*(1-wx)         + v111*wd*wy*wx;
  dst[(size_t)l*192 + tid] = o;
}

// ------------ MFMA attention: block = (window, head, q-group) --------------
__global__ __launch_bounds__(256) void k_attmfma(const u16* __restrict__ Q,
                                                 const u16* __restrict__ K,
                                                 const u16* __restrict__ V,
                                                 const float* __restrict__ bm,
                                                 float* __restrict__ ctx){
  __shared__ __align__(16) u16 Kl[352*40];      // [key][40]
  __shared__ __align__(16) u16 Vt[32*360];      // [dim][360]
  __shared__ __align__(16) u16 Pl[4][2][16*40]; // per-wave, dbuf
  int bid = blockIdx.x;
  int wh = bid/6, qg = bid - (bid/6)*6;
  int w = wh/6, h = wh - w*6;
  int tid = threadIdx.x;
  int nd = w>>4, nh = (w>>2)&3, nw = w&3;
  int type = ((nd==3)?4:0) | ((nh==3)?2:0) | ((nw==3)?1:0);
  const u16* kb = K + (size_t)wh*10976;
  const u16* vbp = V + (size_t)wh*10976;
  for (int idx=tid; idx<343*4; idx+=256){
    int row = idx>>2, c8 = (idx&3)*8;
    uint4 val = *(const uint4*)(kb + row*32 + c8);
    *(uint4*)(&Kl[row*40 + c8]) = val;
  }
  for (int idx=tid; idx<9*40; idx+=256) Kl[343*40 + idx] = 0;
  for (int idx=tid; idx<343*4; idx+=256){
    int row = idx>>2, c8 = (idx&3)*8;
    uint4 val = *(const uint4*)(vbp + row*32 + c8);
    const u16* pv = (const u16*)&val;
    #pragma unroll
    for (int j=0;j<8;j++) Vt[(c8+j)*360 + row] = pv[j];
  }
  for (int idx=tid; idx<32*17; idx+=256){
    int dd = idx/17, cc = 343 + idx - (idx/17)*17;
    Vt[dd*360 + cc] = 0;
  }
  __syncthreads();
  int lane = tid&63, wv = tid>>6;
  int lm = lane&15, lq = lane>>4;
  const float* bmh = bm + (size_t)(type*6 + h)*123904;
  int qt = qg*4 + wv;
  if (qt < 22){
    int q0 = qt*16;
    short8 bq = *(const short8*)(Q + (size_t)wh*10976 + (q0+lm)*32 + lq*8);
    float4v sc[22];
    #pragma unroll
    for (int kt=0; kt<22; kt++){
      short8 ak = *(const short8*)(&Kl[(kt*16+lm)*40 + lq*8]);
      sc[kt] = __builtin_amdgcn_mfma_f32_16x16x32_bf16(ak, bq, (float4v)0.f, 0, 0, 0);
    }
    const float* bcol = bmh + q0 + lm;
    float mx = -3.0e38f;
    #pragma unroll
    for (int kt=0; kt<22; kt++){
      #pragma unroll
      for (int r=0; r<4; r++){
        int key = kt*16 + lq*4 + r;
        float s = sc[kt][r] + bcol[(size_t)key*352];
        sc[kt][r] = s;
        mx = fmaxf(mx, s);
      }
    }
    mx = fmaxf(mx, __shfl_xor(mx, 16));
    mx = fmaxf(mx, __shfl_xor(mx, 32));
    float sm = 0.f;
    #pragma unroll
    for (int kt=0; kt<22; kt++){
      #pragma unroll
      for (int r=0; r<4; r++){
        float p = __expf(sc[kt][r] - mx);
        sc[kt][r] = p;
        sm += p;
      }
    }
    sm += __shfl_xor(sm, 16);
    sm += __shfl_xor(sm, 32);
    float inv = 1.f/sm;
    float4v o0 = (float4v)0.f, o1 = (float4v)0.f;
    #pragma unroll
    for (int s=0; s<11; s++){
      u16* pw = &Pl[wv][s&1][0];
      #pragma unroll
      for (int half=0; half<2; half++){
        int kt = 2*s + half;
        uint2 pv2;
        pv2.x = (u32)f2b(sc[kt][0]) | ((u32)f2b(sc[kt][1])<<16);
        pv2.y = (u32)f2b(sc[kt][2]) | ((u32)f2b(sc[kt][3])<<16);
        *(uint2*)(&pw[lm*40 + half*16 + lq*4]) = pv2;
      }
      short8 bp = *(const short8*)(&pw[lm*40 + lq*8]);
      short8 a0 = *(const short8*)(&Vt[lm*360 + s*32 + lq*8]);
      short8 a1 = *(const short8*)(&Vt[(16+lm)*360 + s*32 + lq*8]);
      o0 = __builtin_amdgcn_mfma_f32_16x16x32_bf16(a0, bp, o0, 0, 0, 0);
      o1 = __builtin_amdgcn_mfma_f32_16x16x32_bf16(a1, bp, o1, 0, 0, 0);
    }
    int query = q0 + lm;
    if (query < 343){
      float* ob = ctx + ((size_t)w*NTOK + query)*192 + h*32;
      float4 t0, t1v;
      t0.x = o0[0]*inv; t0.y = o0[1]*inv; t0.z = o0[2]*inv; t0.w = o0[3]*inv;
      t1v.x = o1[0]*inv; t1v.y = o1[1]*inv; t1v.z = o1[2]*inv; t1v.w = o1[3]*inv;
      *(float4*)(ob + lq*4) = t0;
      *(float4*)(ob + 16 + lq*4) = t1v;
    }
  }
}

// ===========================================================================
extern "C" void kernel_launch(void* const* d_in, const int* in_sizes, int n_in,
                              void* d_out, int out_size, void* d_ws, size_t ws_size,
                              hipStream_t stream){
  const float* mov     = (const float*)d_in[0];
  const float* fix     = (const float*)d_in[1];
  const float* n1g     = (const float*)d_in[2];
  const float* n1b     = (const float*)d_in[3];
  const float* offm_w1 = (const float*)d_in[4];
  const float* offm_g1 = (const float*)d_in[5];
  const float* offm_b1 = (const float*)d_in[6];
  const float* offm_w2 = (const float*)d_in[7];
  const float* offm_g2 = (const float*)d_in[8];
  const float* offm_b2 = (const float*)d_in[9];
  const float* offm_w3 = (const float*)d_in[10];
  const float* offf_w1 = (const float*)d_in[11];
  const float* offf_g1 = (const float*)d_in[12];
  const float* offf_b1 = (const float*)d_in[13];
  const float* offf_w2 = (const float*)d_in[14];
  const float* offf_g2 = (const float*)d_in[15];
  const float* offf_b2 = (const float*)d_in[16];
  const float* offf_w3 = (const float*)d_in[17];
  const float* mq_w    = (const float*)d_in[18];
  const float* mkv_w   = (const float*)d_in[19];
  const float* fq_w    = (const float*)d_in[20];
  const float* fkv_w   = (const float*)d_in[21];
  const float* mproj_w = (const float*)d_in[22];
  const float* fproj_w = (const float*)d_in[23];
  const float* mq_b    = (const float*)d_in[24];
  const float* mkv_b   = (const float*)d_in[25];
  const float* fq_b    = (const float*)d_in[26];
  const float* fkv_b   = (const float*)d_in[27];
  const float* mproj_b = (const float*)d_in[28];
  const float* fproj_b = (const float*)d_in[29];
  const float* rpbt    = (const float*)d_in[30];
  const float* n2g     = (const float*)d_in[31];
  const float* n2b     = (const float*)d_in[32];
  const float* fc1_w   = (const float*)d_in[33];
  const float* fc1_b   = (const float*)d_in[34];
  const float* fc2_w   = (const float*)d_in[35];
  const float* fc2_b   = (const float*)d_in[36];
  float* outp = (float*)d_out;

  float* W = (float*)d_ws;
  const size_t L192 = (size_t)LTOT*192;   // floats per region
  float* m_   = W;
  float* f_   = W + 1*L192;
  float* t1   = W + 2*L192;
  float* t2   = W + 3*L192;
  float* dmov = W + 4*L192;
  float* dfix = W + 5*L192;
  float* ctxm = dmov; float* ctxf = dfix;
  float* mout = m_;   float* fout = f_;
  u16* QMb = (u16*)(W + 6*L192);
  u16* QFb = (u16*)(W + 7*L192);
  u16* Kmb = (u16*)(W + 2*L192);
  u16* Vmb = (u16*)(W + 3*L192);
  u16* Kfb = (u16*)(W + 8*L192);
  u16* Vfb = (u16*)(W + 9*L192);
  float* a1v = W + 6*L192;        float* b1v = a1v + 192;
  float* a2v = a1v + 384;         float* b2v = a1v + 480;
  float* psum = a1v + 512;        // 64*384 floats
  float* flowm = W + 7*L192;      float* flowf = flowm + (size_t)LTOT*18;
  u16* xp   = (u16*)(W + 4*L192);
  u16* xp2  = (u16*)(W + 5*L192 + 2000000);
  u16* wt1m = (u16*)(W + 8*L192);
  u16* wt1f = wt1m + 192*10368;
  u16* wt2m = wt1f + 192*10368;
  u16* wt2f = wt2m + 96*5184;
  float* bm = W;
  // GEMM weights (bf16) in region-9 tail (after Vfb's 8.43MB; persists all run)
  u16* wq_m  = (u16*)(W + 9*L192) + 4214784;
  u16* wq_f  = wq_m  + 36864;
  u16* wkv_m = wq_f  + 36864;
  u16* wkv_f = wkv_m + 73728;
  u16* wpj_m = wkv_f + 73728;
  u16* wpj_f = wpj_m + 36864;
  u16* wfc1  = wpj_f + 36864;
  u16* wfc2  = wfc1  + 147456;
  u16* hs16  = (u16*)(W + 2*L192);   // bf16 hs: 21952*768*2B = 33.7MB (regions 2-3)
  float* lnbuf = W + 6*L192;

  // conv weight prep
  k_prepw1b<<<(192*10368+255)/256, 256, 0, stream>>>(offm_w1, wt1m, 0);
  k_prepw1b<<<(192*10368+255)/256, 256, 0, stream>>>(offf_w1, wt1f, 192);
  k_prepw2b<<<(96*5184+255)/256, 256, 0, stream>>>(offm_w2, wt2m);
  k_prepw2b<<<(96*5184+255)/256, 256, 0, stream>>>(offf_w2, wt2f);
  // GEMM weight prep (f32 -> bf16, same layout)
  k_prepwb<<<144, 256, 0, stream>>>(mq_w,    wq_m,  36864);
  k_prepwb<<<144, 256, 0, stream>>>(fq_w,    wq_f,  36864);
  k_prepwb<<<288, 256, 0, stream>>>(mkv_w,   wkv_m, 73728);
  k_prepwb<<<288, 256, 0, stream>>>(fkv_w,   wkv_f, 73728);
  k_prepwb<<<144, 256, 0, stream>>>(mproj_w, wpj_m, 36864);
  k_prepwb<<<144, 256, 0, stream>>>(fproj_w, wpj_f, 36864);
  k_prepwb<<<576, 256, 0, stream>>>(fc1_w,   wfc1,  147456);
  k_prepwb<<<576, 256, 0, stream>>>(fc2_w,   wfc2,  147456);
  // layernorm1
  k_ln<<<2*LTOT, 64, 0, stream>>>(mov, fix, n1g, n1b, m_, f_);
  // padded bf16 volume [m|f]
  k_pad1<<<27000, 192, 0, stream>>>(m_, f_, xp);
  // offset block (moving)
  k_convmfma<384,96,192,2><<<686, 256, 0, stream>>>(xp, wt1m, t1);
  k_bnsum<<<64, 192, 0, stream>>>(t1, 192, psum);
  k_bnfin<<<1, 192, 0, stream>>>(psum, 192, offm_g1, offm_b1, a1v, b1v);
  k_pad2<<<27000, 192, 0, stream>>>(t1, a1v, b1v, xp2);
  k_convmfma<192,48,96,1><<<686, 256, 0, stream>>>(xp2, wt2m, t2);
  k_bnsum<<<64, 192, 0, stream>>>(t2, 96, psum);
  k_bnfin<<<1, 96, 0, stream>>>(psum, 96, offm_g2, offm_b2, a2v, b2v);
  k_flow<<<LTOT, 96, 0, stream>>>(t2, a2v, b2v, offm_w3, flowm);
  // offset block (fixed)
  k_convmfma<384,96,192,2><<<686, 256, 0, stream>>>(xp, wt1f, t1);
  k_bnsum<<<64, 192, 0, stream>>>(t1, 192, psum);
  k_bnfin<<<1, 192, 0, stream>>>(psum, 192, offf_g1, offf_b1, a1v, b1v);
  k_pad2<<<27000, 192, 0, stream>>>(t1, a1v, b1v, xp2);
  k_convmfma<192,48,96,1><<<686, 256, 0, stream>>>(xp2, wt2f, t2);
  k_bnsum<<<64, 192, 0, stream>>>(t2, 96, psum);
  k_bnfin<<<1, 96, 0, stream>>>(psum, 96, offf_g2, offf_b2, a2v, b2v);
  k_flow<<<LTOT, 96, 0, stream>>>(t2, a2v, b2v, offf_w3, flowf);
  // deformable warp
  k_warp<<<LTOT, 192, 0, stream>>>(m_, flowm, dmov);
  k_warp<<<LTOT, 192, 0, stream>>>(f_, flowf, dfix);
  // windowed projections (MFMA GEMM, gather folded into A-map) -> bf16
  const float scale = 0.17677669529663687f; // 32^-0.5
  k_gemm<192,192,1,0,0><<<343*3, 256, 0, stream>>>(dmov, nullptr, wq_m,  mq_b,  nullptr, nullptr, QMb, nullptr, scale);
  k_gemm<192,192,1,0,0><<<343*3, 256, 0, stream>>>(dfix, nullptr, wq_f,  fq_b,  nullptr, nullptr, QFb, nullptr, scale);
  k_gemm<192,384,1,0,3><<<343*6, 256, 0, stream>>>(m_,   nullptr, wkv_m, mkv_b, nullptr, nullptr, Kmb, Vmb, 1.f);
  k_gemm<192,384,1,0,3><<<343*6, 256, 0, stream>>>(f_,   nullptr, wkv_f, fkv_b, nullptr, nullptr, Kfb, Vfb, 1.f);
  // bias matrix (m_/f_ now dead)
  k_prepbias<<<(48*123904+255)/256, 256, 0, stream>>>(rpbt, bm);
  // attention: mo = attend(dfQ, mK, mV); fo = attend(dmQ, fK, fV)
  k_attmfma<<<2304, 256, 0, stream>>>(QFb, Kmb, Vmb, bm, ctxm);
  k_attmfma<<<2304, 256, 0, stream>>>(QMb, Kfb, Vfb, bm, ctxf);
  // proj + residual + window-reverse (gather on A rows)
  k_gemm<192,192,2,0,1><<<343*3, 256, 0, stream>>>(ctxm, nullptr, wpj_m, mproj_b, mov, mout, nullptr, nullptr, 1.f);
  k_gemm<192,192,2,0,1><<<343*3, 256, 0, stream>>>(ctxf, nullptr, wpj_f, fproj_b, fix, fout, nullptr, nullptr, 1.f);
  // MLP (mov half): LN -> fc1(gelu, bf16 hs) -> fc2(+resid)
  k_ln1<<<LTOT, 64, 0, stream>>>(mout, n2g, n2b, lnbuf);
  k_gemm<192,768,0,0,2><<<343*12, 256, 0, stream>>>(lnbuf, nullptr, wfc1, fc1_b, nullptr, nullptr, hs16, nullptr, 1.f);
  k_gemm<768,192,0,1,1><<<343*3, 256, 0, stream>>>(nullptr, hs16, wfc2, fc2_b, mout, outp, nullptr, nullptr, 1.f);
  // MLP (fix half)
  k_ln1<<<LTOT, 64, 0, stream>>>(fout, n2g, n2b, lnbuf);
  k_gemm<192,768,0,0,2><<<343*12, 256, 0, stream>>>(lnbuf, nullptr, wfc1, fc1_b, nullptr, nullptr, hs16, nullptr, 1.f);
  k_gemm<768,192,0,1,1><<<343*3, 256, 0, stream>>>(nullptr, hs16, wfc2, fc2_b, fout, outp + L192, nullptr, nullptr, 1.f);
}